// Round 1
// baseline (1581.292 us; speedup 1.0000x reference)
//
#include <hip/hip_runtime.h>
#include <hip/hip_bf16.h>
#include <math.h>

#define NTOK   4096
#define DMODEL 1024
#define SEQL   2048
#define QKVW   1152     // 1024 q + 64 k + 64 v
#define NH     16
#define HDIM   64
#define NE     8
#define HIDD   4096
#define EPSV   1e-5f

typedef __attribute__((ext_vector_type(8))) short bf16x8;   // 8 x bf16 (4 VGPRs)
typedef __attribute__((ext_vector_type(4))) float f32x4;

__device__ __forceinline__ short f2b(float x){
  __hip_bfloat16 h = __float2bfloat16(x);
  return *reinterpret_cast<short*>(&h);
}

// ---------------- transpose fp32 [R][C] -> bf16 [C][R] ----------------
__global__ __launch_bounds__(256) void transpose_conv_kernel(
    const float* __restrict__ in, short* __restrict__ out,
    int R, int C, long inb, long outb)
{
  __shared__ float tile[32][33];
  in  += (size_t)blockIdx.z * inb;
  out += (size_t)blockIdx.z * outb;
  int c0 = blockIdx.x*32, r0 = blockIdx.y*32;
  int tx = threadIdx.x & 31, ty = threadIdx.x >> 5;
  #pragma unroll
  for (int i=0;i<4;i++)
    tile[ty+i*8][tx] = in[(size_t)(r0+ty+i*8)*C + c0+tx];
  __syncthreads();
  #pragma unroll
  for (int i=0;i<4;i++)
    out[(size_t)(c0+ty+i*8)*R + r0+tx] = f2b(tile[tx][ty+i*8]);
}

// ---------------- rmsnorm(x) -> fp32 ----------------
__global__ __launch_bounds__(256) void rms1_kernel(
    const float* __restrict__ x, const float* __restrict__ g, float* __restrict__ out)
{
  int row = blockIdx.x, tid = threadIdx.x;
  const float4* xr = (const float4*)(x + (size_t)row*DMODEL);
  float4 v = xr[tid];
  float ss = v.x*v.x + v.y*v.y + v.z*v.z + v.w*v.w;
  #pragma unroll
  for (int off=32; off; off>>=1) ss += __shfl_down(ss, off);
  __shared__ float red[4];
  if ((tid&63)==0) red[tid>>6] = ss;
  __syncthreads();
  float rs = rsqrtf((red[0]+red[1]+red[2]+red[3])*(1.f/1024.f) + EPSV);
  float4 gv = ((const float4*)g)[tid];
  float4 o;
  o.x = v.x*rs*gv.x; o.y = v.y*rs*gv.y; o.z = v.z*rs*gv.z; o.w = v.w*rs*gv.w;
  ((float4*)(out + (size_t)row*DMODEL))[tid] = o;
}

// ---------------- fp32 tiled GEMM: C[M,N] = A[M,K] @ B[K,N] ----------------
// 64x64 tile, BK=16, 256 thr, 4x4 microtile. B row-major (no transpose needed).
__global__ __launch_bounds__(256) void gemm_f32_kernel(
    const float* __restrict__ A, const float* __restrict__ B, float* __restrict__ C,
    int M, int N, int K, int lda, int ldb, int ldc, int coff)
{
  __shared__ float As[16][68];  // [k][m] transposed
  __shared__ float Bs[16][68];  // [k][n]
  int m0 = blockIdx.y*64, n0 = blockIdx.x*64;
  int tid = threadIdx.x, tx = tid & 15, ty = tid >> 4;
  float acc[4][4] = {};
  for (int k0=0; k0<K; k0+=16){
    #pragma unroll
    for (int i=0;i<4;i++){
      int c = tid + 256*i;
      int ar = c>>4, ac = c&15;
      As[ac][ar] = A[(size_t)(m0+ar)*lda + k0+ac];
      int br = c>>6, bc = c&63;
      Bs[br][bc] = B[(size_t)(k0+br)*ldb + n0+bc];
    }
    __syncthreads();
    #pragma unroll
    for (int k=0;k<16;k++){
      float4 a4 = *(const float4*)&As[k][ty*4];
      float4 b4 = *(const float4*)&Bs[k][tx*4];
      float ar[4] = {a4.x,a4.y,a4.z,a4.w};
      float bc[4] = {b4.x,b4.y,b4.z,b4.w};
      #pragma unroll
      for (int r=0;r<4;r++)
        #pragma unroll
        for (int cc=0;cc<4;cc++) acc[r][cc] += ar[r]*bc[cc];
    }
    __syncthreads();
  }
  #pragma unroll
  for (int r=0;r<4;r++){
    size_t rowb = (size_t)(m0+ty*4+r)*ldc + coff + n0 + tx*4;
    #pragma unroll
    for (int cc=0;cc<4;cc++) C[rowb+cc] = acc[r][cc];
  }
}

// ---------------- fp32 flash attention (MQA), per (qtile64, head, batch) ----------------
__global__ __launch_bounds__(256) void attn_f32_kernel(
    const float* __restrict__ qkv, float* __restrict__ out)
{
  __shared__ float Qst[64][68];   // [d][q]
  __shared__ float KPst[64][68];  // K-phase: [d][s] ; P-phase: [s][q]
  __shared__ float Vs [64][68];   // [s][d]
  int qt = blockIdx.x, h = blockIdx.y, b = blockIdx.z;
  int tid = threadIdx.x, tx = tid & 15, ty = tid >> 4;
  const float* qb = qkv + (size_t)b*SEQL*QKVW + (size_t)h*HDIM;
  const float* kb = qkv + (size_t)b*SEQL*QKVW + DMODEL;
  const float* vb = kb + HDIM;
  #pragma unroll
  for (int i=0;i<16;i++){
    int c = tid + 256*i;
    int row = c>>6, col = c&63;
    Qst[col][row] = qb[(size_t)(qt*64+row)*QKVW + col];
  }
  __syncthreads();
  float mrow[4], lrow[4], oacc[4][4];
  #pragma unroll
  for (int r=0;r<4;r++){ mrow[r]=-1e30f; lrow[r]=0.f;
    #pragma unroll
    for (int cc=0;cc<4;cc++) oacc[r][cc]=0.f; }

  for (int kv=0; kv<SEQL/64; kv++){
    __syncthreads();                        // prev-iter PV readers done
    #pragma unroll
    for (int i=0;i<16;i++){
      int c = tid + 256*i;
      int row = c>>6, col = c&63;
      KPst[col][row] = kb[(size_t)(kv*64+row)*QKVW + col];
      Vs[row][col]   = vb[(size_t)(kv*64+row)*QKVW + col];
    }
    __syncthreads();
    float sc[4][4] = {};
    #pragma unroll
    for (int k=0;k<64;k++){
      float4 a4 = *(const float4*)&Qst[k][ty*4];
      float4 b4 = *(const float4*)&KPst[k][tx*4];
      float ar[4] = {a4.x,a4.y,a4.z,a4.w};
      float bc[4] = {b4.x,b4.y,b4.z,b4.w};
      #pragma unroll
      for (int r=0;r<4;r++)
        #pragma unroll
        for (int cc=0;cc<4;cc++) sc[r][cc] += ar[r]*bc[cc];
    }
    __syncthreads();                        // all done reading K before P overwrites
    #pragma unroll
    for (int r=0;r<4;r++){
      float mx = fmaxf(fmaxf(sc[r][0],sc[r][1]), fmaxf(sc[r][2],sc[r][3]));
      #pragma unroll
      for (int off=1; off<16; off<<=1) mx = fmaxf(mx, __shfl_xor(mx, off));
      mx *= 0.125f;
      float mn = fmaxf(mrow[r], mx);
      float al = expf(mrow[r] - mn);
      float rsum = 0.f;
      #pragma unroll
      for (int cc=0;cc<4;cc++){ float p = expf(sc[r][cc]*0.125f - mn); sc[r][cc]=p; rsum += p; }
      #pragma unroll
      for (int off=1; off<16; off<<=1) rsum += __shfl_xor(rsum, off);
      lrow[r] = lrow[r]*al + rsum;
      mrow[r] = mn;
      #pragma unroll
      for (int cc=0;cc<4;cc++){
        oacc[r][cc] *= al;
        KPst[tx*4+cc][ty*4+r] = sc[r][cc];  // P^T write: [s][q]; same-wave readers only
      }
    }
    #pragma unroll
    for (int k=0;k<64;k++){
      float4 a4 = *(const float4*)&KPst[k][ty*4];  // P[s][q]
      float4 b4 = *(const float4*)&Vs[k][tx*4];    // V[s][d]
      float ar[4] = {a4.x,a4.y,a4.z,a4.w};
      float bc[4] = {b4.x,b4.y,b4.z,b4.w};
      #pragma unroll
      for (int r=0;r<4;r++)
        #pragma unroll
        for (int cc=0;cc<4;cc++) oacc[r][cc] += ar[r]*bc[cc];
    }
  }
  #pragma unroll
  for (int r=0;r<4;r++){
    int q = qt*64 + ty*4 + r;
    float inv = 1.f/lrow[r];
    size_t rowb = (size_t)(b*SEQL + q)*DMODEL + h*HDIM + tx*4;
    #pragma unroll
    for (int cc=0;cc<4;cc++) out[rowb+cc] = oacc[r][cc]*inv;
  }
}

// ---------------- x2 = x + rmsnorm(ao)*g_post ; h = bf16(rmsnorm(x2)*g_pre) ----------------
__global__ __launch_bounds__(256) void attnres_kernel(
    const float* __restrict__ x, const float* __restrict__ ao,
    const float* __restrict__ gpost, const float* __restrict__ gpre,
    float* __restrict__ x2, short* __restrict__ h)
{
  int row = blockIdx.x, tid = threadIdx.x;
  float4 a  = ((const float4*)(ao + (size_t)row*DMODEL))[tid];
  float4 xv = ((const float4*)(x  + (size_t)row*DMODEL))[tid];
  float ss = a.x*a.x + a.y*a.y + a.z*a.z + a.w*a.w;
  #pragma unroll
  for (int off=32; off; off>>=1) ss += __shfl_down(ss, off);
  __shared__ float red[4];
  if ((tid&63)==0) red[tid>>6] = ss;
  __syncthreads();
  float rs1 = rsqrtf((red[0]+red[1]+red[2]+red[3])*(1.f/1024.f) + EPSV);
  float4 gp = ((const float4*)gpost)[tid];
  float4 o;
  o.x = xv.x + a.x*rs1*gp.x; o.y = xv.y + a.y*rs1*gp.y;
  o.z = xv.z + a.z*rs1*gp.z; o.w = xv.w + a.w*rs1*gp.w;
  ((float4*)(x2 + (size_t)row*DMODEL))[tid] = o;
  float s2 = o.x*o.x + o.y*o.y + o.z*o.z + o.w*o.w;
  __syncthreads();
  #pragma unroll
  for (int off=32; off; off>>=1) s2 += __shfl_down(s2, off);
  if ((tid&63)==0) red[tid>>6] = s2;
  __syncthreads();
  float rs2 = rsqrtf((red[0]+red[1]+red[2]+red[3])*(1.f/1024.f) + EPSV);
  float4 gm = ((const float4*)gpre)[tid];
  short4 hs;
  hs.x = f2b(o.x*rs2*gm.x); hs.y = f2b(o.y*rs2*gm.y);
  hs.z = f2b(o.z*rs2*gm.z); hs.w = f2b(o.w*rs2*gm.w);
  *(short4*)(h + (size_t)row*DMODEL + tid*4) = hs;
}

// ---------------- router: fp32 rmsnorm(x2)@Wg, softmax, top-2, build expert lists ----------------
__global__ __launch_bounds__(64) void router_kernel(
    const float* __restrict__ x2, const float* __restrict__ g, const float* __restrict__ Wg,
    float* __restrict__ probs_out, int* __restrict__ tok_list, float* __restrict__ w_list,
    int* __restrict__ counts)
{
  int t = blockIdx.x, lane = threadIdx.x;
  const float4* xr = (const float4*)(x2 + (size_t)t*DMODEL);
  float4 v[4]; float ss = 0.f;
  #pragma unroll
  for (int i=0;i<4;i++){ v[i] = xr[lane + 64*i];
    ss += v[i].x*v[i].x + v[i].y*v[i].y + v[i].z*v[i].z + v[i].w*v[i].w; }
  #pragma unroll
  for (int off=32; off; off>>=1) ss += __shfl_xor(ss, off);
  float rs = rsqrtf(ss*(1.f/1024.f) + EPSV);
  float le[8] = {0,0,0,0,0,0,0,0};
  #pragma unroll
  for (int i=0;i<4;i++){
    int jb = (lane + 64*i)*4;
    float hv[4] = {v[i].x, v[i].y, v[i].z, v[i].w};
    #pragma unroll
    for (int c=0;c<4;c++){
      float hj = hv[c]*rs*g[jb+c];
      const float* wrow = Wg + (size_t)(jb+c)*NE;
      #pragma unroll
      for (int ee=0;ee<8;ee++) le[ee] += hj*wrow[ee];
    }
  }
  #pragma unroll
  for (int ee=0;ee<8;ee++)
    #pragma unroll
    for (int off=32; off; off>>=1) le[ee] += __shfl_xor(le[ee], off);
  float mx = le[0];
  #pragma unroll
  for (int ee=1;ee<8;ee++) mx = fmaxf(mx, le[ee]);
  float p[8], s = 0.f;
  #pragma unroll
  for (int ee=0;ee<8;ee++){ p[ee] = expf(le[ee]-mx); s += p[ee]; }
  float inv = 1.f/s;
  #pragma unroll
  for (int ee=0;ee<8;ee++) p[ee] *= inv;
  if (lane < 8) probs_out[(size_t)t*NE + lane] = p[lane];
  if (lane == 0){
    int i1 = 0;
    #pragma unroll
    for (int ee=1;ee<8;ee++) if (p[ee] > p[i1]) i1 = ee;
    int i2 = (i1==0) ? 1 : 0;
    #pragma unroll
    for (int ee=0;ee<8;ee++) if (ee != i1 && p[ee] > p[i2]) i2 = ee;
    int pos = atomicAdd(&counts[i1], 1);
    tok_list[i1*NTOK+pos] = t; w_list[i1*NTOK+pos] = p[i1];
    pos = atomicAdd(&counts[i2], 1);
    tok_list[i2*NTOK+pos] = t; w_list[i2*NTOK+pos] = p[i2];
  }
}

__global__ void prefix_kernel(const int* __restrict__ counts, int* __restrict__ bases){
  if (threadIdx.x == 0){
    int a = 0;
    for (int ee=0;ee<8;ee++){ bases[ee] = a; a += counts[ee]; }
  }
}

// ---------------- MoE grouped GEMM1: mid = gelu(h_gathered @ We1[e]) (bf16 MFMA) ----------------
// 128x128 tile, BK=32, 4 waves, 16x16x32 bf16 MFMA. Bt is [N][K] (pre-transposed).
__global__ __launch_bounds__(256) void moe_gemm1_kernel(
    const short* __restrict__ h, const short* __restrict__ we1t,
    const int* __restrict__ tok_list, const int* __restrict__ counts,
    const int* __restrict__ bases, short* __restrict__ mid)
{
  int e = blockIdx.z;
  int cnt = counts[e];
  int m0 = blockIdx.y*128, n0 = blockIdx.x*128;
  if (m0 >= cnt) return;
  int base = bases[e];
  const short* Bt = we1t + (size_t)e*HIDD*DMODEL;
  const int* tl = tok_list + e*NTOK;
  __shared__ short lsA[128*40];
  __shared__ short lsB[128*40];
  int tid = threadIdx.x, wave = tid>>6, lane = tid&63;
  int wm = (wave>>1)*64, wn = (wave&1)*64;
  const short* aptr[2]; const short* bptr[2];
  #pragma unroll
  for (int i=0;i<2;i++){
    int c = tid + 256*i; int row = c>>2;
    int rr = min(m0+row, cnt-1);
    aptr[i] = h + (size_t)tl[rr]*DMODEL;
    bptr[i] = Bt + (size_t)(n0+row)*DMODEL;
  }
  f32x4 acc[4][4] = {};
  for (int k0=0; k0<DMODEL; k0+=32){
    #pragma unroll
    for (int i=0;i<2;i++){
      int c = tid + 256*i; int row = c>>2, col = (c&3)*8;
      *(bf16x8*)&lsA[row*40+col] = *(const bf16x8*)(aptr[i]+k0+col);
      *(bf16x8*)&lsB[row*40+col] = *(const bf16x8*)(bptr[i]+k0+col);
    }
    __syncthreads();
    bf16x8 af[4], bfr[4];
    #pragma unroll
    for (int m=0;m<4;m++) af[m] = *(bf16x8*)&lsA[(wm+m*16+(lane&15))*40 + (lane>>4)*8];
    #pragma unroll
    for (int n=0;n<4;n++) bfr[n] = *(bf16x8*)&lsB[(wn+n*16+(lane&15))*40 + (lane>>4)*8];
    #pragma unroll
    for (int m=0;m<4;m++)
      #pragma unroll
      for (int n=0;n<4;n++)
        acc[m][n] = __builtin_amdgcn_mfma_f32_16x16x32_bf16(af[m], bfr[n], acc[m][n], 0,0,0);
    __syncthreads();
  }
  #pragma unroll
  for (int m=0;m<4;m++){
    int lr0 = wm + m*16 + ((lane>>4)<<2);
    #pragma unroll
    for (int n=0;n<4;n++){
      int col = n0 + wn + n*16 + (lane&15);
      #pragma unroll
      for (int r=0;r<4;r++){
        int gr = m0 + lr0 + r;
        if (gr < cnt){
          float tval = acc[m][n][r];
          float ge = 0.5f*tval*(1.f + tanhf(0.7978845608f*(tval + 0.044715f*tval*tval*tval)));
          mid[(size_t)(base+gr)*HIDD + col] = f2b(ge);
        }
      }
    }
  }
}

// ---------------- MoE grouped GEMM2: moe_out[tok] += w * (mid @ We2[e]) ----------------
__global__ __launch_bounds__(256) void moe_gemm2_kernel(
    const short* __restrict__ mid, const short* __restrict__ we2t,
    const int* __restrict__ tok_list, const float* __restrict__ w_list,
    const int* __restrict__ counts, const int* __restrict__ bases,
    float* __restrict__ moe_out)
{
  int e = blockIdx.z;
  int cnt = counts[e];
  int m0 = blockIdx.y*128, n0 = blockIdx.x*128;
  if (m0 >= cnt) return;
  int base = bases[e];
  const short* A  = mid + (size_t)base*HIDD;
  const short* Bt = we2t + (size_t)e*DMODEL*HIDD;
  const int* tl = tok_list + e*NTOK;
  const float* wl = w_list + e*NTOK;
  __shared__ short lsA[128*40];
  __shared__ short lsB[128*40];
  int tid = threadIdx.x, wave = tid>>6, lane = tid&63;
  int wm = (wave>>1)*64, wn = (wave&1)*64;
  const short* aptr[2]; const short* bptr[2];
  #pragma unroll
  for (int i=0;i<2;i++){
    int c = tid + 256*i; int row = c>>2;
    int rr = min(m0+row, cnt-1);
    aptr[i] = A + (size_t)rr*HIDD;
    bptr[i] = Bt + (size_t)(n0+row)*HIDD;
  }
  f32x4 acc[4][4] = {};
  for (int k0=0; k0<HIDD; k0+=32){
    #pragma unroll
    for (int i=0;i<2;i++){
      int c = tid + 256*i; int row = c>>2, col = (c&3)*8;
      *(bf16x8*)&lsA[row*40+col] = *(const bf16x8*)(aptr[i]+k0+col);
      *(bf16x8*)&lsB[row*40+col] = *(const bf16x8*)(bptr[i]+k0+col);
    }
    __syncthreads();
    bf16x8 af[4], bfr[4];
    #pragma unroll
    for (int m=0;m<4;m++) af[m] = *(bf16x8*)&lsA[(wm+m*16+(lane&15))*40 + (lane>>4)*8];
    #pragma unroll
    for (int n=0;n<4;n++) bfr[n] = *(bf16x8*)&lsB[(wn+n*16+(lane&15))*40 + (lane>>4)*8];
    #pragma unroll
    for (int m=0;m<4;m++)
      #pragma unroll
      for (int n=0;n<4;n++)
        acc[m][n] = __builtin_amdgcn_mfma_f32_16x16x32_bf16(af[m], bfr[n], acc[m][n], 0,0,0);
    __syncthreads();
  }
  #pragma unroll
  for (int m=0;m<4;m++){
    int lr0 = wm + m*16 + ((lane>>4)<<2);
    #pragma unroll
    for (int n=0;n<4;n++){
      int col = n0 + wn + n*16 + (lane&15);
      #pragma unroll
      for (int r=0;r<4;r++){
        int gr = m0 + lr0 + r;
        if (gr < cnt)
          atomicAdd(&moe_out[(size_t)tl[gr]*DMODEL + col], wl[gr]*acc[m][n][r]);
      }
    }
  }
}

// ---------------- out = x2 + rmsnorm(moe)*g_post_moe ----------------
__global__ __launch_bounds__(256) void final_kernel(
    const float* __restrict__ x2, const float* __restrict__ moe,
    const float* __restrict__ g, float* __restrict__ out)
{
  int row = blockIdx.x, tid = threadIdx.x;
  float4 mv = ((const float4*)(moe + (size_t)row*DMODEL))[tid];
  float4 xv = ((const float4*)(x2  + (size_t)row*DMODEL))[tid];
  float ss = mv.x*mv.x + mv.y*mv.y + mv.z*mv.z + mv.w*mv.w;
  #pragma unroll
  for (int off=32; off; off>>=1) ss += __shfl_down(ss, off);
  __shared__ float red[4];
  if ((tid&63)==0) red[tid>>6] = ss;
  __syncthreads();
  float rs = rsqrtf((red[0]+red[1]+red[2]+red[3])*(1.f/1024.f) + EPSV);
  float4 gv = ((const float4*)g)[tid];
  float4 o;
  o.x = xv.x + mv.x*rs*gv.x; o.y = xv.y + mv.y*rs*gv.y;
  o.z = xv.z + mv.z*rs*gv.z; o.w = xv.w + mv.w*rs*gv.w;
  ((float4*)(out + (size_t)row*DMODEL))[tid] = o;
}

extern "C" void kernel_launch(void* const* d_in, const int* in_sizes, int n_in,
                              void* d_out, int out_size, void* d_ws, size_t ws_size,
                              hipStream_t stream) {
  (void)in_sizes; (void)n_in; (void)out_size; (void)ws_size;
  const float* x          = (const float*)d_in[0];
  const float* g_pre_mqa  = (const float*)d_in[1];
  const float* g_post_mqa = (const float*)d_in[2];
  const float* g_pre_moe  = (const float*)d_in[3];
  const float* g_post_moe = (const float*)d_in[4];
  const float* Wq         = (const float*)d_in[5];
  const float* Wk         = (const float*)d_in[6];
  const float* Wv         = (const float*)d_in[7];
  const float* Wo         = (const float*)d_in[8];
  const float* Wg         = (const float*)d_in[9];
  const float* We1        = (const float*)d_in[10];
  const float* We2        = (const float*)d_in[11];

  float* out_x = (float*)d_out;
  float* out_probs = out_x + (size_t)NTOK*DMODEL;

  // workspace layout
  char* p = (char*)d_ws;
  size_t off = 0;
  auto alloc = [&](size_t bytes)->void*{
    void* r = p + off; off = (off + bytes + 255) & ~(size_t)255; return r; };
  short* we1t   = (short*)alloc((size_t)NE*HIDD*DMODEL*2);   // [e][hid][d] bf16
  short* we2t   = (short*)alloc((size_t)NE*DMODEL*HIDD*2);   // [e][d][hid] bf16
  short* mid    = (short*)alloc((size_t)2*NTOK*HIDD*2);      // [8192][4096] bf16
  float* bufA   = (float*)alloc((size_t)NTOK*QKVW*4);        // qkv fp32, later ao fp32
  float* bufB   = (float*)alloc((size_t)NTOK*DMODEL*4);      // xn1 fp32, later attn fp32
  float* x2     = (float*)alloc((size_t)NTOK*DMODEL*4);
  short* hbuf   = (short*)alloc((size_t)NTOK*DMODEL*2);
  float* moe    = (float*)alloc((size_t)NTOK*DMODEL*4);
  int*   tok_l  = (int*)  alloc((size_t)NE*NTOK*4);
  float* w_l    = (float*)alloc((size_t)NE*NTOK*4);
  int*   counts = (int*)  alloc(64);
  int*   bases  = (int*)  alloc(64);

  float* qkv = bufA;          // [4096][1152]
  float* xn1 = bufB;          // [4096][1024]
  float* attn = bufB;         // reused after xn1 dead
  float* ao = bufA;           // reused after qkv dead

  hipMemsetAsync(moe, 0, (size_t)NTOK*DMODEL*4, stream);
  hipMemsetAsync(counts, 0, 32, stream);

  // weight convert+transpose (expert weights only; fp32 GEMMs read raw weights)
  transpose_conv_kernel<<<dim3(HIDD/32, DMODEL/32, NE), 256, 0, stream>>>(
      We1, we1t, DMODEL, HIDD, (long)DMODEL*HIDD, (long)HIDD*DMODEL);
  transpose_conv_kernel<<<dim3(DMODEL/32, HIDD/32, NE), 256, 0, stream>>>(
      We2, we2t, HIDD, DMODEL, (long)HIDD*DMODEL, (long)DMODEL*HIDD);

  // pre-router chain, all fp32 (router top-2 must match fp32 reference)
  rms1_kernel<<<NTOK, 256, 0, stream>>>(x, g_pre_mqa, xn1);
  gemm_f32_kernel<<<dim3(DMODEL/64, NTOK/64), 256, 0, stream>>>(
      xn1, Wq, qkv, NTOK, DMODEL, DMODEL, DMODEL, DMODEL, QKVW, 0);
  gemm_f32_kernel<<<dim3(1, NTOK/64), 256, 0, stream>>>(
      xn1, Wk, qkv, NTOK, HDIM, DMODEL, DMODEL, HDIM, QKVW, DMODEL);
  gemm_f32_kernel<<<dim3(1, NTOK/64), 256, 0, stream>>>(
      xn1, Wv, qkv, NTOK, HDIM, DMODEL, DMODEL, HDIM, QKVW, DMODEL+HDIM);
  attn_f32_kernel<<<dim3(SEQL/64, NH, 2), 256, 0, stream>>>(qkv, attn);
  gemm_f32_kernel<<<dim3(DMODEL/64, NTOK/64), 256, 0, stream>>>(
      attn, Wo, ao, NTOK, DMODEL, DMODEL, DMODEL, DMODEL, DMODEL, 0);
  attnres_kernel<<<NTOK, 256, 0, stream>>>(x, ao, g_post_mqa, g_pre_moe, x2, hbuf);

  // router + grouped MoE (bf16 MFMA)
  router_kernel<<<NTOK, 64, 0, stream>>>(x2, g_pre_moe, Wg, out_probs, tok_l, w_l, counts);
  prefix_kernel<<<1, 64, 0, stream>>>(counts, bases);
  moe_gemm1_kernel<<<dim3(HIDD/128, NTOK/128, NE), 256, 0, stream>>>(
      hbuf, we1t, tok_l, counts, bases, mid);
  moe_gemm2_kernel<<<dim3(DMODEL/128, NTOK/128, NE), 256, 0, stream>>>(
      mid, we2t, tok_l, w_l, counts, bases, moe);
  final_kernel<<<NTOK, 256, 0, stream>>>(x2, moe, g_post_moe, out_x);
}

// Round 2
// 1034.895 us; speedup vs baseline: 1.5280x; 1.5280x over previous
//
#include <hip/hip_runtime.h>
#include <hip/hip_bf16.h>
#include <math.h>

#define NTOK   4096
#define DMODEL 1024
#define SEQL   2048
#define QKVW   1152     // 1024 q + 64 k + 64 v
#define NH     16
#define HDIM   64
#define NE     8
#define HIDD   4096
#define EPSV   1e-5f
#define KT     32       // attention kv-tile

typedef __attribute__((ext_vector_type(8))) short bf16x8;
typedef __attribute__((ext_vector_type(4))) float f32x4;

__device__ __forceinline__ short f2b(float x){
  __hip_bfloat16 h = __float2bfloat16(x);
  return *reinterpret_cast<short*>(&h);
}
__device__ __forceinline__ float b2f(short s){
  __hip_bfloat16 h = *reinterpret_cast<__hip_bfloat16*>(&s);
  return __bfloat162float(h);
}
// 3-piece bf16 split: x ~= a+b+c to ~2^-26 rel
__device__ __forceinline__ void split3(float x, short& a, short& b, short& c){
  a = f2b(x);
  float r1 = x - b2f(a);
  b = f2b(r1);
  float r2 = r1 - b2f(b);
  c = f2b(r2);
}

// ---------------- transpose fp32 [R][C] -> bf16 [C][R] (expert weights) ----------------
__global__ __launch_bounds__(256) void transpose_conv_kernel(
    const float* __restrict__ in, short* __restrict__ out,
    int R, int C, long inb, long outb)
{
  __shared__ float tile[32][33];
  in  += (size_t)blockIdx.z * inb;
  out += (size_t)blockIdx.z * outb;
  int c0 = blockIdx.x*32, r0 = blockIdx.y*32;
  int tx = threadIdx.x & 31, ty = threadIdx.x >> 5;
  #pragma unroll
  for (int i=0;i<4;i++)
    tile[ty+i*8][tx] = in[(size_t)(r0+ty+i*8)*C + c0+tx];
  __syncthreads();
  #pragma unroll
  for (int i=0;i<4;i++)
    out[(size_t)(c0+ty+i*8)*R + r0+tx] = f2b(tile[tx][ty+i*8]);
}

// ---------------- transpose fp32 [R][C] -> 3 bf16 planes [C+rowOff][outLD=R] ----------------
__global__ __launch_bounds__(256) void transpose_split3_kernel(
    const float* __restrict__ in, short* __restrict__ o1, short* __restrict__ o2,
    short* __restrict__ o3, int R, int C, int rowOff, int outLD)
{
  __shared__ float tile[32][33];
  int c0 = blockIdx.x*32, r0 = blockIdx.y*32;
  int tx = threadIdx.x & 31, ty = threadIdx.x >> 5;
  #pragma unroll
  for (int i=0;i<4;i++)
    tile[ty+i*8][tx] = in[(size_t)(r0+ty+i*8)*C + c0+tx];
  __syncthreads();
  #pragma unroll
  for (int i=0;i<4;i++){
    float v = tile[tx][ty+i*8];
    short a,b,c; split3(v,a,b,c);
    size_t idx = (size_t)(c0+ty+i*8+rowOff)*outLD + r0+tx;
    o1[idx]=a; o2[idx]=b; o3[idx]=c;
  }
}

// ---------------- rmsnorm(x)*g -> 3 bf16 planes ----------------
__global__ __launch_bounds__(256) void rms_split3_kernel(
    const float* __restrict__ x, const float* __restrict__ g,
    short* __restrict__ o1, short* __restrict__ o2, short* __restrict__ o3)
{
  int row = blockIdx.x, tid = threadIdx.x;
  const float4* xr = (const float4*)(x + (size_t)row*DMODEL);
  float4 v = xr[tid];
  float ss = v.x*v.x + v.y*v.y + v.z*v.z + v.w*v.w;
  #pragma unroll
  for (int off=32; off; off>>=1) ss += __shfl_down(ss, off);
  __shared__ float red[4];
  if ((tid&63)==0) red[tid>>6] = ss;
  __syncthreads();
  float rs = rsqrtf((red[0]+red[1]+red[2]+red[3])*(1.f/1024.f) + EPSV);
  float4 gv = ((const float4*)g)[tid];
  float o[4] = {v.x*rs*gv.x, v.y*rs*gv.y, v.z*rs*gv.z, v.w*rs*gv.w};
  short4 s1,s2,s3;
  split3(o[0], s1.x, s2.x, s3.x);
  split3(o[1], s1.y, s2.y, s3.y);
  split3(o[2], s1.z, s2.z, s3.z);
  split3(o[3], s1.w, s2.w, s3.w);
  size_t base = (size_t)row*DMODEL + tid*4;
  *(short4*)(o1+base) = s1; *(short4*)(o2+base) = s2; *(short4*)(o3+base) = s3;
}

// ---------------- flat fp32 -> 3 bf16 planes ----------------
__global__ void split3_flat_kernel(const float* __restrict__ in,
    short* __restrict__ o1, short* __restrict__ o2, short* __restrict__ o3, int n4)
{
  int i = blockIdx.x*256 + threadIdx.x;
  if (i >= n4) return;
  float4 v = ((const float4*)in)[i];
  short4 s1,s2,s3;
  split3(v.x, s1.x, s2.x, s3.x);
  split3(v.y, s1.y, s2.y, s3.y);
  split3(v.z, s1.z, s2.z, s3.z);
  split3(v.w, s1.w, s2.w, s3.w);
  ((short4*)o1)[i]=s1; ((short4*)o2)[i]=s2; ((short4*)o3)[i]=s3;
}

// ---------------- V^T build: qkv fp32 [4096][1152] -> vt planes [2][64][2048] ----------------
__global__ __launch_bounds__(256) void vtrans_split3_kernel(
    const float* __restrict__ qkv,
    short* __restrict__ o1, short* __restrict__ o2, short* __restrict__ o3)
{
  __shared__ float tile[32][33];
  int s0 = blockIdx.x*32, d0 = blockIdx.y*32, b = blockIdx.z;
  int tx = threadIdx.x & 31, ty = threadIdx.x >> 5;
  #pragma unroll
  for (int i=0;i<4;i++)
    tile[ty+i*8][tx] = qkv[(size_t)(b*SEQL + s0+ty+i*8)*QKVW + DMODEL+HDIM + d0+tx];
  __syncthreads();
  #pragma unroll
  for (int i=0;i<4;i++){
    float v = tile[tx][ty+i*8];   // [s=tx][d=ty+i*8]
    short a,bs,c; split3(v,a,bs,c);
    size_t idx = (size_t)(b*HDIM + d0+ty+i*8)*SEQL + s0+tx;
    o1[idx]=a; o2[idx]=bs; o3[idx]=c;
  }
}

// ---------------- fp32-accurate GEMM via 6-pass bf16x3 MFMA ----------------
// C[M][N] = A @ B^T ; A planes [M][K], B planes [N][K]. 128x128 tile, BK=32.
__global__ __launch_bounds__(256) void gemm_bf16x3_kernel(
    const short* __restrict__ a1, const short* __restrict__ a2, const short* __restrict__ a3,
    const short* __restrict__ b1, const short* __restrict__ b2, const short* __restrict__ b3,
    float* __restrict__ C, int K, int ldc)
{
  __shared__ short lsA[3][128*40];
  __shared__ short lsB[3][128*40];
  int m0 = blockIdx.y*128, n0 = blockIdx.x*128;
  int tid = threadIdx.x, wave = tid>>6, lane = tid&63;
  int g = lane>>4, li = lane&15;
  int wm = (wave>>1)*64, wn = (wave&1)*64;
  const short* Ap[3] = {a1,a2,a3};
  const short* Bp[3] = {b1,b2,b3};
  f32x4 acc[4][4] = {};
  for (int k0=0; k0<K; k0+=32){
    #pragma unroll
    for (int p=0;p<3;p++){
      #pragma unroll
      for (int i=0;i<2;i++){
        int c = tid + 256*i;
        int row = c>>2, col = (c&3)*8;
        *(bf16x8*)&lsA[p][row*40+col] = *(const bf16x8*)(Ap[p] + (size_t)(m0+row)*K + k0+col);
        *(bf16x8*)&lsB[p][row*40+col] = *(const bf16x8*)(Bp[p] + (size_t)(n0+row)*K + k0+col);
      }
    }
    __syncthreads();
    #pragma unroll
    for (int i=0;i<3;i++){
      bf16x8 af[4];
      #pragma unroll
      for (int m=0;m<4;m++) af[m] = *(bf16x8*)&lsA[i][(wm+m*16+li)*40 + g*8];
      #pragma unroll
      for (int j=0;j<3-i;j++){
        #pragma unroll
        for (int n=0;n<4;n++){
          bf16x8 bfr = *(bf16x8*)&lsB[j][(wn+n*16+li)*40 + g*8];
          #pragma unroll
          for (int m=0;m<4;m++)
            acc[m][n] = __builtin_amdgcn_mfma_f32_16x16x32_bf16(af[m], bfr, acc[m][n], 0,0,0);
        }
      }
    }
    __syncthreads();
  }
  #pragma unroll
  for (int m=0;m<4;m++){
    int lr0 = wm + m*16 + g*4;
    #pragma unroll
    for (int n=0;n<4;n++){
      int col = n0 + wn + n*16 + li;
      #pragma unroll
      for (int r=0;r<4;r++)
        C[(size_t)(m0+lr0+r)*ldc + col] = acc[m][n][r];
    }
  }
}

// ---------------- flash attention, bf16x3 6-pass MFMA, swapped QK^T ----------------
// grid (16 qtiles of 128, 16 heads, 2 batch), 256 thr (4 waves x 32 q-rows)
__global__ __launch_bounds__(256) void attn_bf16x3_kernel(
    const short* __restrict__ q1, const short* __restrict__ q2, const short* __restrict__ q3,
    const short* __restrict__ v1, const short* __restrict__ v2, const short* __restrict__ v3,
    short* __restrict__ o1, short* __restrict__ o2, short* __restrict__ o3)
{
  __shared__ short Qs[128*200];   // [q][plane*64+d]
  __shared__ short Ks[32*200];    // [kv][plane*64+d]
  __shared__ short Vs[64*104];    // [d][plane*32+kv]
  int qt = blockIdx.x, h = blockIdx.y, b = blockIdx.z;
  int tid = threadIdx.x, wave = tid>>6, lane = tid&63;
  int g = lane>>4, li = lane&15;
  size_t qbase = (size_t)b*SEQL + qt*128;
  const short* qsrc[3] = {q1,q2,q3};
  const short* vsrc[3] = {v1,v2,v3};
  #pragma unroll
  for (int i=0;i<12;i++){
    int c = tid + 256*i;            // 128 rows * 24 chunks
    int row = c/24, sub = c - row*24;
    int p = sub>>3, d = (sub&7)*8;
    *(bf16x8*)&Qs[row*200 + p*64 + d] =
        *(const bf16x8*)(qsrc[p] + (qbase+row)*QKVW + h*HDIM + d);
  }
  float m_run[2] = {-1e30f,-1e30f}, l_run[2] = {0.f,0.f};
  f32x4 acc_o[4][2] = {};
  int src1 = (((2*g)&3)<<4) + li;
  int src2 = (((2*g+1)&3)<<4) + li;
  bool hi_half = (g>=2);

  for (int kvt=0; kvt<SEQL/KT; kvt++){
    __syncthreads();
    #pragma unroll
    for (int i=0;i<3;i++){
      int c = tid + 256*i;
      { // K: 32 rows * 24 chunks
        int row = c/24, sub = c - row*24;
        int p = sub>>3, d = (sub&7)*8;
        *(bf16x8*)&Ks[row*200 + p*64 + d] =
          *(const bf16x8*)(qsrc[p] + ((size_t)b*SEQL + kvt*KT + row)*QKVW + DMODEL + d);
      }
      { // V^T: 64 rows * 12 chunks
        int row = c/12, sub = c - row*12;
        int p = sub>>2, s8 = (sub&3)*8;
        *(bf16x8*)&Vs[row*104 + p*32 + s8] =
          *(const bf16x8*)(vsrc[p] + ((size_t)b*HDIM + row)*SEQL + kvt*KT + s8);
      }
    }
    __syncthreads();
    // S^T = K . Q^T  (rows kv, cols q)
    f32x4 s_acc[2][2] = {};
    #pragma unroll
    for (int i=0;i<3;i++){
      #pragma unroll
      for (int kk=0;kk<2;kk++){
        bf16x8 af[2];
        #pragma unroll
        for (int mf=0;mf<2;mf++)
          af[mf] = *(bf16x8*)&Ks[(mf*16+li)*200 + i*64 + kk*32 + g*8];
        #pragma unroll
        for (int j=0;j<3-i;j++){
          #pragma unroll
          for (int nf=0;nf<2;nf++){
            bf16x8 bfr = *(bf16x8*)&Qs[(wave*32+nf*16+li)*200 + j*64 + kk*32 + g*8];
            #pragma unroll
            for (int mf=0;mf<2;mf++)
              s_acc[mf][nf] = __builtin_amdgcn_mfma_f32_16x16x32_bf16(af[mf], bfr, s_acc[mf][nf], 0,0,0);
          }
        }
      }
    }
    // online softmax (per q-col; kv spread in-lane over mf,r and across groups g)
    float p[2][2][4];
    float alf[2];
    #pragma unroll
    for (int nf=0;nf<2;nf++){
      float mx = -1e30f;
      #pragma unroll
      for (int mf=0;mf<2;mf++)
        #pragma unroll
        for (int r=0;r<4;r++) mx = fmaxf(mx, s_acc[mf][nf][r]);
      mx = fmaxf(mx, __shfl_xor(mx,16));
      mx = fmaxf(mx, __shfl_xor(mx,32));
      mx *= 0.125f;
      float mn = fmaxf(m_run[nf], mx);
      float al = expf(m_run[nf]-mn);
      m_run[nf] = mn; alf[nf] = al;
      float rsum = 0.f;
      #pragma unroll
      for (int mf=0;mf<2;mf++)
        #pragma unroll
        for (int r=0;r<4;r++){
          float pv = expf(s_acc[mf][nf][r]*0.125f - mn);
          p[mf][nf][r] = pv; rsum += pv;
        }
      rsum += __shfl_xor(rsum,16);
      rsum += __shfl_xor(rsum,32);
      l_run[nf] = l_run[nf]*al + rsum;
    }
    #pragma unroll
    for (int mfd=0; mfd<4; mfd++)
      #pragma unroll
      for (int nf=0; nf<2; nf++){
        acc_o[mfd][nf][0]*=alf[nf]; acc_o[mfd][nf][1]*=alf[nf];
        acc_o[mfd][nf][2]*=alf[nf]; acc_o[mfd][nf][3]*=alf[nf];
      }
    // gather this lane's B-frag kv-slice (kv = 8g..8g+7) and split to 3 planes
    bf16x8 fp_frag[2][3];
    #pragma unroll
    for (int nf=0;nf<2;nf++){
      float p8[8];
      #pragma unroll
      for (int jj=0;jj<4;jj++){
        float v0 = __shfl(p[0][nf][jj], src1);
        float vv1 = __shfl(p[1][nf][jj], src1);
        p8[jj] = hi_half ? vv1 : v0;
        float w0 = __shfl(p[0][nf][jj], src2);
        float w1 = __shfl(p[1][nf][jj], src2);
        p8[4+jj] = hi_half ? w1 : w0;
      }
      #pragma unroll
      for (int jj=0;jj<8;jj++){
        short xa,xb,xc; split3(p8[jj], xa,xb,xc);
        fp_frag[nf][0][jj]=xa; fp_frag[nf][1][jj]=xb; fp_frag[nf][2][jj]=xc;
      }
    }
    // O^T += V^T . P   (rows d, cols q)
    #pragma unroll
    for (int vj=0;vj<3;vj++){
      bf16x8 av[4];
      #pragma unroll
      for (int mfd=0;mfd<4;mfd++)
        av[mfd] = *(bf16x8*)&Vs[(mfd*16+li)*104 + vj*32 + g*8];
      #pragma unroll
      for (int pi=0; pi<3-vj; pi++)
        #pragma unroll
        for (int mfd=0;mfd<4;mfd++)
          #pragma unroll
          for (int nf=0;nf<2;nf++)
            acc_o[mfd][nf] = __builtin_amdgcn_mfma_f32_16x16x32_bf16(av[mfd], fp_frag[nf][pi], acc_o[mfd][nf], 0,0,0);
    }
  }
  // epilogue: normalize, split3, write attn planes [token][1024]
  #pragma unroll
  for (int nf=0;nf<2;nf++){
    float inv = 1.f/l_run[nf];
    size_t q = qbase + wave*32 + nf*16 + li;
    #pragma unroll
    for (int mfd=0;mfd<4;mfd++){
      int d0 = mfd*16 + g*4;
      short4 sa,sb,sc;
      float v0 = acc_o[mfd][nf][0]*inv, v1 = acc_o[mfd][nf][1]*inv;
      float v2 = acc_o[mfd][nf][2]*inv, v3 = acc_o[mfd][nf][3]*inv;
      split3(v0, sa.x, sb.x, sc.x);
      split3(v1, sa.y, sb.y, sc.y);
      split3(v2, sa.z, sb.z, sc.z);
      split3(v3, sa.w, sb.w, sc.w);
      size_t base = q*DMODEL + h*HDIM + d0;
      *(short4*)(o1+base)=sa; *(short4*)(o2+base)=sb; *(short4*)(o3+base)=sc;
    }
  }
}

// ---------------- x2 = x + rmsnorm(ao)*g_post ; h = bf16(rmsnorm(x2)*g_pre) ----------------
__global__ __launch_bounds__(256) void attnres_kernel(
    const float* __restrict__ x, const float* __restrict__ ao,
    const float* __restrict__ gpost, const float* __restrict__ gpre,
    float* __restrict__ x2, short* __restrict__ h)
{
  int row = blockIdx.x, tid = threadIdx.x;
  float4 a  = ((const float4*)(ao + (size_t)row*DMODEL))[tid];
  float4 xv = ((const float4*)(x  + (size_t)row*DMODEL))[tid];
  float ss = a.x*a.x + a.y*a.y + a.z*a.z + a.w*a.w;
  #pragma unroll
  for (int off=32; off; off>>=1) ss += __shfl_down(ss, off);
  __shared__ float red[4];
  if ((tid&63)==0) red[tid>>6] = ss;
  __syncthreads();
  float rs1 = rsqrtf((red[0]+red[1]+red[2]+red[3])*(1.f/1024.f) + EPSV);
  float4 gp = ((const float4*)gpost)[tid];
  float4 o;
  o.x = xv.x + a.x*rs1*gp.x; o.y = xv.y + a.y*rs1*gp.y;
  o.z = xv.z + a.z*rs1*gp.z; o.w = xv.w + a.w*rs1*gp.w;
  ((float4*)(x2 + (size_t)row*DMODEL))[tid] = o;
  float s2 = o.x*o.x + o.y*o.y + o.z*o.z + o.w*o.w;
  __syncthreads();
  #pragma unroll
  for (int off=32; off; off>>=1) s2 += __shfl_down(s2, off);
  if ((tid&63)==0) red[tid>>6] = s2;
  __syncthreads();
  float rs2 = rsqrtf((red[0]+red[1]+red[2]+red[3])*(1.f/1024.f) + EPSV);
  float4 gm = ((const float4*)gpre)[tid];
  short4 hs;
  hs.x = f2b(o.x*rs2*gm.x); hs.y = f2b(o.y*rs2*gm.y);
  hs.z = f2b(o.z*rs2*gm.z); hs.w = f2b(o.w*rs2*gm.w);
  *(short4*)(h + (size_t)row*DMODEL + tid*4) = hs;
}

// ---------------- router ----------------
__global__ __launch_bounds__(64) void router_kernel(
    const float* __restrict__ x2, const float* __restrict__ g, const float* __restrict__ Wg,
    float* __restrict__ probs_out, int* __restrict__ tok_list, float* __restrict__ w_list,
    int* __restrict__ counts)
{
  int t = blockIdx.x, lane = threadIdx.x;
  const float4* xr = (const float4*)(x2 + (size_t)t*DMODEL);
  float4 v[4]; float ss = 0.f;
  #pragma unroll
  for (int i=0;i<4;i++){ v[i] = xr[lane + 64*i];
    ss += v[i].x*v[i].x + v[i].y*v[i].y + v[i].z*v[i].z + v[i].w*v[i].w; }
  #pragma unroll
  for (int off=32; off; off>>=1) ss += __shfl_xor(ss, off);
  float rs = rsqrtf(ss*(1.f/1024.f) + EPSV);
  float le[8] = {0,0,0,0,0,0,0,0};
  #pragma unroll
  for (int i=0;i<4;i++){
    int jb = (lane + 64*i)*4;
    float hv[4] = {v[i].x, v[i].y, v[i].z, v[i].w};
    #pragma unroll
    for (int c=0;c<4;c++){
      float hj = hv[c]*rs*g[jb+c];
      const float* wrow = Wg + (size_t)(jb+c)*NE;
      #pragma unroll
      for (int ee=0;ee<8;ee++) le[ee] += hj*wrow[ee];
    }
  }
  #pragma unroll
  for (int ee=0;ee<8;ee++)
    #pragma unroll
    for (int off=32; off; off>>=1) le[ee] += __shfl_xor(le[ee], off);
  float mx = le[0];
  #pragma unroll
  for (int ee=1;ee<8;ee++) mx = fmaxf(mx, le[ee]);
  float p[8], s = 0.f;
  #pragma unroll
  for (int ee=0;ee<8;ee++){ p[ee] = expf(le[ee]-mx); s += p[ee]; }
  float inv = 1.f/s;
  #pragma unroll
  for (int ee=0;ee<8;ee++) p[ee] *= inv;
  if (lane < 8) probs_out[(size_t)t*NE + lane] = p[lane];
  if (lane == 0){
    int i1 = 0;
    #pragma unroll
    for (int ee=1;ee<8;ee++) if (p[ee] > p[i1]) i1 = ee;
    int i2 = (i1==0) ? 1 : 0;
    #pragma unroll
    for (int ee=0;ee<8;ee++) if (ee != i1 && p[ee] > p[i2]) i2 = ee;
    int pos = atomicAdd(&counts[i1], 1);
    tok_list[i1*NTOK+pos] = t; w_list[i1*NTOK+pos] = p[i1];
    pos = atomicAdd(&counts[i2], 1);
    tok_list[i2*NTOK+pos] = t; w_list[i2*NTOK+pos] = p[i2];
  }
}

__global__ void prefix_kernel(const int* __restrict__ counts, int* __restrict__ bases){
  if (threadIdx.x == 0){
    int a = 0;
    for (int ee=0;ee<8;ee++){ bases[ee] = a; a += counts[ee]; }
  }
}

// ---------------- MoE grouped GEMM1 ----------------
__global__ __launch_bounds__(256) void moe_gemm1_kernel(
    const short* __restrict__ h, const short* __restrict__ we1t,
    const int* __restrict__ tok_list, const int* __restrict__ counts,
    const int* __restrict__ bases, short* __restrict__ mid)
{
  int e = blockIdx.z;
  int cnt = counts[e];
  int m0 = blockIdx.y*128, n0 = blockIdx.x*128;
  if (m0 >= cnt) return;
  int base = bases[e];
  const short* Bt = we1t + (size_t)e*HIDD*DMODEL;
  const int* tl = tok_list + e*NTOK;
  __shared__ short lsA[128*40];
  __shared__ short lsB[128*40];
  int tid = threadIdx.x, wave = tid>>6, lane = tid&63;
  int wm = (wave>>1)*64, wn = (wave&1)*64;
  const short* aptr[2]; const short* bptr[2];
  #pragma unroll
  for (int i=0;i<2;i++){
    int c = tid + 256*i; int row = c>>2;
    int rr = min(m0+row, cnt-1);
    aptr[i] = h + (size_t)tl[rr]*DMODEL;
    bptr[i] = Bt + (size_t)(n0+row)*DMODEL;
  }
  f32x4 acc[4][4] = {};
  for (int k0=0; k0<DMODEL; k0+=32){
    #pragma unroll
    for (int i=0;i<2;i++){
      int c = tid + 256*i; int row = c>>2, col = (c&3)*8;
      *(bf16x8*)&lsA[row*40+col] = *(const bf16x8*)(aptr[i]+k0+col);
      *(bf16x8*)&lsB[row*40+col] = *(const bf16x8*)(bptr[i]+k0+col);
    }
    __syncthreads();
    bf16x8 af[4], bfr[4];
    #pragma unroll
    for (int m=0;m<4;m++) af[m] = *(bf16x8*)&lsA[(wm+m*16+(lane&15))*40 + (lane>>4)*8];
    #pragma unroll
    for (int n=0;n<4;n++) bfr[n] = *(bf16x8*)&lsB[(wn+n*16+(lane&15))*40 + (lane>>4)*8];
    #pragma unroll
    for (int m=0;m<4;m++)
      #pragma unroll
      for (int n=0;n<4;n++)
        acc[m][n] = __builtin_amdgcn_mfma_f32_16x16x32_bf16(af[m], bfr[n], acc[m][n], 0,0,0);
    __syncthreads();
  }
  #pragma unroll
  for (int m=0;m<4;m++){
    int lr0 = wm + m*16 + ((lane>>4)<<2);
    #pragma unroll
    for (int n=0;n<4;n++){
      int col = n0 + wn + n*16 + (lane&15);
      #pragma unroll
      for (int r=0;r<4;r++){
        int gr = m0 + lr0 + r;
        if (gr < cnt){
          float tval = acc[m][n][r];
          float ge = 0.5f*tval*(1.f + tanhf(0.7978845608f*(tval + 0.044715f*tval*tval*tval)));
          mid[(size_t)(base+gr)*HIDD + col] = f2b(ge);
        }
      }
    }
  }
}

// ---------------- MoE grouped GEMM2 ----------------
__global__ __launch_bounds__(256) void moe_gemm2_kernel(
    const short* __restrict__ mid, const short* __restrict__ we2t,
    const int* __restrict__ tok_list, const float* __restrict__ w_list,
    const int* __restrict__ counts, const int* __restrict__ bases,
    float* __restrict__ moe_out)
{
  int e = blockIdx.z;
  int cnt = counts[e];
  int m0 = blockIdx.y*128, n0 = blockIdx.x*128;
  if (m0 >= cnt) return;
  int base = bases[e];
  const short* A  = mid + (size_t)base*HIDD;
  const short* Bt = we2t + (size_t)e*DMODEL*HIDD;
  const int* tl = tok_list + e*NTOK;
  const float* wl = w_list + e*NTOK;
  __shared__ short lsA[128*40];
  __shared__ short lsB[128*40];
  int tid = threadIdx.x, wave = tid>>6, lane = tid&63;
  int wm = (wave>>1)*64, wn = (wave&1)*64;
  const short* aptr[2]; const short* bptr[2];
  #pragma unroll
  for (int i=0;i<2;i++){
    int c = tid + 256*i; int row = c>>2;
    int rr = min(m0+row, cnt-1);
    aptr[i] = A + (size_t)rr*HIDD;
    bptr[i] = Bt + (size_t)(n0+row)*HIDD;
  }
  f32x4 acc[4][4] = {};
  for (int k0=0; k0<HIDD; k0+=32){
    #pragma unroll
    for (int i=0;i<2;i++){
      int c = tid + 256*i; int row = c>>2, col = (c&3)*8;
      *(bf16x8*)&lsA[row*40+col] = *(const bf16x8*)(aptr[i]+k0+col);
      *(bf16x8*)&lsB[row*40+col] = *(const bf16x8*)(bptr[i]+k0+col);
    }
    __syncthreads();
    bf16x8 af[4], bfr[4];
    #pragma unroll
    for (int m=0;m<4;m++) af[m] = *(bf16x8*)&lsA[(wm+m*16+(lane&15))*40 + (lane>>4)*8];
    #pragma unroll
    for (int n=0;n<4;n++) bfr[n] = *(bf16x8*)&lsB[(wn+n*16+(lane&15))*40 + (lane>>4)*8];
    #pragma unroll
    for (int m=0;m<4;m++)
      #pragma unroll
      for (int n=0;n<4;n++)
        acc[m][n] = __builtin_amdgcn_mfma_f32_16x16x32_bf16(af[m], bfr[n], acc[m][n], 0,0,0);
    __syncthreads();
  }
  #pragma unroll
  for (int m=0;m<4;m++){
    int lr0 = wm + m*16 + ((lane>>4)<<2);
    #pragma unroll
    for (int n=0;n<4;n++){
      int col = n0 + wn + n*16 + (lane&15);
      #pragma unroll
      for (int r=0;r<4;r++){
        int gr = m0 + lr0 + r;
        if (gr < cnt)
          atomicAdd(&moe_out[(size_t)tl[gr]*DMODEL + col], wl[gr]*acc[m][n][r]);
      }
    }
  }
}

// ---------------- out = x2 + rmsnorm(moe)*g_post_moe ----------------
__global__ __launch_bounds__(256) void final_kernel(
    const float* __restrict__ x2, const float* __restrict__ moe,
    const float* __restrict__ g, float* __restrict__ out)
{
  int row = blockIdx.x, tid = threadIdx.x;
  float4 mv = ((const float4*)(moe + (size_t)row*DMODEL))[tid];
  float4 xv = ((const float4*)(x2  + (size_t)row*DMODEL))[tid];
  float ss = mv.x*mv.x + mv.y*mv.y + mv.z*mv.z + mv.w*mv.w;
  #pragma unroll
  for (int off=32; off; off>>=1) ss += __shfl_down(ss, off);
  __shared__ float red[4];
  if ((tid&63)==0) red[tid>>6] = ss;
  __syncthreads();
  float rs = rsqrtf((red[0]+red[1]+red[2]+red[3])*(1.f/1024.f) + EPSV);
  float4 gv = ((const float4*)g)[tid];
  float4 o;
  o.x = xv.x + mv.x*rs*gv.x; o.y = xv.y + mv.y*rs*gv.y;
  o.z = xv.z + mv.z*rs*gv.z; o.w = xv.w + mv.w*rs*gv.w;
  ((float4*)(out + (size_t)row*DMODEL))[tid] = o;
}

extern "C" void kernel_launch(void* const* d_in, const int* in_sizes, int n_in,
                              void* d_out, int out_size, void* d_ws, size_t ws_size,
                              hipStream_t stream) {
  (void)in_sizes; (void)n_in; (void)out_size; (void)ws_size;
  const float* x          = (const float*)d_in[0];
  const float* g_pre_mqa  = (const float*)d_in[1];
  const float* g_post_mqa = (const float*)d_in[2];
  const float* g_pre_moe  = (const float*)d_in[3];
  const float* g_post_moe = (const float*)d_in[4];
  const float* Wq         = (const float*)d_in[5];
  const float* Wk         = (const float*)d_in[6];
  const float* Wv         = (const float*)d_in[7];
  const float* Wo         = (const float*)d_in[8];
  const float* Wg         = (const float*)d_in[9];
  const float* We1        = (const float*)d_in[10];
  const float* We2        = (const float*)d_in[11];

  float* out_x = (float*)d_out;
  float* out_probs = out_x + (size_t)NTOK*DMODEL;

  char* p = (char*)d_ws;
  size_t off = 0;
  auto alloc = [&](size_t bytes)->char*{
    char* r = p + off; off = (off + bytes + 255) & ~(size_t)255; return r; };

  short* we1t = (short*)alloc((size_t)NE*HIDD*DMODEL*2);       // 64M
  short* we2t = (short*)alloc((size_t)NE*DMODEL*HIDD*2);       // 64M
  short* mid  = (short*)alloc((size_t)2*NTOK*HIDD*2);          // 64M

  // region: xn1 planes (3x8M), later ao fp32 (16M)
  char* regA = alloc((size_t)3*NTOK*DMODEL*2);
  short* xn1p1 = (short*)regA;
  short* xn1p2 = (short*)(regA + (size_t)NTOK*DMODEL*2);
  short* xn1p3 = (short*)(regA + (size_t)2*NTOK*DMODEL*2);
  float* ao    = (float*)regA;

  short* wqkvT1 = (short*)alloc((size_t)QKVW*DMODEL*2);
  short* wqkvT2 = (short*)alloc((size_t)QKVW*DMODEL*2);
  short* wqkvT3 = (short*)alloc((size_t)QKVW*DMODEL*2);
  short* woT1   = (short*)alloc((size_t)DMODEL*DMODEL*2);
  short* woT2   = (short*)alloc((size_t)DMODEL*DMODEL*2);
  short* woT3   = (short*)alloc((size_t)DMODEL*DMODEL*2);

  // region: qkv fp32 (18.9M), later attn planes (3x8M)
  char* regB = alloc((size_t)3*NTOK*DMODEL*2);
  float* qkv = (float*)regB;
  short* attnp1 = (short*)regB;
  short* attnp2 = (short*)(regB + (size_t)NTOK*DMODEL*2);
  short* attnp3 = (short*)(regB + (size_t)2*NTOK*DMODEL*2);

  // region: qkvs planes (3x9.4M), later moe (16.8M) + hbuf (8.4M)
  char* regC = alloc((size_t)3*NTOK*QKVW*2);
  short* qkvs1 = (short*)regC;
  short* qkvs2 = (short*)(regC + (size_t)NTOK*QKVW*2);
  short* qkvs3 = (short*)(regC + (size_t)2*NTOK*QKVW*2);
  float* moe   = (float*)regC;
  short* hbuf  = (short*)(regC + (size_t)NTOK*DMODEL*4);

  short* vt1 = (short*)alloc((size_t)2*HDIM*SEQL*2);
  short* vt2 = (short*)alloc((size_t)2*HDIM*SEQL*2);
  short* vt3 = (short*)alloc((size_t)2*HDIM*SEQL*2);
  float* x2  = (float*)alloc((size_t)NTOK*DMODEL*4);
  int*   tok_l  = (int*)  alloc((size_t)NE*NTOK*4);
  float* w_l    = (float*)alloc((size_t)NE*NTOK*4);
  int*   counts = (int*)  alloc(256);
  int*   bases  = (int*)  alloc(256);

  // ---- weights prep ----
  transpose_conv_kernel<<<dim3(HIDD/32, DMODEL/32, NE), 256, 0, stream>>>(
      We1, we1t, DMODEL, HIDD, (long)DMODEL*HIDD, (long)HIDD*DMODEL);
  transpose_conv_kernel<<<dim3(DMODEL/32, HIDD/32, NE), 256, 0, stream>>>(
      We2, we2t, HIDD, DMODEL, (long)HIDD*DMODEL, (long)DMODEL*HIDD);
  transpose_split3_kernel<<<dim3(DMODEL/32, DMODEL/32), 256, 0, stream>>>(
      Wq, wqkvT1, wqkvT2, wqkvT3, DMODEL, DMODEL, 0, DMODEL);
  transpose_split3_kernel<<<dim3(HDIM/32, DMODEL/32), 256, 0, stream>>>(
      Wk, wqkvT1, wqkvT2, wqkvT3, DMODEL, HDIM, DMODEL, DMODEL);
  transpose_split3_kernel<<<dim3(HDIM/32, DMODEL/32), 256, 0, stream>>>(
      Wv, wqkvT1, wqkvT2, wqkvT3, DMODEL, HDIM, DMODEL+HDIM, DMODEL);
  transpose_split3_kernel<<<dim3(DMODEL/32, DMODEL/32), 256, 0, stream>>>(
      Wo, woT1, woT2, woT3, DMODEL, DMODEL, 0, DMODEL);

  // ---- pre-router chain (fp32-accurate via bf16x3 6-pass MFMA) ----
  rms_split3_kernel<<<NTOK, 256, 0, stream>>>(x, g_pre_mqa, xn1p1, xn1p2, xn1p3);
  gemm_bf16x3_kernel<<<dim3(QKVW/128, NTOK/128), 256, 0, stream>>>(
      xn1p1, xn1p2, xn1p3, wqkvT1, wqkvT2, wqkvT3, qkv, DMODEL, QKVW);
  split3_flat_kernel<<<(NTOK*QKVW/4 + 255)/256, 256, 0, stream>>>(
      qkv, qkvs1, qkvs2, qkvs3, NTOK*QKVW/4);
  vtrans_split3_kernel<<<dim3(SEQL/32, HDIM/32, 2), 256, 0, stream>>>(qkv, vt1, vt2, vt3);
  attn_bf16x3_kernel<<<dim3(SEQL/128, NH, 2), 256, 0, stream>>>(
      qkvs1, qkvs2, qkvs3, vt1, vt2, vt3, attnp1, attnp2, attnp3);
  gemm_bf16x3_kernel<<<dim3(DMODEL/128, NTOK/128), 256, 0, stream>>>(
      attnp1, attnp2, attnp3, woT1, woT2, woT3, ao, DMODEL, DMODEL);
  attnres_kernel<<<NTOK, 256, 0, stream>>>(x, ao, g_post_mqa, g_pre_moe, x2, hbuf);

  // ---- router + grouped MoE (bf16 MFMA) ----
  hipMemsetAsync(moe, 0, (size_t)NTOK*DMODEL*4, stream);
  hipMemsetAsync(counts, 0, 32, stream);
  router_kernel<<<NTOK, 64, 0, stream>>>(x2, g_pre_moe, Wg, out_probs, tok_l, w_l, counts);
  prefix_kernel<<<1, 64, 0, stream>>>(counts, bases);
  moe_gemm1_kernel<<<dim3(HIDD/128, NTOK/128, NE), 256, 0, stream>>>(
      hbuf, we1t, tok_l, counts, bases, mid);
  moe_gemm2_kernel<<<dim3(DMODEL/128, NTOK/128, NE), 256, 0, stream>>>(
      mid, we2t, tok_l, w_l, counts, bases, moe);
  final_kernel<<<NTOK, 256, 0, stream>>>(x2, moe, g_post_moe, out_x);
}

// Round 4
// 1005.606 us; speedup vs baseline: 1.5725x; 1.0291x over previous
//
#include <hip/hip_runtime.h>
#include <hip/hip_bf16.h>
#include <math.h>

#define NTOK   4096
#define DMODEL 1024
#define SEQL   2048
#define QKVW   1152     // 1024 q + 64 k + 64 v
#define NH     16
#define HDIM   64
#define NE     8
#define HIDD   4096
#define EPSV   1e-5f
#define KT     32       // attention kv-tile
#define QB     64       // attention q-tile

// fp16 GEMM scales: activations *2^8, weights *2^12 (keeps split-2 second
// pieces out of fp16-subnormal range); folded out via OUTSCL.
#define ASCL   256.f
#define WSCL   4096.f
#define OUTSCL (1.f/1048576.f)          // 2^-20

typedef __attribute__((ext_vector_type(8))) short bf16x8;
typedef __attribute__((ext_vector_type(8))) _Float16 f16x8;
typedef __attribute__((ext_vector_type(4))) _Float16 f16x4;
typedef __attribute__((ext_vector_type(4))) float f32x4;

__device__ __forceinline__ short f2b(float x){
  __hip_bfloat16 h = __float2bfloat16(x);
  return *reinterpret_cast<short*>(&h);
}
__device__ __forceinline__ float b2f(short s){
  __hip_bfloat16 h = *reinterpret_cast<__hip_bfloat16*>(&s);
  return __bfloat162float(h);
}
// 3-piece bf16 split: x ~= a+b+c to ~2^-26 rel (PROVEN round 2)
__device__ __forceinline__ void split3(float x, short& a, short& b, short& c){
  a = f2b(x);
  float r1 = x - b2f(a);
  b = f2b(r1);
  float r2 = r1 - b2f(b);
  c = f2b(r2);
}
__device__ __forceinline__ void split2h(float x, _Float16& a, _Float16& b){
  a = (_Float16)x;
  b = (_Float16)(x - (float)a);
}

// ---------------- transpose fp32 [R][C] -> bf16 [C][R] (expert weights) ----------------
__global__ __launch_bounds__(256) void transpose_conv_kernel(
    const float* __restrict__ in, short* __restrict__ out,
    int R, int C, long inb, long outb)
{
  __shared__ float tile[32][33];
  in  += (size_t)blockIdx.z * inb;
  out += (size_t)blockIdx.z * outb;
  int c0 = blockIdx.x*32, r0 = blockIdx.y*32;
  int tx = threadIdx.x & 31, ty = threadIdx.x >> 5;
  #pragma unroll
  for (int i=0;i<4;i++)
    tile[ty+i*8][tx] = in[(size_t)(r0+ty+i*8)*C + c0+tx];
  __syncthreads();
  #pragma unroll
  for (int i=0;i<4;i++)
    out[(size_t)(c0+ty+i*8)*R + r0+tx] = f2b(tile[tx][ty+i*8]);
}

// ---------------- transpose fp32 [R][C] -> 2 fp16 planes [C+rowOff][outLD=R], *2^12 ----------------
__global__ __launch_bounds__(256) void transpose_split2f16_kernel(
    const float* __restrict__ in, _Float16* __restrict__ o1, _Float16* __restrict__ o2,
    int R, int C, int rowOff, int outLD)
{
  __shared__ float tile[32][33];
  int c0 = blockIdx.x*32, r0 = blockIdx.y*32;
  int tx = threadIdx.x & 31, ty = threadIdx.x >> 5;
  #pragma unroll
  for (int i=0;i<4;i++)
    tile[ty+i*8][tx] = in[(size_t)(r0+ty+i*8)*C + c0+tx];
  __syncthreads();
  #pragma unroll
  for (int i=0;i<4;i++){
    float v = tile[tx][ty+i*8] * WSCL;
    _Float16 a,b; split2h(v,a,b);
    size_t idx = (size_t)(c0+ty+i*8+rowOff)*outLD + r0+tx;
    o1[idx]=a; o2[idx]=b;
  }
}

// ---------------- rmsnorm(x)*g*2^8 -> 2 fp16 planes ----------------
__global__ __launch_bounds__(256) void rms_split2_kernel(
    const float* __restrict__ x, const float* __restrict__ g,
    _Float16* __restrict__ o1, _Float16* __restrict__ o2)
{
  int row = blockIdx.x, tid = threadIdx.x;
  const float4* xr = (const float4*)(x + (size_t)row*DMODEL);
  float4 v = xr[tid];
  float ss = v.x*v.x + v.y*v.y + v.z*v.z + v.w*v.w;
  #pragma unroll
  for (int off=32; off; off>>=1) ss += __shfl_down(ss, off);
  __shared__ float red[4];
  if ((tid&63)==0) red[tid>>6] = ss;
  __syncthreads();
  float rs = rsqrtf((red[0]+red[1]+red[2]+red[3])*(1.f/1024.f) + EPSV) * ASCL;
  float4 gv = ((const float4*)g)[tid];
  float o[4] = {v.x*rs*gv.x, v.y*rs*gv.y, v.z*rs*gv.z, v.w*rs*gv.w};
  f16x4 s1,s2;
  #pragma unroll
  for (int c=0;c<4;c++){ _Float16 a,b; split2h(o[c],a,b); s1[c]=a; s2[c]=b; }
  size_t base = (size_t)row*DMODEL + tid*4;
  *(f16x4*)(o1+base) = s1; *(f16x4*)(o2+base) = s2;
}

// ---------------- flat fp32 -> 3 bf16 planes (unscaled, for attention) ----------------
__global__ void split3_flat_kernel(const float* __restrict__ in,
    short* __restrict__ o1, short* __restrict__ o2, short* __restrict__ o3, int n4)
{
  int i = blockIdx.x*256 + threadIdx.x;
  if (i >= n4) return;
  float4 v = ((const float4*)in)[i];
  short4 s1,s2,s3;
  split3(v.x, s1.x, s2.x, s3.x);
  split3(v.y, s1.y, s2.y, s3.y);
  split3(v.z, s1.z, s2.z, s3.z);
  split3(v.w, s1.w, s2.w, s3.w);
  ((short4*)o1)[i]=s1; ((short4*)o2)[i]=s2; ((short4*)o3)[i]=s3;
}

// ---------------- V^T build: qkv fp32 [4096][1152] -> vt planes [2][64][2048] ----------------
__global__ __launch_bounds__(256) void vtrans_split3_kernel(
    const float* __restrict__ qkv,
    short* __restrict__ o1, short* __restrict__ o2, short* __restrict__ o3)
{
  __shared__ float tile[32][33];
  int s0 = blockIdx.x*32, d0 = blockIdx.y*32, b = blockIdx.z;
  int tx = threadIdx.x & 31, ty = threadIdx.x >> 5;
  #pragma unroll
  for (int i=0;i<4;i++)
    tile[ty+i*8][tx] = qkv[(size_t)(b*SEQL + s0+ty+i*8)*QKVW + DMODEL+HDIM + d0+tx];
  __syncthreads();
  #pragma unroll
  for (int i=0;i<4;i++){
    float v = tile[tx][ty+i*8];   // [s=tx][d=ty+i*8]
    short a,bs,c; split3(v,a,bs,c);
    size_t idx = (size_t)(b*HDIM + d0+ty+i*8)*SEQL + s0+tx;
    o1[idx]=a; o2[idx]=bs; o3[idx]=c;
  }
}

// ---------------- fp32-accurate GEMM via 3-pass fp16x2 MFMA ----------------
// C[M][N] = (A @ B^T) * outscale ; A planes [M][K], B planes [N][K]. 128x128 tile, BK=32.
// Permutation-robust: A and B fragments both read LDS with the same lane->k
// slot rule, so any internal MFMA k-ordering cancels.
__global__ __launch_bounds__(256) void gemm_f16x2_kernel(
    const _Float16* __restrict__ a1, const _Float16* __restrict__ a2,
    const _Float16* __restrict__ b1, const _Float16* __restrict__ b2,
    float* __restrict__ C, int K, int ldc, float outscale)
{
  __shared__ _Float16 lsA[2][128*40];
  __shared__ _Float16 lsB[2][128*40];
  int m0 = blockIdx.y*128, n0 = blockIdx.x*128;
  int tid = threadIdx.x, wave = tid>>6, lane = tid&63;
  int g = lane>>4, li = lane&15;
  int wm = (wave>>1)*64, wn = (wave&1)*64;
  const _Float16* Ap[2] = {a1,a2};
  const _Float16* Bp[2] = {b1,b2};
  f32x4 acc[4][4] = {};
  for (int k0=0; k0<K; k0+=32){
    #pragma unroll
    for (int p=0;p<2;p++){
      #pragma unroll
      for (int i=0;i<2;i++){
        int c = tid + 256*i;
        int row = c>>2, col = (c&3)*8;
        *(f16x8*)&lsA[p][row*40+col] = *(const f16x8*)(Ap[p] + (size_t)(m0+row)*K + k0+col);
        *(f16x8*)&lsB[p][row*40+col] = *(const f16x8*)(Bp[p] + (size_t)(n0+row)*K + k0+col);
      }
    }
    __syncthreads();
    #pragma unroll
    for (int i=0;i<2;i++){
      f16x8 af[4];
      #pragma unroll
      for (int m=0;m<4;m++) af[m] = *(f16x8*)&lsA[i][(wm+m*16+li)*40 + g*8];
      #pragma unroll
      for (int j=0;j<2-i;j++){
        #pragma unroll
        for (int n=0;n<4;n++){
          f16x8 bfr = *(f16x8*)&lsB[j][(wn+n*16+li)*40 + g*8];
          #pragma unroll
          for (int m=0;m<4;m++)
            acc[m][n] = __builtin_amdgcn_mfma_f32_16x16x32_f16(af[m], bfr, acc[m][n], 0,0,0);
        }
      }
    }
    __syncthreads();
  }
  #pragma unroll
  for (int m=0;m<4;m++){
    int lr0 = wm + m*16 + g*4;
    #pragma unroll
    for (int n=0;n<4;n++){
      int col = n0 + wn + n*16 + li;
      #pragma unroll
      for (int r=0;r<4;r++)
        C[(size_t)(m0+lr0+r)*ldc + col] = acc[m][n][r]*outscale;
    }
  }
}

// ---------------- flash attention, bf16x3 6-pass MFMA (PROVEN), swapped QK^T ----------------
// QB=64: grid (32 qtiles, 16 heads, 2 batch), 256 thr (4 waves x 16 q-rows).
// LDS 51.7KB -> 3 blocks/CU. Epilogue: fp16x2 *2^8 planes (feeds fp16 Wo GEMM).
__global__ __launch_bounds__(256) void attn_bf16x3_kernel(
    const short* __restrict__ q1, const short* __restrict__ q2, const short* __restrict__ q3,
    const short* __restrict__ v1, const short* __restrict__ v2, const short* __restrict__ v3,
    _Float16* __restrict__ o1, _Float16* __restrict__ o2)
{
  __shared__ short Qs[QB*200];    // [q][plane*64+d]
  __shared__ short Ks[32*200];    // [kv][plane*64+d]
  __shared__ short Vs[64*104];    // [d][plane*32+kv]
  int qt = blockIdx.x, h = blockIdx.y, b = blockIdx.z;
  int tid = threadIdx.x, wave = tid>>6, lane = tid&63;
  int g = lane>>4, li = lane&15;
  size_t qbase = (size_t)b*SEQL + qt*QB;
  const short* qsrc[3] = {q1,q2,q3};
  const short* vsrc[3] = {v1,v2,v3};
  #pragma unroll
  for (int i=0;i<6;i++){
    int c = tid + 256*i;            // 64 rows * 24 chunks
    int row = c/24, sub = c - row*24;
    int p = sub>>3, d = (sub&7)*8;
    *(bf16x8*)&Qs[row*200 + p*64 + d] =
        *(const bf16x8*)(qsrc[p] + (qbase+row)*QKVW + h*HDIM + d);
  }
  float m_run = -1e30f, l_run = 0.f;
  f32x4 acc_o[4] = {};
  int src1 = (((2*g)&3)<<4) + li;
  int src2 = (((2*g+1)&3)<<4) + li;
  bool hi_half = (g>=2);

  for (int kvt=0; kvt<SEQL/KT; kvt++){
    __syncthreads();
    #pragma unroll
    for (int i=0;i<3;i++){
      int c = tid + 256*i;
      { // K: 32 rows * 24 chunks
        int row = c/24, sub = c - row*24;
        int p = sub>>3, d = (sub&7)*8;
        *(bf16x8*)&Ks[row*200 + p*64 + d] =
          *(const bf16x8*)(qsrc[p] + ((size_t)b*SEQL + kvt*KT + row)*QKVW + DMODEL + d);
      }
      { // V^T: 64 rows * 12 chunks
        int row = c/12, sub = c - row*12;
        int p = sub>>2, s8 = (sub&3)*8;
        *(bf16x8*)&Vs[row*104 + p*32 + s8] =
          *(const bf16x8*)(vsrc[p] + ((size_t)b*HDIM + row)*SEQL + kvt*KT + s8);
      }
    }
    __syncthreads();
    // S^T = K . Q^T  (rows kv, cols q)
    f32x4 s_acc[2] = {};
    #pragma unroll
    for (int i=0;i<3;i++){
      #pragma unroll
      for (int kk=0;kk<2;kk++){
        bf16x8 af[2];
        #pragma unroll
        for (int mf=0;mf<2;mf++)
          af[mf] = *(bf16x8*)&Ks[(mf*16+li)*200 + i*64 + kk*32 + g*8];
        #pragma unroll
        for (int j=0;j<3-i;j++){
          bf16x8 bfr = *(bf16x8*)&Qs[(wave*16+li)*200 + j*64 + kk*32 + g*8];
          #pragma unroll
          for (int mf=0;mf<2;mf++)
            s_acc[mf] = __builtin_amdgcn_mfma_f32_16x16x32_bf16(af[mf], bfr, s_acc[mf], 0,0,0);
        }
      }
    }
    // online softmax (per q-col; kv spread in-lane over mf,r and across groups g)
    float mx = -1e30f;
    #pragma unroll
    for (int mf=0;mf<2;mf++)
      #pragma unroll
      for (int r=0;r<4;r++) mx = fmaxf(mx, s_acc[mf][r]);
    mx = fmaxf(mx, __shfl_xor(mx,16));
    mx = fmaxf(mx, __shfl_xor(mx,32));
    mx *= 0.125f;
    float mn = fmaxf(m_run, mx);
    float al = __expf(m_run - mn);
    m_run = mn;
    float p[2][4];
    float rsum = 0.f;
    #pragma unroll
    for (int mf=0;mf<2;mf++)
      #pragma unroll
      for (int r=0;r<4;r++){
        float pv = __expf(s_acc[mf][r]*0.125f - mn);
        p[mf][r] = pv; rsum += pv;
      }
    rsum += __shfl_xor(rsum,16);
    rsum += __shfl_xor(rsum,32);
    l_run = l_run*al + rsum;
    #pragma unroll
    for (int mfd=0; mfd<4; mfd++){
      acc_o[mfd][0]*=al; acc_o[mfd][1]*=al;
      acc_o[mfd][2]*=al; acc_o[mfd][3]*=al;
    }
    // gather this lane's B-frag kv-slice (kv = 8g..8g+7), split3 (bf16 mapping PROVEN)
    float p8[8];
    #pragma unroll
    for (int jj=0;jj<4;jj++){
      float v0 = __shfl(p[0][jj], src1);
      float vv1 = __shfl(p[1][jj], src1);
      p8[jj] = hi_half ? vv1 : v0;
      float w0 = __shfl(p[0][jj], src2);
      float w1 = __shfl(p[1][jj], src2);
      p8[4+jj] = hi_half ? w1 : w0;
    }
    bf16x8 fp_frag[3];
    #pragma unroll
    for (int jj=0;jj<8;jj++){
      short xa,xb,xc; split3(p8[jj], xa,xb,xc);
      fp_frag[0][jj]=xa; fp_frag[1][jj]=xb; fp_frag[2][jj]=xc;
    }
    // O^T += V^T . P   (rows d, cols q)
    #pragma unroll
    for (int vj=0;vj<3;vj++){
      bf16x8 av[4];
      #pragma unroll
      for (int mfd=0;mfd<4;mfd++)
        av[mfd] = *(bf16x8*)&Vs[(mfd*16+li)*104 + vj*32 + g*8];
      #pragma unroll
      for (int pi=0; pi<3-vj; pi++)
        #pragma unroll
        for (int mfd=0;mfd<4;mfd++)
          acc_o[mfd] = __builtin_amdgcn_mfma_f32_16x16x32_bf16(av[mfd], fp_frag[pi], acc_o[mfd], 0,0,0);
    }
  }
  // epilogue: attn*2^8, split2 -> fp16 planes [token][1024]
  float inv = ASCL/l_run;
  size_t q = qbase + wave*16 + li;
  #pragma unroll
  for (int mfd=0;mfd<4;mfd++){
    int d0 = mfd*16 + g*4;
    f16x4 sa,sb;
    #pragma unroll
    for (int r=0;r<4;r++){
      _Float16 xa,xb; split2h(acc_o[mfd][r]*inv, xa,xb);
      sa[r]=xa; sb[r]=xb;
    }
    size_t base = q*DMODEL + h*HDIM + d0;
    *(f16x4*)(o1+base)=sa; *(f16x4*)(o2+base)=sb;
  }
}

// ---------------- x2 = x + rmsnorm(ao)*g_post ; h = bf16(rmsnorm(x2)*g_pre) ----------------
__global__ __launch_bounds__(256) void attnres_kernel(
    const float* __restrict__ x, const float* __restrict__ ao,
    const float* __restrict__ gpost, const float* __restrict__ gpre,
    float* __restrict__ x2, short* __restrict__ h)
{
  int row = blockIdx.x, tid = threadIdx.x;
  float4 a  = ((const float4*)(ao + (size_t)row*DMODEL))[tid];
  float4 xv = ((const float4*)(x  + (size_t)row*DMODEL))[tid];
  float ss = a.x*a.x + a.y*a.y + a.z*a.z + a.w*a.w;
  #pragma unroll
  for (int off=32; off; off>>=1) ss += __shfl_down(ss, off);
  __shared__ float red[4];
  if ((tid&63)==0) red[tid>>6] = ss;
  __syncthreads();
  float rs1 = rsqrtf((red[0]+red[1]+red[2]+red[3])*(1.f/1024.f) + EPSV);
  float4 gp = ((const float4*)gpost)[tid];
  float4 o;
  o.x = xv.x + a.x*rs1*gp.x; o.y = xv.y + a.y*rs1*gp.y;
  o.z = xv.z + a.z*rs1*gp.z; o.w = xv.w + a.w*rs1*gp.w;
  ((float4*)(x2 + (size_t)row*DMODEL))[tid] = o;
  float s2 = o.x*o.x + o.y*o.y + o.z*o.z + o.w*o.w;
  __syncthreads();
  #pragma unroll
  for (int off=32; off; off>>=1) s2 += __shfl_down(s2, off);
  if ((tid&63)==0) red[tid>>6] = s2;
  __syncthreads();
  float rs2 = rsqrtf((red[0]+red[1]+red[2]+red[3])*(1.f/1024.f) + EPSV);
  float4 gm = ((const float4*)gpre)[tid];
  short4 hs;
  hs.x = f2b(o.x*rs2*gm.x); hs.y = f2b(o.y*rs2*gm.y);
  hs.z = f2b(o.z*rs2*gm.z); hs.w = f2b(o.w*rs2*gm.w);
  *(short4*)(h + (size_t)row*DMODEL + tid*4) = hs;
}

// ---------------- router ----------------
__global__ __launch_bounds__(64) void router_kernel(
    const float* __restrict__ x2, const float* __restrict__ g, const float* __restrict__ Wg,
    float* __restrict__ probs_out, int* __restrict__ tok_list, float* __restrict__ w_list,
    int* __restrict__ counts)
{
  int t = blockIdx.x, lane = threadIdx.x;
  const float4* xr = (const float4*)(x2 + (size_t)t*DMODEL);
  float4 v[4]; float ss = 0.f;
  #pragma unroll
  for (int i=0;i<4;i++){ v[i] = xr[lane + 64*i];
    ss += v[i].x*v[i].x + v[i].y*v[i].y + v[i].z*v[i].z + v[i].w*v[i].w; }
  #pragma unroll
  for (int off=32; off; off>>=1) ss += __shfl_xor(ss, off);
  float rs = rsqrtf(ss*(1.f/1024.f) + EPSV);
  float le[8] = {0,0,0,0,0,0,0,0};
  #pragma unroll
  for (int i=0;i<4;i++){
    int jb = (lane + 64*i)*4;
    float hv[4] = {v[i].x, v[i].y, v[i].z, v[i].w};
    #pragma unroll
    for (int c=0;c<4;c++){
      float hj = hv[c]*rs*g[jb+c];
      const float* wrow = Wg + (size_t)(jb+c)*NE;
      #pragma unroll
      for (int ee=0;ee<8;ee++) le[ee] += hj*wrow[ee];
    }
  }
  #pragma unroll
  for (int ee=0;ee<8;ee++)
    #pragma unroll
    for (int off=32; off; off>>=1) le[ee] += __shfl_xor(le[ee], off);
  float mx = le[0];
  #pragma unroll
  for (int ee=1;ee<8;ee++) mx = fmaxf(mx, le[ee]);
  float p[8], s = 0.f;
  #pragma unroll
  for (int ee=0;ee<8;ee++){ p[ee] = expf(le[ee]-mx); s += p[ee]; }
  float inv = 1.f/s;
  #pragma unroll
  for (int ee=0;ee<8;ee++) p[ee] *= inv;
  if (lane < 8) probs_out[(size_t)t*NE + lane] = p[lane];
  if (lane == 0){
    int i1 = 0;
    #pragma unroll
    for (int ee=1;ee<8;ee++) if (p[ee] > p[i1]) i1 = ee;
    int i2 = (i1==0) ? 1 : 0;
    #pragma unroll
    for (int ee=0;ee<8;ee++) if (ee != i1 && p[ee] > p[i2]) i2 = ee;
    int pos = atomicAdd(&counts[i1], 1);
    tok_list[i1*NTOK+pos] = t; w_list[i1*NTOK+pos] = p[i1];
    pos = atomicAdd(&counts[i2], 1);
    tok_list[i2*NTOK+pos] = t; w_list[i2*NTOK+pos] = p[i2];
  }
}

__global__ void prefix_kernel(const int* __restrict__ counts, int* __restrict__ bases){
  if (threadIdx.x == 0){
    int a = 0;
    for (int ee=0;ee<8;ee++){ bases[ee] = a; a += counts[ee]; }
  }
}

// ---------------- MoE grouped GEMM1: mid = gelu(h @ We1[e]^T) ----------------
__global__ __launch_bounds__(256) void moe_gemm1_kernel(
    const short* __restrict__ h, const short* __restrict__ we1t,
    const int* __restrict__ tok_list, const int* __restrict__ counts,
    const int* __restrict__ bases, short* __restrict__ mid)
{
  int e = blockIdx.z;
  int cnt = counts[e];
  int m0 = blockIdx.y*128, n0 = blockIdx.x*128;
  if (m0 >= cnt) return;
  int base = bases[e];
  const short* Bt = we1t + (size_t)e*HIDD*DMODEL;
  const int* tl = tok_list + e*NTOK;
  __shared__ short lsA[128*40];
  __shared__ short lsB[128*40];
  int tid = threadIdx.x, wave = tid>>6, lane = tid&63;
  int wm = (wave>>1)*64, wn = (wave&1)*64;
  const short* aptr[2]; const short* bptr[2];
  #pragma unroll
  for (int i=0;i<2;i++){
    int c = tid + 256*i; int row = c>>2;
    int rr = min(m0+row, cnt-1);
    aptr[i] = h + (size_t)tl[rr]*DMODEL;
    bptr[i] = Bt + (size_t)(n0+row)*DMODEL;
  }
  f32x4 acc[4][4] = {};
  for (int k0=0; k0<DMODEL; k0+=32){
    #pragma unroll
    for (int i=0;i<2;i++){
      int c = tid + 256*i; int row = c>>2, col = (c&3)*8;
      *(bf16x8*)&lsA[row*40+col] = *(const bf16x8*)(aptr[i]+k0+col);
      *(bf16x8*)&lsB[row*40+col] = *(const bf16x8*)(bptr[i]+k0+col);
    }
    __syncthreads();
    bf16x8 af[4], bfr[4];
    #pragma unroll
    for (int m=0;m<4;m++) af[m] = *(bf16x8*)&lsA[(wm+m*16+(lane&15))*40 + (lane>>4)*8];
    #pragma unroll
    for (int n=0;n<4;n++) bfr[n] = *(bf16x8*)&lsB[(wn+n*16+(lane&15))*40 + (lane>>4)*8];
    #pragma unroll
    for (int m=0;m<4;m++)
      #pragma unroll
      for (int n=0;n<4;n++)
        acc[m][n] = __builtin_amdgcn_mfma_f32_16x16x32_bf16(af[m], bfr[n], acc[m][n], 0,0,0);
    __syncthreads();
  }
  #pragma unroll
  for (int m=0;m<4;m++){
    int lr0 = wm + m*16 + ((lane>>4)<<2);
    #pragma unroll
    for (int n=0;n<4;n++){
      int col = n0 + wn + n*16 + (lane&15);
      #pragma unroll
      for (int r=0;r<4;r++){
        int gr = m0 + lr0 + r;
        if (gr < cnt){
          float tval = acc[m][n][r];
          // gelu(t) = t * sigmoid(1.59577*(t + 0.044715 t^3))  (exact tanh identity)
          float u = 1.5957691216057308f*(tval + 0.044715f*tval*tval*tval);
          float ge = tval / (1.f + __expf(-u));
          mid[(size_t)(base+gr)*HIDD + col] = f2b(ge);
        }
      }
    }
  }
}

// ---------------- MoE grouped GEMM2: moe_out[tok] += w * (mid @ We2[e]^T) ----------------
__global__ __launch_bounds__(256) void moe_gemm2_kernel(
    const short* __restrict__ mid, const short* __restrict__ we2t,
    const int* __restrict__ tok_list, const float* __restrict__ w_list,
    const int* __restrict__ counts, const int* __restrict__ bases,
    float* __restrict__ moe_out)
{
  int e = blockIdx.z;
  int cnt = counts[e];
  int m0 = blockIdx.y*128, n0 = blockIdx.x*128;
  if (m0 >= cnt) return;
  int base = bases[e];
  const short* A  = mid + (size_t)base*HIDD;
  const short* Bt = we2t + (size_t)e*DMODEL*HIDD;
  const int* tl = tok_list + e*NTOK;
  const float* wl = w_list + e*NTOK;
  __shared__ short lsA[128*40];
  __shared__ short lsB[128*40];
  int tid = threadIdx.x, wave = tid>>6, lane = tid&63;
  int wm = (wave>>1)*64, wn = (wave&1)*64;
  const short* aptr[2]; const short* bptr[2];
  #pragma unroll
  for (int i=0;i<2;i++){
    int c = tid + 256*i; int row = c>>2;
    int rr = min(m0+row, cnt-1);
    aptr[i] = A + (size_t)rr*HIDD;
    bptr[i] = Bt + (size_t)(n0+row)*HIDD;
  }
  f32x4 acc[4][4] = {};
  for (int k0=0; k0<HIDD; k0+=32){
    #pragma unroll
    for (int i=0;i<2;i++){
      int c = tid + 256*i; int row = c>>2, col = (c&3)*8;
      *(bf16x8*)&lsA[row*40+col] = *(const bf16x8*)(aptr[i]+k0+col);
      *(bf16x8*)&lsB[row*40+col] = *(const bf16x8*)(bptr[i]+k0+col);
    }
    __syncthreads();
    bf16x8 af[4], bfr[4];
    #pragma unroll
    for (int m=0;m<4;m++) af[m] = *(bf16x8*)&lsA[(wm+m*16+(lane&15))*40 + (lane>>4)*8];
    #pragma unroll
    for (int n=0;n<4;n++) bfr[n] = *(bf16x8*)&lsB[(wn+n*16+(lane&15))*40 + (lane>>4)*8];
    #pragma unroll
    for (int m=0;m<4;m++)
      #pragma unroll
      for (int n=0;n<4;n++)
        acc[m][n] = __builtin_amdgcn_mfma_f32_16x16x32_bf16(af[m], bfr[n], acc[m][n], 0,0,0);
    __syncthreads();
  }
  #pragma unroll
  for (int m=0;m<4;m++){
    int lr0 = wm + m*16 + ((lane>>4)<<2);
    #pragma unroll
    for (int n=0;n<4;n++){
      int col = n0 + wn + n*16 + (lane&15);
      #pragma unroll
      for (int r=0;r<4;r++){
        int gr = m0 + lr0 + r;
        if (gr < cnt)
          atomicAdd(&moe_out[(size_t)tl[gr]*DMODEL + col], wl[gr]*acc[m][n][r]);
      }
    }
  }
}

// ---------------- out = x2 + rmsnorm(moe)*g_post_moe ----------------
__global__ __launch_bounds__(256) void final_kernel(
    const float* __restrict__ x2, const float* __restrict__ moe,
    const float* __restrict__ g, float* __restrict__ out)
{
  int row = blockIdx.x, tid = threadIdx.x;
  float4 mv = ((const float4*)(moe + (size_t)row*DMODEL))[tid];
  float4 xv = ((const float4*)(x2  + (size_t)row*DMODEL))[tid];
  float ss = mv.x*mv.x + mv.y*mv.y + mv.z*mv.z + mv.w*mv.w;
  #pragma unroll
  for (int off=32; off; off>>=1) ss += __shfl_down(ss, off);
  __shared__ float red[4];
  if ((tid&63)==0) red[tid>>6] = ss;
  __syncthreads();
  float rs = rsqrtf((red[0]+red[1]+red[2]+red[3])*(1.f/1024.f) + EPSV);
  float4 gv = ((const float4*)g)[tid];
  float4 o;
  o.x = xv.x + mv.x*rs*gv.x; o.y = xv.y + mv.y*rs*gv.y;
  o.z = xv.z + mv.z*rs*gv.z; o.w = xv.w + mv.w*rs*gv.w;
  ((float4*)(out + (size_t)row*DMODEL))[tid] = o;
}

extern "C" void kernel_launch(void* const* d_in, const int* in_sizes, int n_in,
                              void* d_out, int out_size, void* d_ws, size_t ws_size,
                              hipStream_t stream) {
  (void)in_sizes; (void)n_in; (void)out_size; (void)ws_size;
  const float* x          = (const float*)d_in[0];
  const float* g_pre_mqa  = (const float*)d_in[1];
  const float* g_post_mqa = (const float*)d_in[2];
  const float* g_pre_moe  = (const float*)d_in[3];
  const float* g_post_moe = (const float*)d_in[4];
  const float* Wq         = (const float*)d_in[5];
  const float* Wk         = (const float*)d_in[6];
  const float* Wv         = (const float*)d_in[7];
  const float* Wo         = (const float*)d_in[8];
  const float* Wg         = (const float*)d_in[9];
  const float* We1        = (const float*)d_in[10];
  const float* We2        = (const float*)d_in[11];

  float* out_x = (float*)d_out;
  float* out_probs = out_x + (size_t)NTOK*DMODEL;

  char* p = (char*)d_ws;
  size_t off = 0;
  auto alloc = [&](size_t bytes)->char*{
    char* r = p + off; off = (off + bytes + 255) & ~(size_t)255; return r; };

  short* we1t = (short*)alloc((size_t)NE*HIDD*DMODEL*2);       // 64M
  short* we2t = (short*)alloc((size_t)NE*DMODEL*HIDD*2);       // 64M
  short* mid  = (short*)alloc((size_t)2*NTOK*HIDD*2);          // 64M

  // region A: xn1 fp16 planes (2x8M), later ao fp32 (16M)
  char* regA = alloc((size_t)2*NTOK*DMODEL*2);
  _Float16* xn1p1 = (_Float16*)regA;
  _Float16* xn1p2 = (_Float16*)(regA + (size_t)NTOK*DMODEL*2);
  float* ao       = (float*)regA;

  _Float16* wqkvT1 = (_Float16*)alloc((size_t)QKVW*DMODEL*2);
  _Float16* wqkvT2 = (_Float16*)alloc((size_t)QKVW*DMODEL*2);
  _Float16* woT1   = (_Float16*)alloc((size_t)DMODEL*DMODEL*2);
  _Float16* woT2   = (_Float16*)alloc((size_t)DMODEL*DMODEL*2);

  // region B: qkv fp32 (18.9M), later attn fp16 planes (2x8M)
  char* regB = alloc((size_t)NTOK*QKVW*4);
  float* qkv = (float*)regB;
  _Float16* attnp1 = (_Float16*)regB;
  _Float16* attnp2 = (_Float16*)(regB + (size_t)NTOK*DMODEL*2);

  // region C: qkvs bf16 planes (3x9.4M), later moe fp32 (16.8M) + hbuf (8.4M)
  char* regC = alloc((size_t)3*NTOK*QKVW*2);
  short* qkvs1 = (short*)regC;
  short* qkvs2 = (short*)(regC + (size_t)NTOK*QKVW*2);
  short* qkvs3 = (short*)(regC + (size_t)2*NTOK*QKVW*2);
  float* moe   = (float*)regC;
  short* hbuf  = (short*)(regC + (size_t)NTOK*DMODEL*4);

  short* vt1 = (short*)alloc((size_t)2*HDIM*SEQL*2);
  short* vt2 = (short*)alloc((size_t)2*HDIM*SEQL*2);
  short* vt3 = (short*)alloc((size_t)2*HDIM*SEQL*2);
  float* x2  = (float*)alloc((size_t)NTOK*DMODEL*4);
  int*   tok_l  = (int*)  alloc((size_t)NE*NTOK*4);
  float* w_l    = (float*)alloc((size_t)NE*NTOK*4);
  int*   counts = (int*)  alloc(256);
  int*   bases  = (int*)  alloc(256);

  // ---- weights prep ----
  transpose_conv_kernel<<<dim3(HIDD/32, DMODEL/32, NE), 256, 0, stream>>>(
      We1, we1t, DMODEL, HIDD, (long)DMODEL*HIDD, (long)HIDD*DMODEL);
  transpose_conv_kernel<<<dim3(DMODEL/32, HIDD/32, NE), 256, 0, stream>>>(
      We2, we2t, HIDD, DMODEL, (long)HIDD*DMODEL, (long)DMODEL*HIDD);
  transpose_split2f16_kernel<<<dim3(DMODEL/32, DMODEL/32), 256, 0, stream>>>(
      Wq, wqkvT1, wqkvT2, DMODEL, DMODEL, 0, DMODEL);
  transpose_split2f16_kernel<<<dim3(HDIM/32, DMODEL/32), 256, 0, stream>>>(
      Wk, wqkvT1, wqkvT2, DMODEL, HDIM, DMODEL, DMODEL);
  transpose_split2f16_kernel<<<dim3(HDIM/32, DMODEL/32), 256, 0, stream>>>(
      Wv, wqkvT1, wqkvT2, DMODEL, HDIM, DMODEL+HDIM, DMODEL);
  transpose_split2f16_kernel<<<dim3(DMODEL/32, DMODEL/32), 256, 0, stream>>>(
      Wo, woT1, woT2, DMODEL, DMODEL, 0, DMODEL);

  // ---- pre-router chain: fp16x2 GEMMs + bf16x3 attention ----
  rms_split2_kernel<<<NTOK, 256, 0, stream>>>(x, g_pre_mqa, xn1p1, xn1p2);
  gemm_f16x2_kernel<<<dim3(QKVW/128, NTOK/128), 256, 0, stream>>>(
      xn1p1, xn1p2, wqkvT1, wqkvT2, qkv, DMODEL, QKVW, OUTSCL);
  split3_flat_kernel<<<(NTOK*QKVW/4 + 255)/256, 256, 0, stream>>>(
      qkv, qkvs1, qkvs2, qkvs3, NTOK*QKVW/4);
  vtrans_split3_kernel<<<dim3(SEQL/32, HDIM/32, 2), 256, 0, stream>>>(qkv, vt1, vt2, vt3);
  attn_bf16x3_kernel<<<dim3(SEQL/QB, NH, 2), 256, 0, stream>>>(
      qkvs1, qkvs2, qkvs3, vt1, vt2, vt3, attnp1, attnp2);
  gemm_f16x2_kernel<<<dim3(DMODEL/128, NTOK/128), 256, 0, stream>>>(
      attnp1, attnp2, woT1, woT2, ao, DMODEL, DMODEL, OUTSCL);
  attnres_kernel<<<NTOK, 256, 0, stream>>>(x, ao, g_post_mqa, g_pre_moe, x2, hbuf);

  // ---- router + grouped MoE (bf16 MFMA) ----
  hipMemsetAsync(moe, 0, (size_t)NTOK*DMODEL*4, stream);
  hipMemsetAsync(counts, 0, 32, stream);
  router_kernel<<<NTOK, 64, 0, stream>>>(x2, g_pre_moe, Wg, out_probs, tok_l, w_l, counts);
  prefix_kernel<<<1, 64, 0, stream>>>(counts, bases);
  moe_gemm1_kernel<<<dim3(HIDD/128, NTOK/128, NE), 256, 0, stream>>>(
      hbuf, we1t, tok_l, counts, bases, mid);
  moe_gemm2_kernel<<<dim3(DMODEL/128, NTOK/128, NE), 256, 0, stream>>>(
      mid, we2t, tok_l, w_l, counts, bases, moe);
  final_kernel<<<NTOK, 256, 0, stream>>>(x2, moe, g_post_moe, out_x);
}

// Round 5
// 894.311 us; speedup vs baseline: 1.7682x; 1.1244x over previous
//
#include <hip/hip_runtime.h>
#include <hip/hip_bf16.h>
#include <math.h>

#define NTOK   4096
#define DMODEL 1024
#define SEQL   2048
#define QKVW   1152     // 1024 q + 64 k + 64 v
#define NH     16
#define HDIM   64
#define NE     8
#define HIDD   4096
#define EPSV   1e-5f
#define KT     32       // attention kv-tile

// fp16 GEMM scales: activations *2^8, weights *2^12 (keeps split-2 second
// pieces out of fp16-subnormal range); folded out via OUTSCL.
#define ASCL   256.f
#define WSCL   4096.f
#define OUTSCL (1.f/1048576.f)          // 2^-20

typedef __attribute__((ext_vector_type(8))) short bf16x8;
typedef __attribute__((ext_vector_type(8))) _Float16 f16x8;
typedef __attribute__((ext_vector_type(4))) _Float16 f16x4;
typedef __attribute__((ext_vector_type(4))) float f32x4;

__device__ __forceinline__ short f2b(float x){
  __hip_bfloat16 h = __float2bfloat16(x);
  return *reinterpret_cast<short*>(&h);
}
__device__ __forceinline__ float b2f(short s){
  __hip_bfloat16 h = *reinterpret_cast<__hip_bfloat16*>(&s);
  return __bfloat162float(h);
}
// 3-piece bf16 split: x ~= a+b+c to ~2^-26 rel (PROVEN rounds 2/4)
__device__ __forceinline__ void split3(float x, short& a, short& b, short& c){
  a = f2b(x);
  float r1 = x - b2f(a);
  b = f2b(r1);
  float r2 = r1 - b2f(b);
  c = f2b(r2);
}
__device__ __forceinline__ void split2h(float x, _Float16& a, _Float16& b){
  a = (_Float16)x;
  b = (_Float16)(x - (float)a);
}

// ---------------- transpose fp32 [R][C] -> bf16 [C][R] (expert weights) ----------------
__global__ __launch_bounds__(256) void transpose_conv_kernel(
    const float* __restrict__ in, short* __restrict__ out,
    int R, int C, long inb, long outb)
{
  __shared__ float tile[32][33];
  in  += (size_t)blockIdx.z * inb;
  out += (size_t)blockIdx.z * outb;
  int c0 = blockIdx.x*32, r0 = blockIdx.y*32;
  int tx = threadIdx.x & 31, ty = threadIdx.x >> 5;
  #pragma unroll
  for (int i=0;i<4;i++)
    tile[ty+i*8][tx] = in[(size_t)(r0+ty+i*8)*C + c0+tx];
  __syncthreads();
  #pragma unroll
  for (int i=0;i<4;i++)
    out[(size_t)(c0+ty+i*8)*R + r0+tx] = f2b(tile[tx][ty+i*8]);
}

// ---------------- transpose fp32 [R][C] -> 2 fp16 planes [C+rowOff][outLD=R], *2^12 ----------------
__global__ __launch_bounds__(256) void transpose_split2f16_kernel(
    const float* __restrict__ in, _Float16* __restrict__ o1, _Float16* __restrict__ o2,
    int R, int C, int rowOff, int outLD)
{
  __shared__ float tile[32][33];
  int c0 = blockIdx.x*32, r0 = blockIdx.y*32;
  int tx = threadIdx.x & 31, ty = threadIdx.x >> 5;
  #pragma unroll
  for (int i=0;i<4;i++)
    tile[ty+i*8][tx] = in[(size_t)(r0+ty+i*8)*C + c0+tx];
  __syncthreads();
  #pragma unroll
  for (int i=0;i<4;i++){
    float v = tile[tx][ty+i*8] * WSCL;
    _Float16 a,b; split2h(v,a,b);
    size_t idx = (size_t)(c0+ty+i*8+rowOff)*outLD + r0+tx;
    o1[idx]=a; o2[idx]=b;
  }
}

// ---------------- rmsnorm(x)*g*2^8 -> 2 fp16 planes ----------------
__global__ __launch_bounds__(256) void rms_split2_kernel(
    const float* __restrict__ x, const float* __restrict__ g,
    _Float16* __restrict__ o1, _Float16* __restrict__ o2)
{
  int row = blockIdx.x, tid = threadIdx.x;
  const float4* xr = (const float4*)(x + (size_t)row*DMODEL);
  float4 v = xr[tid];
  float ss = v.x*v.x + v.y*v.y + v.z*v.z + v.w*v.w;
  #pragma unroll
  for (int off=32; off; off>>=1) ss += __shfl_down(ss, off);
  __shared__ float red[4];
  if ((tid&63)==0) red[tid>>6] = ss;
  __syncthreads();
  float rs = rsqrtf((red[0]+red[1]+red[2]+red[3])*(1.f/1024.f) + EPSV) * ASCL;
  float4 gv = ((const float4*)g)[tid];
  float o[4] = {v.x*rs*gv.x, v.y*rs*gv.y, v.z*rs*gv.z, v.w*rs*gv.w};
  f16x4 s1,s2;
  #pragma unroll
  for (int c=0;c<4;c++){ _Float16 a,b; split2h(o[c],a,b); s1[c]=a; s2[c]=b; }
  size_t base = (size_t)row*DMODEL + tid*4;
  *(f16x4*)(o1+base) = s1; *(f16x4*)(o2+base) = s2;
}

// ---------------- flat fp32 -> 3 bf16 planes (unscaled, for attention) ----------------
__global__ void split3_flat_kernel(const float* __restrict__ in,
    short* __restrict__ o1, short* __restrict__ o2, short* __restrict__ o3, int n4)
{
  int i = blockIdx.x*256 + threadIdx.x;
  if (i >= n4) return;
  float4 v = ((const float4*)in)[i];
  short4 s1,s2,s3;
  split3(v.x, s1.x, s2.x, s3.x);
  split3(v.y, s1.y, s2.y, s3.y);
  split3(v.z, s1.z, s2.z, s3.z);
  split3(v.w, s1.w, s2.w, s3.w);
  ((short4*)o1)[i]=s1; ((short4*)o2)[i]=s2; ((short4*)o3)[i]=s3;
}

// ---------------- V^T build: qkv fp32 [4096][1152] -> vt planes [2][64][2048] ----------------
__global__ __launch_bounds__(256) void vtrans_split3_kernel(
    const float* __restrict__ qkv,
    short* __restrict__ o1, short* __restrict__ o2, short* __restrict__ o3)
{
  __shared__ float tile[32][33];
  int s0 = blockIdx.x*32, d0 = blockIdx.y*32, b = blockIdx.z;
  int tx = threadIdx.x & 31, ty = threadIdx.x >> 5;
  #pragma unroll
  for (int i=0;i<4;i++)
    tile[ty+i*8][tx] = qkv[(size_t)(b*SEQL + s0+ty+i*8)*QKVW + DMODEL+HDIM + d0+tx];
  __syncthreads();
  #pragma unroll
  for (int i=0;i<4;i++){
    float v = tile[tx][ty+i*8];   // [s=tx][d=ty+i*8]
    short a,bs,c; split3(v,a,bs,c);
    size_t idx = (size_t)(b*HDIM + d0+ty+i*8)*SEQL + s0+tx;
    o1[idx]=a; o2[idx]=bs; o3[idx]=c;
  }
}

// ---------------- fp32-accurate GEMM via 3-pass fp16x2 MFMA (PROVEN round 4) ----------------
__global__ __launch_bounds__(256) void gemm_f16x2_kernel(
    const _Float16* __restrict__ a1, const _Float16* __restrict__ a2,
    const _Float16* __restrict__ b1, const _Float16* __restrict__ b2,
    float* __restrict__ C, int K, int ldc, float outscale)
{
  __shared__ _Float16 lsA[2][128*40];
  __shared__ _Float16 lsB[2][128*40];
  int m0 = blockIdx.y*128, n0 = blockIdx.x*128;
  int tid = threadIdx.x, wave = tid>>6, lane = tid&63;
  int g = lane>>4, li = lane&15;
  int wm = (wave>>1)*64, wn = (wave&1)*64;
  const _Float16* Ap[2] = {a1,a2};
  const _Float16* Bp[2] = {b1,b2};
  f32x4 acc[4][4] = {};
  for (int k0=0; k0<K; k0+=32){
    #pragma unroll
    for (int p=0;p<2;p++){
      #pragma unroll
      for (int i=0;i<2;i++){
        int c = tid + 256*i;
        int row = c>>2, col = (c&3)*8;
        *(f16x8*)&lsA[p][row*40+col] = *(const f16x8*)(Ap[p] + (size_t)(m0+row)*K + k0+col);
        *(f16x8*)&lsB[p][row*40+col] = *(const f16x8*)(Bp[p] + (size_t)(n0+row)*K + k0+col);
      }
    }
    __syncthreads();
    #pragma unroll
    for (int i=0;i<2;i++){
      f16x8 af[4];
      #pragma unroll
      for (int m=0;m<4;m++) af[m] = *(f16x8*)&lsA[i][(wm+m*16+li)*40 + g*8];
      #pragma unroll
      for (int j=0;j<2-i;j++){
        #pragma unroll
        for (int n=0;n<4;n++){
          f16x8 bfr = *(f16x8*)&lsB[j][(wn+n*16+li)*40 + g*8];
          #pragma unroll
          for (int m=0;m<4;m++)
            acc[m][n] = __builtin_amdgcn_mfma_f32_16x16x32_f16(af[m], bfr, acc[m][n], 0,0,0);
        }
      }
    }
    __syncthreads();
  }
  #pragma unroll
  for (int m=0;m<4;m++){
    int lr0 = wm + m*16 + g*4;
    #pragma unroll
    for (int n=0;n<4;n++){
      int col = n0 + wn + n*16 + li;
      #pragma unroll
      for (int r=0;r<4;r++)
        C[(size_t)(m0+lr0+r)*ldc + col] = acc[m][n][r]*outscale;
    }
  }
}

// ---------------- flash attention, bf16x3 6-pass MFMA, swapped QK^T (round-2 core) ----------------
// QB=128: grid (16 qtiles, 16 heads, 2 batch), 256 thr (4 waves x 32 q-rows).
// + defer-max rescale (THR=8), __expf, fp16x2 *2^8 epilogue.
__global__ __launch_bounds__(256) void attn_bf16x3_kernel(
    const short* __restrict__ q1, const short* __restrict__ q2, const short* __restrict__ q3,
    const short* __restrict__ v1, const short* __restrict__ v2, const short* __restrict__ v3,
    _Float16* __restrict__ o1, _Float16* __restrict__ o2)
{
  __shared__ short Qs[128*200];   // [q][plane*64+d]
  __shared__ short Ks[32*200];    // [kv][plane*64+d]
  __shared__ short Vs[64*104];    // [d][plane*32+kv]
  int qt = blockIdx.x, h = blockIdx.y, b = blockIdx.z;
  int tid = threadIdx.x, wave = tid>>6, lane = tid&63;
  int g = lane>>4, li = lane&15;
  size_t qbase = (size_t)b*SEQL + qt*128;
  const short* qsrc[3] = {q1,q2,q3};
  const short* vsrc[3] = {v1,v2,v3};
  #pragma unroll
  for (int i=0;i<12;i++){
    int c = tid + 256*i;            // 128 rows * 24 chunks
    int row = c/24, sub = c - row*24;
    int p = sub>>3, d = (sub&7)*8;
    *(bf16x8*)&Qs[row*200 + p*64 + d] =
        *(const bf16x8*)(qsrc[p] + (qbase+row)*QKVW + h*HDIM + d);
  }
  float m_run[2] = {-1e30f,-1e30f}, l_run[2] = {0.f,0.f};
  f32x4 acc_o[4][2] = {};
  int src1 = (((2*g)&3)<<4) + li;
  int src2 = (((2*g+1)&3)<<4) + li;
  bool hi_half = (g>=2);

  for (int kvt=0; kvt<SEQL/KT; kvt++){
    __syncthreads();
    #pragma unroll
    for (int i=0;i<3;i++){
      int c = tid + 256*i;
      { // K: 32 rows * 24 chunks
        int row = c/24, sub = c - row*24;
        int p = sub>>3, d = (sub&7)*8;
        *(bf16x8*)&Ks[row*200 + p*64 + d] =
          *(const bf16x8*)(qsrc[p] + ((size_t)b*SEQL + kvt*KT + row)*QKVW + DMODEL + d);
      }
      { // V^T: 64 rows * 12 chunks
        int row = c/12, sub = c - row*12;
        int p = sub>>2, s8 = (sub&3)*8;
        *(bf16x8*)&Vs[row*104 + p*32 + s8] =
          *(const bf16x8*)(vsrc[p] + ((size_t)b*HDIM + row)*SEQL + kvt*KT + s8);
      }
    }
    __syncthreads();
    // S^T = K . Q^T  (rows kv, cols q)
    f32x4 s_acc[2][2] = {};
    #pragma unroll
    for (int i=0;i<3;i++){
      #pragma unroll
      for (int kk=0;kk<2;kk++){
        bf16x8 af[2];
        #pragma unroll
        for (int mf=0;mf<2;mf++)
          af[mf] = *(bf16x8*)&Ks[(mf*16+li)*200 + i*64 + kk*32 + g*8];
        #pragma unroll
        for (int j=0;j<3-i;j++){
          #pragma unroll
          for (int nf=0;nf<2;nf++){
            bf16x8 bfr = *(bf16x8*)&Qs[(wave*32+nf*16+li)*200 + j*64 + kk*32 + g*8];
            #pragma unroll
            for (int mf=0;mf<2;mf++)
              s_acc[mf][nf] = __builtin_amdgcn_mfma_f32_16x16x32_bf16(af[mf], bfr, s_acc[mf][nf], 0,0,0);
          }
        }
      }
    }
    // online softmax with defer-max (T13, THR=8)
    float p[2][2][4];
    #pragma unroll
    for (int nf=0;nf<2;nf++){
      float mx = -1e30f;
      #pragma unroll
      for (int mf=0;mf<2;mf++)
        #pragma unroll
        for (int r=0;r<4;r++) mx = fmaxf(mx, s_acc[mf][nf][r]);
      mx = fmaxf(mx, __shfl_xor(mx,16));
      mx = fmaxf(mx, __shfl_xor(mx,32));
      mx *= 0.125f;
      if (!__all(mx <= m_run[nf] + 8.f)){
        float mn = fmaxf(m_run[nf], mx);
        float al = __expf(m_run[nf] - mn);
        m_run[nf] = mn;
        l_run[nf] *= al;
        #pragma unroll
        for (int mfd=0; mfd<4; mfd++){
          acc_o[mfd][nf][0]*=al; acc_o[mfd][nf][1]*=al;
          acc_o[mfd][nf][2]*=al; acc_o[mfd][nf][3]*=al;
        }
      }
      float rsum = 0.f;
      #pragma unroll
      for (int mf=0;mf<2;mf++)
        #pragma unroll
        for (int r=0;r<4;r++){
          float pv = __expf(s_acc[mf][nf][r]*0.125f - m_run[nf]);
          p[mf][nf][r] = pv; rsum += pv;
        }
      rsum += __shfl_xor(rsum,16);
      rsum += __shfl_xor(rsum,32);
      l_run[nf] += rsum;
    }
    // gather this lane's B-frag kv-slice (kv = 8g..8g+7) and split to 3 planes
    bf16x8 fp_frag[2][3];
    #pragma unroll
    for (int nf=0;nf<2;nf++){
      float p8[8];
      #pragma unroll
      for (int jj=0;jj<4;jj++){
        float v0 = __shfl(p[0][nf][jj], src1);
        float vv1 = __shfl(p[1][nf][jj], src1);
        p8[jj] = hi_half ? vv1 : v0;
        float w0 = __shfl(p[0][nf][jj], src2);
        float w1 = __shfl(p[1][nf][jj], src2);
        p8[4+jj] = hi_half ? w1 : w0;
      }
      #pragma unroll
      for (int jj=0;jj<8;jj++){
        short xa,xb,xc; split3(p8[jj], xa,xb,xc);
        fp_frag[nf][0][jj]=xa; fp_frag[nf][1][jj]=xb; fp_frag[nf][2][jj]=xc;
      }
    }
    // O^T += V^T . P   (rows d, cols q)
    #pragma unroll
    for (int vj=0;vj<3;vj++){
      bf16x8 av[4];
      #pragma unroll
      for (int mfd=0;mfd<4;mfd++)
        av[mfd] = *(bf16x8*)&Vs[(mfd*16+li)*104 + vj*32 + g*8];
      #pragma unroll
      for (int pi=0; pi<3-vj; pi++)
        #pragma unroll
        for (int mfd=0;mfd<4;mfd++)
          #pragma unroll
          for (int nf=0;nf<2;nf++)
            acc_o[mfd][nf] = __builtin_amdgcn_mfma_f32_16x16x32_bf16(av[mfd], fp_frag[nf][pi], acc_o[mfd][nf], 0,0,0);
    }
  }
  // epilogue: attn*2^8, split2 -> fp16 planes (feeds fp16 Wo GEMM)
  #pragma unroll
  for (int nf=0;nf<2;nf++){
    float inv = ASCL/l_run[nf];
    size_t q = qbase + wave*32 + nf*16 + li;
    #pragma unroll
    for (int mfd=0;mfd<4;mfd++){
      int d0 = mfd*16 + g*4;
      f16x4 sa,sb;
      #pragma unroll
      for (int r=0;r<4;r++){
        _Float16 xa,xb; split2h(acc_o[mfd][nf][r]*inv, xa,xb);
        sa[r]=xa; sb[r]=xb;
      }
      size_t base = q*DMODEL + h*HDIM + d0;
      *(f16x4*)(o1+base)=sa; *(f16x4*)(o2+base)=sb;
    }
  }
}

// ---------------- x2 = x + rmsnorm(ao)*g_post ; h = bf16(rmsnorm(x2)*g_pre) ----------------
__global__ __launch_bounds__(256) void attnres_kernel(
    const float* __restrict__ x, const float* __restrict__ ao,
    const float* __restrict__ gpost, const float* __restrict__ gpre,
    float* __restrict__ x2, short* __restrict__ h)
{
  int row = blockIdx.x, tid = threadIdx.x;
  float4 a  = ((const float4*)(ao + (size_t)row*DMODEL))[tid];
  float4 xv = ((const float4*)(x  + (size_t)row*DMODEL))[tid];
  float ss = a.x*a.x + a.y*a.y + a.z*a.z + a.w*a.w;
  #pragma unroll
  for (int off=32; off; off>>=1) ss += __shfl_down(ss, off);
  __shared__ float red[4];
  if ((tid&63)==0) red[tid>>6] = ss;
  __syncthreads();
  float rs1 = rsqrtf((red[0]+red[1]+red[2]+red[3])*(1.f/1024.f) + EPSV);
  float4 gp = ((const float4*)gpost)[tid];
  float4 o;
  o.x = xv.x + a.x*rs1*gp.x; o.y = xv.y + a.y*rs1*gp.y;
  o.z = xv.z + a.z*rs1*gp.z; o.w = xv.w + a.w*rs1*gp.w;
  ((float4*)(x2 + (size_t)row*DMODEL))[tid] = o;
  float s2 = o.x*o.x + o.y*o.y + o.z*o.z + o.w*o.w;
  __syncthreads();
  #pragma unroll
  for (int off=32; off; off>>=1) s2 += __shfl_down(s2, off);
  if ((tid&63)==0) red[tid>>6] = s2;
  __syncthreads();
  float rs2 = rsqrtf((red[0]+red[1]+red[2]+red[3])*(1.f/1024.f) + EPSV);
  float4 gm = ((const float4*)gpre)[tid];
  short4 hs;
  hs.x = f2b(o.x*rs2*gm.x); hs.y = f2b(o.y*rs2*gm.y);
  hs.z = f2b(o.z*rs2*gm.z); hs.w = f2b(o.w*rs2*gm.w);
  *(short4*)(h + (size_t)row*DMODEL + tid*4) = hs;
}

// ---------------- router: top-2 lists with slot packed in bit 16 ----------------
__global__ __launch_bounds__(64) void router_kernel(
    const float* __restrict__ x2, const float* __restrict__ g, const float* __restrict__ Wg,
    float* __restrict__ probs_out, int* __restrict__ tok_list, float* __restrict__ w_list,
    int* __restrict__ counts)
{
  int t = blockIdx.x, lane = threadIdx.x;
  const float4* xr = (const float4*)(x2 + (size_t)t*DMODEL);
  float4 v[4]; float ss = 0.f;
  #pragma unroll
  for (int i=0;i<4;i++){ v[i] = xr[lane + 64*i];
    ss += v[i].x*v[i].x + v[i].y*v[i].y + v[i].z*v[i].z + v[i].w*v[i].w; }
  #pragma unroll
  for (int off=32; off; off>>=1) ss += __shfl_xor(ss, off);
  float rs = rsqrtf(ss*(1.f/1024.f) + EPSV);
  float le[8] = {0,0,0,0,0,0,0,0};
  #pragma unroll
  for (int i=0;i<4;i++){
    int jb = (lane + 64*i)*4;
    float hv[4] = {v[i].x, v[i].y, v[i].z, v[i].w};
    #pragma unroll
    for (int c=0;c<4;c++){
      float hj = hv[c]*rs*g[jb+c];
      const float* wrow = Wg + (size_t)(jb+c)*NE;
      #pragma unroll
      for (int ee=0;ee<8;ee++) le[ee] += hj*wrow[ee];
    }
  }
  #pragma unroll
  for (int ee=0;ee<8;ee++)
    #pragma unroll
    for (int off=32; off; off>>=1) le[ee] += __shfl_xor(le[ee], off);
  float mx = le[0];
  #pragma unroll
  for (int ee=1;ee<8;ee++) mx = fmaxf(mx, le[ee]);
  float p[8], s = 0.f;
  #pragma unroll
  for (int ee=0;ee<8;ee++){ p[ee] = expf(le[ee]-mx); s += p[ee]; }
  float inv = 1.f/s;
  #pragma unroll
  for (int ee=0;ee<8;ee++) p[ee] *= inv;
  if (lane < 8) probs_out[(size_t)t*NE + lane] = p[lane];
  if (lane == 0){
    int i1 = 0;
    #pragma unroll
    for (int ee=1;ee<8;ee++) if (p[ee] > p[i1]) i1 = ee;
    int i2 = (i1==0) ? 1 : 0;
    #pragma unroll
    for (int ee=0;ee<8;ee++) if (ee != i1 && p[ee] > p[i2]) i2 = ee;
    int pos = atomicAdd(&counts[i1], 1);
    tok_list[i1*NTOK+pos] = t;              // slot 0
    w_list[i1*NTOK+pos] = p[i1];
    pos = atomicAdd(&counts[i2], 1);
    tok_list[i2*NTOK+pos] = t | (1<<16);    // slot 1
    w_list[i2*NTOK+pos] = p[i2];
  }
}

__global__ void prefix_kernel(const int* __restrict__ counts, int* __restrict__ bases){
  if (threadIdx.x == 0){
    int a = 0;
    for (int ee=0;ee<8;ee++){ bases[ee] = a; a += counts[ee]; }
  }
}

// ---------------- MoE grouped GEMM1: mid = gelu(h @ We1[e]^T) ----------------
__global__ __launch_bounds__(256) void moe_gemm1_kernel(
    const short* __restrict__ h, const short* __restrict__ we1t,
    const int* __restrict__ tok_list, const int* __restrict__ counts,
    const int* __restrict__ bases, short* __restrict__ mid)
{
  int e = blockIdx.z;
  int cnt = counts[e];
  int m0 = blockIdx.y*128, n0 = blockIdx.x*128;
  if (m0 >= cnt) return;
  int base = bases[e];
  const short* Bt = we1t + (size_t)e*HIDD*DMODEL;
  const int* tl = tok_list + e*NTOK;
  __shared__ short lsA[128*40];
  __shared__ short lsB[128*40];
  int tid = threadIdx.x, wave = tid>>6, lane = tid&63;
  int wm = (wave>>1)*64, wn = (wave&1)*64;
  const short* aptr[2]; const short* bptr[2];
  #pragma unroll
  for (int i=0;i<2;i++){
    int c = tid + 256*i; int row = c>>2;
    int rr = min(m0+row, cnt-1);
    aptr[i] = h + (size_t)(tl[rr] & 0xFFFF)*DMODEL;
    bptr[i] = Bt + (size_t)(n0+row)*DMODEL;
  }
  f32x4 acc[4][4] = {};
  for (int k0=0; k0<DMODEL; k0+=32){
    #pragma unroll
    for (int i=0;i<2;i++){
      int c = tid + 256*i; int row = c>>2, col = (c&3)*8;
      *(bf16x8*)&lsA[row*40+col] = *(const bf16x8*)(aptr[i]+k0+col);
      *(bf16x8*)&lsB[row*40+col] = *(const bf16x8*)(bptr[i]+k0+col);
    }
    __syncthreads();
    bf16x8 af[4], bfr[4];
    #pragma unroll
    for (int m=0;m<4;m++) af[m] = *(bf16x8*)&lsA[(wm+m*16+(lane&15))*40 + (lane>>4)*8];
    #pragma unroll
    for (int n=0;n<4;n++) bfr[n] = *(bf16x8*)&lsB[(wn+n*16+(lane&15))*40 + (lane>>4)*8];
    #pragma unroll
    for (int m=0;m<4;m++)
      #pragma unroll
      for (int n=0;n<4;n++)
        acc[m][n] = __builtin_amdgcn_mfma_f32_16x16x32_bf16(af[m], bfr[n], acc[m][n], 0,0,0);
    __syncthreads();
  }
  #pragma unroll
  for (int m=0;m<4;m++){
    int lr0 = wm + m*16 + ((lane>>4)<<2);
    #pragma unroll
    for (int n=0;n<4;n++){
      int col = n0 + wn + n*16 + (lane&15);
      #pragma unroll
      for (int r=0;r<4;r++){
        int gr = m0 + lr0 + r;
        if (gr < cnt){
          float tval = acc[m][n][r];
          // gelu(t) = t * sigmoid(1.59577*(t + 0.044715 t^3))  (exact tanh identity)
          float u = 1.5957691216057308f*(tval + 0.044715f*tval*tval*tval);
          float ge = tval / (1.f + __expf(-u));
          mid[(size_t)(base+gr)*HIDD + col] = f2b(ge);
        }
      }
    }
  }
}

// ---------------- MoE grouped GEMM2: eo[slot][tok] = w * (mid @ We2[e]^T)  (no atomics) ----------------
__global__ __launch_bounds__(256) void moe_gemm2_kernel(
    const short* __restrict__ mid, const short* __restrict__ we2t,
    const int* __restrict__ tok_list, const float* __restrict__ w_list,
    const int* __restrict__ counts, const int* __restrict__ bases,
    float* __restrict__ eo)
{
  int e = blockIdx.z;
  int cnt = counts[e];
  int m0 = blockIdx.y*128, n0 = blockIdx.x*128;
  if (m0 >= cnt) return;
  int base = bases[e];
  const short* A  = mid + (size_t)base*HIDD;
  const short* Bt = we2t + (size_t)e*DMODEL*HIDD;
  const int* tl = tok_list + e*NTOK;
  const float* wl = w_list + e*NTOK;
  __shared__ short lsA[128*40];
  __shared__ short lsB[128*40];
  int tid = threadIdx.x, wave = tid>>6, lane = tid&63;
  int wm = (wave>>1)*64, wn = (wave&1)*64;
  const short* aptr[2]; const short* bptr[2];
  #pragma unroll
  for (int i=0;i<2;i++){
    int c = tid + 256*i; int row = c>>2;
    int rr = min(m0+row, cnt-1);
    aptr[i] = A + (size_t)rr*HIDD;
    bptr[i] = Bt + (size_t)(n0+row)*HIDD;
  }
  f32x4 acc[4][4] = {};
  for (int k0=0; k0<HIDD; k0+=32){
    #pragma unroll
    for (int i=0;i<2;i++){
      int c = tid + 256*i; int row = c>>2, col = (c&3)*8;
      *(bf16x8*)&lsA[row*40+col] = *(const bf16x8*)(aptr[i]+k0+col);
      *(bf16x8*)&lsB[row*40+col] = *(const bf16x8*)(bptr[i]+k0+col);
    }
    __syncthreads();
    bf16x8 af[4], bfr[4];
    #pragma unroll
    for (int m=0;m<4;m++) af[m] = *(bf16x8*)&lsA[(wm+m*16+(lane&15))*40 + (lane>>4)*8];
    #pragma unroll
    for (int n=0;n<4;n++) bfr[n] = *(bf16x8*)&lsB[(wn+n*16+(lane&15))*40 + (lane>>4)*8];
    #pragma unroll
    for (int m=0;m<4;m++)
      #pragma unroll
      for (int n=0;n<4;n++)
        acc[m][n] = __builtin_amdgcn_mfma_f32_16x16x32_bf16(af[m], bfr[n], acc[m][n], 0,0,0);
    __syncthreads();
  }
  #pragma unroll
  for (int m=0;m<4;m++){
    int lr0 = wm + m*16 + ((lane>>4)<<2);
    #pragma unroll
    for (int n=0;n<4;n++){
      int col = n0 + wn + n*16 + (lane&15);
      #pragma unroll
      for (int r=0;r<4;r++){
        int gr = m0 + lr0 + r;
        if (gr < cnt){
          int pv = tl[gr];
          eo[((size_t)(pv>>16)*NTOK + (pv & 0xFFFF))*DMODEL + col] = wl[gr]*acc[m][n][r];
        }
      }
    }
  }
}

// ---------------- out = x2 + rmsnorm(eo0+eo1)*g_post_moe ----------------
__global__ __launch_bounds__(256) void final_kernel(
    const float* __restrict__ x2, const float* __restrict__ eo,
    const float* __restrict__ g, float* __restrict__ out)
{
  int row = blockIdx.x, tid = threadIdx.x;
  float4 m0 = ((const float4*)(eo + (size_t)row*DMODEL))[tid];
  float4 m1 = ((const float4*)(eo + (size_t)(NTOK+row)*DMODEL))[tid];
  float4 mv;
  mv.x = m0.x+m1.x; mv.y = m0.y+m1.y; mv.z = m0.z+m1.z; mv.w = m0.w+m1.w;
  float4 xv = ((const float4*)(x2  + (size_t)row*DMODEL))[tid];
  float ss = mv.x*mv.x + mv.y*mv.y + mv.z*mv.z + mv.w*mv.w;
  #pragma unroll
  for (int off=32; off; off>>=1) ss += __shfl_down(ss, off);
  __shared__ float red[4];
  if ((tid&63)==0) red[tid>>6] = ss;
  __syncthreads();
  float rs = rsqrtf((red[0]+red[1]+red[2]+red[3])*(1.f/1024.f) + EPSV);
  float4 gv = ((const float4*)g)[tid];
  float4 o;
  o.x = xv.x + mv.x*rs*gv.x; o.y = xv.y + mv.y*rs*gv.y;
  o.z = xv.z + mv.z*rs*gv.z; o.w = xv.w + mv.w*rs*gv.w;
  ((float4*)(out + (size_t)row*DMODEL))[tid] = o;
}

extern "C" void kernel_launch(void* const* d_in, const int* in_sizes, int n_in,
                              void* d_out, int out_size, void* d_ws, size_t ws_size,
                              hipStream_t stream) {
  (void)in_sizes; (void)n_in; (void)out_size; (void)ws_size;
  const float* x          = (const float*)d_in[0];
  const float* g_pre_mqa  = (const float*)d_in[1];
  const float* g_post_mqa = (const float*)d_in[2];
  const float* g_pre_moe  = (const float*)d_in[3];
  const float* g_post_moe = (const float*)d_in[4];
  const float* Wq         = (const float*)d_in[5];
  const float* Wk         = (const float*)d_in[6];
  const float* Wv         = (const float*)d_in[7];
  const float* Wo         = (const float*)d_in[8];
  const float* Wg         = (const float*)d_in[9];
  const float* We1        = (const float*)d_in[10];
  const float* We2        = (const float*)d_in[11];

  float* out_x = (float*)d_out;
  float* out_probs = out_x + (size_t)NTOK*DMODEL;

  char* p = (char*)d_ws;
  size_t off = 0;
  auto alloc = [&](size_t bytes)->char*{
    char* r = p + off; off = (off + bytes + 255) & ~(size_t)255; return r; };

  short* we1t = (short*)alloc((size_t)NE*HIDD*DMODEL*2);       // 64M
  short* we2t = (short*)alloc((size_t)NE*DMODEL*HIDD*2);       // 64M
  short* mid  = (short*)alloc((size_t)2*NTOK*HIDD*2);          // 64M

  // region A: xn1 fp16 planes (2x8.4M), later ao fp32 (16.8M)
  char* regA = alloc((size_t)2*NTOK*DMODEL*2);
  _Float16* xn1p1 = (_Float16*)regA;
  _Float16* xn1p2 = (_Float16*)(regA + (size_t)NTOK*DMODEL*2);
  float* ao       = (float*)regA;

  _Float16* wqkvT1 = (_Float16*)alloc((size_t)QKVW*DMODEL*2);
  _Float16* wqkvT2 = (_Float16*)alloc((size_t)QKVW*DMODEL*2);
  _Float16* woT1   = (_Float16*)alloc((size_t)DMODEL*DMODEL*2);
  _Float16* woT2   = (_Float16*)alloc((size_t)DMODEL*DMODEL*2);

  // region B: qkv fp32 (18.9M), later attn fp16 planes (2x8.4M)
  char* regB = alloc((size_t)NTOK*QKVW*4);
  float* qkv = (float*)regB;
  _Float16* attnp1 = (_Float16*)regB;
  _Float16* attnp2 = (_Float16*)(regB + (size_t)NTOK*DMODEL*2);

  // region C: qkvs bf16 planes (3x9.4M=28.3M), later eo fp32 2 slabs (33.6M) + hbuf (8.4M)
  char* regC = alloc((size_t)2*NTOK*DMODEL*4 + (size_t)NTOK*DMODEL*2);
  short* qkvs1 = (short*)regC;
  short* qkvs2 = (short*)(regC + (size_t)NTOK*QKVW*2);
  short* qkvs3 = (short*)(regC + (size_t)2*NTOK*QKVW*2);
  float* eo    = (float*)regC;
  short* hbuf  = (short*)(regC + (size_t)2*NTOK*DMODEL*4);

  short* vt1 = (short*)alloc((size_t)2*HDIM*SEQL*2);
  short* vt2 = (short*)alloc((size_t)2*HDIM*SEQL*2);
  short* vt3 = (short*)alloc((size_t)2*HDIM*SEQL*2);
  float* x2  = (float*)alloc((size_t)NTOK*DMODEL*4);
  int*   tok_l  = (int*)  alloc((size_t)NE*NTOK*4);
  float* w_l    = (float*)alloc((size_t)NE*NTOK*4);
  int*   counts = (int*)  alloc(256);
  int*   bases  = (int*)  alloc(256);

  // ---- weights prep ----
  transpose_conv_kernel<<<dim3(HIDD/32, DMODEL/32, NE), 256, 0, stream>>>(
      We1, we1t, DMODEL, HIDD, (long)DMODEL*HIDD, (long)HIDD*DMODEL);
  transpose_conv_kernel<<<dim3(DMODEL/32, HIDD/32, NE), 256, 0, stream>>>(
      We2, we2t, HIDD, DMODEL, (long)HIDD*DMODEL, (long)DMODEL*HIDD);
  transpose_split2f16_kernel<<<dim3(DMODEL/32, DMODEL/32), 256, 0, stream>>>(
      Wq, wqkvT1, wqkvT2, DMODEL, DMODEL, 0, DMODEL);
  transpose_split2f16_kernel<<<dim3(HDIM/32, DMODEL/32), 256, 0, stream>>>(
      Wk, wqkvT1, wqkvT2, DMODEL, HDIM, DMODEL, DMODEL);
  transpose_split2f16_kernel<<<dim3(HDIM/32, DMODEL/32), 256, 0, stream>>>(
      Wv, wqkvT1, wqkvT2, DMODEL, HDIM, DMODEL+HDIM, DMODEL);
  transpose_split2f16_kernel<<<dim3(DMODEL/32, DMODEL/32), 256, 0, stream>>>(
      Wo, woT1, woT2, DMODEL, DMODEL, 0, DMODEL);

  // ---- pre-router chain: fp16x2 GEMMs + bf16x3 attention ----
  rms_split2_kernel<<<NTOK, 256, 0, stream>>>(x, g_pre_mqa, xn1p1, xn1p2);
  gemm_f16x2_kernel<<<dim3(QKVW/128, NTOK/128), 256, 0, stream>>>(
      xn1p1, xn1p2, wqkvT1, wqkvT2, qkv, DMODEL, QKVW, OUTSCL);
  split3_flat_kernel<<<(NTOK*QKVW/4 + 255)/256, 256, 0, stream>>>(
      qkv, qkvs1, qkvs2, qkvs3, NTOK*QKVW/4);
  vtrans_split3_kernel<<<dim3(SEQL/32, HDIM/32, 2), 256, 0, stream>>>(qkv, vt1, vt2, vt3);
  attn_bf16x3_kernel<<<dim3(SEQL/128, NH, 2), 256, 0, stream>>>(
      qkvs1, qkvs2, qkvs3, vt1, vt2, vt3, attnp1, attnp2);
  gemm_f16x2_kernel<<<dim3(DMODEL/128, NTOK/128), 256, 0, stream>>>(
      attnp1, attnp2, woT1, woT2, ao, DMODEL, DMODEL, OUTSCL);
  attnres_kernel<<<NTOK, 256, 0, stream>>>(x, ao, g_post_mqa, g_pre_moe, x2, hbuf);

  // ---- router + grouped MoE (bf16 MFMA, atomic-free combine) ----
  hipMemsetAsync(counts, 0, 32, stream);
  router_kernel<<<NTOK, 64, 0, stream>>>(x2, g_pre_moe, Wg, out_probs, tok_l, w_l, counts);
  prefix_kernel<<<1, 64, 0, stream>>>(counts, bases);
  moe_gemm1_kernel<<<dim3(HIDD/128, NTOK/128, NE), 256, 0, stream>>>(
      hbuf, we1t, tok_l, counts, bases, mid);
  moe_gemm2_kernel<<<dim3(DMODEL/128, NTOK/128, NE), 256, 0, stream>>>(
      mid, we2t, tok_l, w_l, counts, bases, eo);
  final_kernel<<<NTOK, 256, 0, stream>>>(x2, eo, g_post_moe, out_x);
}

// Round 6
// 839.750 us; speedup vs baseline: 1.8831x; 1.0650x over previous
//
#include <hip/hip_runtime.h>
#include <hip/hip_bf16.h>
#include <math.h>

#define NTOK   4096
#define DMODEL 1024
#define SEQL   2048
#define QKVW   1152     // 1024 q + 64 k + 64 v
#define NH     16
#define HDIM   64
#define NE     8
#define HIDD   4096
#define EPSV   1e-5f
#define KT     32       // attention kv-tile

// fp16 GEMM scales: activations *2^8, weights *2^12 (keeps split-2 second
// pieces out of fp16-subnormal range); folded out via OUTSCL.
#define ASCL   256.f
#define WSCL   4096.f
#define OUTSCL (1.f/1048576.f)          // 2^-20

typedef __attribute__((ext_vector_type(8))) short bf16x8;
typedef __attribute__((ext_vector_type(8))) _Float16 f16x8;
typedef __attribute__((ext_vector_type(4))) _Float16 f16x4;
typedef __attribute__((ext_vector_type(4))) float f32x4;

#define GLOBAL_AS __attribute__((address_space(1)))
#define LDS_AS    __attribute__((address_space(3)))
// async global->LDS DMA, 16B/lane; LDS dest = wave-uniform base + lane*16,
// global source is per-lane (m97 pattern).
__device__ __forceinline__ void gl_lds16(const void* g, void* l){
  __builtin_amdgcn_global_load_lds((const GLOBAL_AS void*)g, (LDS_AS void*)l, 16u, 0, 0u);
}

__device__ __forceinline__ short f2b(float x){
  __hip_bfloat16 h = __float2bfloat16(x);
  return *reinterpret_cast<short*>(&h);
}
__device__ __forceinline__ float b2f(short s){
  __hip_bfloat16 h = *reinterpret_cast<__hip_bfloat16*>(&s);
  return __bfloat162float(h);
}
// 3-piece bf16 split: x ~= a+b+c to ~2^-26 rel (PROVEN rounds 2/4/5)
__device__ __forceinline__ void split3(float x, short& a, short& b, short& c){
  a = f2b(x);
  float r1 = x - b2f(a);
  b = f2b(r1);
  float r2 = r1 - b2f(b);
  c = f2b(r2);
}
__device__ __forceinline__ void split2h(float x, _Float16& a, _Float16& b){
  a = (_Float16)x;
  b = (_Float16)(x - (float)a);
}

// ---------------- transpose fp32 [R][C] -> bf16 [C][R] (expert weights) ----------------
__global__ __launch_bounds__(256) void transpose_conv_kernel(
    const float* __restrict__ in, short* __restrict__ out,
    int R, int C, long inb, long outb)
{
  __shared__ float tile[32][33];
  in  += (size_t)blockIdx.z * inb;
  out += (size_t)blockIdx.z * outb;
  int c0 = blockIdx.x*32, r0 = blockIdx.y*32;
  int tx = threadIdx.x & 31, ty = threadIdx.x >> 5;
  #pragma unroll
  for (int i=0;i<4;i++)
    tile[ty+i*8][tx] = in[(size_t)(r0+ty+i*8)*C + c0+tx];
  __syncthreads();
  #pragma unroll
  for (int i=0;i<4;i++)
    out[(size_t)(c0+ty+i*8)*R + r0+tx] = f2b(tile[tx][ty+i*8]);
}

// ---------------- transpose fp32 [R][C] -> 2 fp16 planes [C+rowOff][outLD=R], *2^12 ----------------
__global__ __launch_bounds__(256) void transpose_split2f16_kernel(
    const float* __restrict__ in, _Float16* __restrict__ o1, _Float16* __restrict__ o2,
    int R, int C, int rowOff, int outLD)
{
  __shared__ float tile[32][33];
  int c0 = blockIdx.x*32, r0 = blockIdx.y*32;
  int tx = threadIdx.x & 31, ty = threadIdx.x >> 5;
  #pragma unroll
  for (int i=0;i<4;i++)
    tile[ty+i*8][tx] = in[(size_t)(r0+ty+i*8)*C + c0+tx];
  __syncthreads();
  #pragma unroll
  for (int i=0;i<4;i++){
    float v = tile[tx][ty+i*8] * WSCL;
    _Float16 a,b; split2h(v,a,b);
    size_t idx = (size_t)(c0+ty+i*8+rowOff)*outLD + r0+tx;
    o1[idx]=a; o2[idx]=b;
  }
}

// ---------------- rmsnorm(x)*g*2^8 -> 2 fp16 planes ----------------
__global__ __launch_bounds__(256) void rms_split2_kernel(
    const float* __restrict__ x, const float* __restrict__ g,
    _Float16* __restrict__ o1, _Float16* __restrict__ o2)
{
  int row = blockIdx.x, tid = threadIdx.x;
  const float4* xr = (const float4*)(x + (size_t)row*DMODEL);
  float4 v = xr[tid];
  float ss = v.x*v.x + v.y*v.y + v.z*v.z + v.w*v.w;
  #pragma unroll
  for (int off=32; off; off>>=1) ss += __shfl_down(ss, off);
  __shared__ float red[4];
  if ((tid&63)==0) red[tid>>6] = ss;
  __syncthreads();
  float rs = rsqrtf((red[0]+red[1]+red[2]+red[3])*(1.f/1024.f) + EPSV) * ASCL;
  float4 gv = ((const float4*)g)[tid];
  float o[4] = {v.x*rs*gv.x, v.y*rs*gv.y, v.z*rs*gv.z, v.w*rs*gv.w};
  f16x4 s1,s2;
  #pragma unroll
  for (int c=0;c<4;c++){ _Float16 a,b; split2h(o[c],a,b); s1[c]=a; s2[c]=b; }
  size_t base = (size_t)row*DMODEL + tid*4;
  *(f16x4*)(o1+base) = s1; *(f16x4*)(o2+base) = s2;
}

// ---------------- flat fp32 -> 3 bf16 planes (unscaled, for attention) ----------------
__global__ void split3_flat_kernel(const float* __restrict__ in,
    short* __restrict__ o1, short* __restrict__ o2, short* __restrict__ o3, int n4)
{
  int i = blockIdx.x*256 + threadIdx.x;
  if (i >= n4) return;
  float4 v = ((const float4*)in)[i];
  short4 s1,s2,s3;
  split3(v.x, s1.x, s2.x, s3.x);
  split3(v.y, s1.y, s2.y, s3.y);
  split3(v.z, s1.z, s2.z, s3.z);
  split3(v.w, s1.w, s2.w, s3.w);
  ((short4*)o1)[i]=s1; ((short4*)o2)[i]=s2; ((short4*)o3)[i]=s3;
}

// ---------------- V^T build: qkv fp32 [4096][1152] -> vt planes [2][64][2048] ----------------
__global__ __launch_bounds__(256) void vtrans_split3_kernel(
    const float* __restrict__ qkv,
    short* __restrict__ o1, short* __restrict__ o2, short* __restrict__ o3)
{
  __shared__ float tile[32][33];
  int s0 = blockIdx.x*32, d0 = blockIdx.y*32, b = blockIdx.z;
  int tx = threadIdx.x & 31, ty = threadIdx.x >> 5;
  #pragma unroll
  for (int i=0;i<4;i++)
    tile[ty+i*8][tx] = qkv[(size_t)(b*SEQL + s0+ty+i*8)*QKVW + DMODEL+HDIM + d0+tx];
  __syncthreads();
  #pragma unroll
  for (int i=0;i<4;i++){
    float v = tile[tx][ty+i*8];   // [s=tx][d=ty+i*8]
    short a,bs,c; split3(v,a,bs,c);
    size_t idx = (size_t)(b*HDIM + d0+ty+i*8)*SEQL + s0+tx;
    o1[idx]=a; o2[idx]=bs; o3[idx]=c;
  }
}

// ---------------- fp32-accurate GEMM via 3-pass fp16x2 MFMA + global_load_lds ----------------
// C[M][N] = (A @ B^T) * outscale ; A planes [M][K], B planes [N][K]. 128x128, BK=32.
__global__ __launch_bounds__(256) void gemm_f16x2_kernel(
    const _Float16* __restrict__ a1, const _Float16* __restrict__ a2,
    const _Float16* __restrict__ b1, const _Float16* __restrict__ b2,
    float* __restrict__ C, int K, int ldc, float outscale)
{
  __shared__ _Float16 lsA[2][128*32];
  __shared__ _Float16 lsB[2][128*32];
  int m0 = blockIdx.y*128, n0 = blockIdx.x*128;
  int tid = threadIdx.x, wave = tid>>6, lane = tid&63;
  int g = lane>>4, li = lane&15;
  int wm = (wave>>1)*64, wn = (wave&1)*64;
  const _Float16* Ap[2] = {a1,a2};
  const _Float16* Bp[2] = {b1,b2};
  int srow = wave*32 + (lane>>2), scol = (lane&3)*8;
  const _Float16* gA[2][2]; const _Float16* gB[2][2];
  #pragma unroll
  for (int p=0;p<2;p++)
    #pragma unroll
    for (int i=0;i<2;i++){
      gA[p][i] = Ap[p] + (size_t)(m0+srow+i*16)*K + scol;
      gB[p][i] = Bp[p] + (size_t)(n0+srow+i*16)*K + scol;
    }
  f32x4 acc[4][4] = {};
  for (int k0=0; k0<K; k0+=32){
    #pragma unroll
    for (int p=0;p<2;p++)
      #pragma unroll
      for (int i=0;i<2;i++){
        gl_lds16(gA[p][i]+k0, &lsA[p][(wave*32+i*16)*32]);
        gl_lds16(gB[p][i]+k0, &lsB[p][(wave*32+i*16)*32]);
      }
    __syncthreads();
    #pragma unroll
    for (int i=0;i<2;i++){
      f16x8 af[4];
      #pragma unroll
      for (int m=0;m<4;m++) af[m] = *(f16x8*)&lsA[i][(wm+m*16+li)*32 + g*8];
      #pragma unroll
      for (int j=0;j<2-i;j++){
        #pragma unroll
        for (int n=0;n<4;n++){
          f16x8 bfr = *(f16x8*)&lsB[j][(wn+n*16+li)*32 + g*8];
          #pragma unroll
          for (int m=0;m<4;m++)
            acc[m][n] = __builtin_amdgcn_mfma_f32_16x16x32_f16(af[m], bfr, acc[m][n], 0,0,0);
        }
      }
    }
    __syncthreads();
  }
  #pragma unroll
  for (int m=0;m<4;m++){
    int lr0 = wm + m*16 + g*4;
    #pragma unroll
    for (int n=0;n<4;n++){
      int col = n0 + wn + n*16 + li;
      #pragma unroll
      for (int r=0;r<4;r++)
        C[(size_t)(m0+lr0+r)*ldc + col] = acc[m][n][r]*outscale;
    }
  }
}

// ---------------- flash attention, bf16x3 6-pass MFMA, swapped QK^T, Q in registers ----------------
// QB=128: grid (16 qtiles, 16 heads, 2 batch), 256 thr (4 waves x 32 q-rows).
// LDS 26KB (K,V only); Q hoisted to 12 bf16x8 regs/lane; defer-max; fp16x2 epilogue.
__global__ __launch_bounds__(256) void attn_bf16x3_kernel(
    const short* __restrict__ q1, const short* __restrict__ q2, const short* __restrict__ q3,
    const short* __restrict__ v1, const short* __restrict__ v2, const short* __restrict__ v3,
    _Float16* __restrict__ o1, _Float16* __restrict__ o2)
{
  __shared__ short Ks[32*200];    // [kv][plane*64+d]
  __shared__ short Vs[64*104];    // [d][plane*32+kv]
  int qt = blockIdx.x, h = blockIdx.y, b = blockIdx.z;
  int tid = threadIdx.x, wave = tid>>6, lane = tid&63;
  int g = lane>>4, li = lane&15;
  size_t qbase = (size_t)b*SEQL + qt*128;
  const short* qsrc[3] = {q1,q2,q3};
  const short* vsrc[3] = {v1,v2,v3};
  // Q B-fragments hoisted to registers: [nf][plane][kk]
  bf16x8 qf[2][3][2];
  #pragma unroll
  for (int nf=0;nf<2;nf++){
    size_t qrow = qbase + wave*32 + nf*16 + li;
    #pragma unroll
    for (int j=0;j<3;j++)
      #pragma unroll
      for (int kk=0;kk<2;kk++)
        qf[nf][j][kk] = *(const bf16x8*)(qsrc[j] + qrow*QKVW + h*HDIM + kk*32 + g*8);
  }
  float m_run[2] = {-1e30f,-1e30f}, l_run[2] = {0.f,0.f};
  f32x4 acc_o[4][2] = {};
  int src1 = (((2*g)&3)<<4) + li;
  int src2 = (((2*g+1)&3)<<4) + li;
  bool hi_half = (g>=2);

  for (int kvt=0; kvt<SEQL/KT; kvt++){
    __syncthreads();
    #pragma unroll
    for (int i=0;i<3;i++){
      int c = tid + 256*i;
      { // K: 32 rows * 24 chunks
        int row = c/24, sub = c - row*24;
        int p = sub>>3, d = (sub&7)*8;
        *(bf16x8*)&Ks[row*200 + p*64 + d] =
          *(const bf16x8*)(qsrc[p] + ((size_t)b*SEQL + kvt*KT + row)*QKVW + DMODEL + d);
      }
      { // V^T: 64 rows * 12 chunks
        int row = c/12, sub = c - row*12;
        int p = sub>>2, s8 = (sub&3)*8;
        *(bf16x8*)&Vs[row*104 + p*32 + s8] =
          *(const bf16x8*)(vsrc[p] + ((size_t)b*HDIM + row)*SEQL + kvt*KT + s8);
      }
    }
    __syncthreads();
    // S^T = K . Q^T  (rows kv, cols q)
    f32x4 s_acc[2][2] = {};
    #pragma unroll
    for (int i=0;i<3;i++){
      #pragma unroll
      for (int kk=0;kk<2;kk++){
        bf16x8 af[2];
        #pragma unroll
        for (int mf=0;mf<2;mf++)
          af[mf] = *(bf16x8*)&Ks[(mf*16+li)*200 + i*64 + kk*32 + g*8];
        #pragma unroll
        for (int j=0;j<3-i;j++){
          #pragma unroll
          for (int nf=0;nf<2;nf++){
            #pragma unroll
            for (int mf=0;mf<2;mf++)
              s_acc[mf][nf] = __builtin_amdgcn_mfma_f32_16x16x32_bf16(af[mf], qf[nf][j][kk], s_acc[mf][nf], 0,0,0);
          }
        }
      }
    }
    // online softmax with defer-max (T13, THR=8)
    float p[2][2][4];
    #pragma unroll
    for (int nf=0;nf<2;nf++){
      float mx = -1e30f;
      #pragma unroll
      for (int mf=0;mf<2;mf++)
        #pragma unroll
        for (int r=0;r<4;r++) mx = fmaxf(mx, s_acc[mf][nf][r]);
      mx = fmaxf(mx, __shfl_xor(mx,16));
      mx = fmaxf(mx, __shfl_xor(mx,32));
      mx *= 0.125f;
      if (!__all(mx <= m_run[nf] + 8.f)){
        float mn = fmaxf(m_run[nf], mx);
        float al = __expf(m_run[nf] - mn);
        m_run[nf] = mn;
        l_run[nf] *= al;
        #pragma unroll
        for (int mfd=0; mfd<4; mfd++){
          acc_o[mfd][nf][0]*=al; acc_o[mfd][nf][1]*=al;
          acc_o[mfd][nf][2]*=al; acc_o[mfd][nf][3]*=al;
        }
      }
      float rsum = 0.f;
      #pragma unroll
      for (int mf=0;mf<2;mf++)
        #pragma unroll
        for (int r=0;r<4;r++){
          float pv = __expf(s_acc[mf][nf][r]*0.125f - m_run[nf]);
          p[mf][nf][r] = pv; rsum += pv;
        }
      rsum += __shfl_xor(rsum,16);
      rsum += __shfl_xor(rsum,32);
      l_run[nf] += rsum;
    }
    // gather this lane's B-frag kv-slice (kv = 8g..8g+7) and split to 3 planes
    bf16x8 fp_frag[2][3];
    #pragma unroll
    for (int nf=0;nf<2;nf++){
      float p8[8];
      #pragma unroll
      for (int jj=0;jj<4;jj++){
        float v0 = __shfl(p[0][nf][jj], src1);
        float vv1 = __shfl(p[1][nf][jj], src1);
        p8[jj] = hi_half ? vv1 : v0;
        float w0 = __shfl(p[0][nf][jj], src2);
        float w1 = __shfl(p[1][nf][jj], src2);
        p8[4+jj] = hi_half ? w1 : w0;
      }
      #pragma unroll
      for (int jj=0;jj<8;jj++){
        short xa,xb,xc; split3(p8[jj], xa,xb,xc);
        fp_frag[nf][0][jj]=xa; fp_frag[nf][1][jj]=xb; fp_frag[nf][2][jj]=xc;
      }
    }
    // O^T += V^T . P   (rows d, cols q)
    #pragma unroll
    for (int vj=0;vj<3;vj++){
      bf16x8 av[4];
      #pragma unroll
      for (int mfd=0;mfd<4;mfd++)
        av[mfd] = *(bf16x8*)&Vs[(mfd*16+li)*104 + vj*32 + g*8];
      #pragma unroll
      for (int pi=0; pi<3-vj; pi++)
        #pragma unroll
        for (int mfd=0;mfd<4;mfd++)
          #pragma unroll
          for (int nf=0;nf<2;nf++)
            acc_o[mfd][nf] = __builtin_amdgcn_mfma_f32_16x16x32_bf16(av[mfd], fp_frag[nf][pi], acc_o[mfd][nf], 0,0,0);
    }
  }
  // epilogue: attn*2^8, split2 -> fp16 planes (feeds fp16 Wo GEMM)
  #pragma unroll
  for (int nf=0;nf<2;nf++){
    float inv = ASCL/l_run[nf];
    size_t q = qbase + wave*32 + nf*16 + li;
    #pragma unroll
    for (int mfd=0;mfd<4;mfd++){
      int d0 = mfd*16 + g*4;
      f16x4 sa,sb;
      #pragma unroll
      for (int r=0;r<4;r++){
        _Float16 xa,xb; split2h(acc_o[mfd][nf][r]*inv, xa,xb);
        sa[r]=xa; sb[r]=xb;
      }
      size_t base = q*DMODEL + h*HDIM + d0;
      *(f16x4*)(o1+base)=sa; *(f16x4*)(o2+base)=sb;
    }
  }
}

// ---------------- x2 = x + rmsnorm(ao)*g_post ; h = bf16(rmsnorm(x2)*g_pre) ----------------
__global__ __launch_bounds__(256) void attnres_kernel(
    const float* __restrict__ x, const float* __restrict__ ao,
    const float* __restrict__ gpost, const float* __restrict__ gpre,
    float* __restrict__ x2, short* __restrict__ h)
{
  int row = blockIdx.x, tid = threadIdx.x;
  float4 a  = ((const float4*)(ao + (size_t)row*DMODEL))[tid];
  float4 xv = ((const float4*)(x  + (size_t)row*DMODEL))[tid];
  float ss = a.x*a.x + a.y*a.y + a.z*a.z + a.w*a.w;
  #pragma unroll
  for (int off=32; off; off>>=1) ss += __shfl_down(ss, off);
  __shared__ float red[4];
  if ((tid&63)==0) red[tid>>6] = ss;
  __syncthreads();
  float rs1 = rsqrtf((red[0]+red[1]+red[2]+red[3])*(1.f/1024.f) + EPSV);
  float4 gp = ((const float4*)gpost)[tid];
  float4 o;
  o.x = xv.x + a.x*rs1*gp.x; o.y = xv.y + a.y*rs1*gp.y;
  o.z = xv.z + a.z*rs1*gp.z; o.w = xv.w + a.w*rs1*gp.w;
  ((float4*)(x2 + (size_t)row*DMODEL))[tid] = o;
  float s2 = o.x*o.x + o.y*o.y + o.z*o.z + o.w*o.w;
  __syncthreads();
  #pragma unroll
  for (int off=32; off; off>>=1) s2 += __shfl_down(s2, off);
  if ((tid&63)==0) red[tid>>6] = s2;
  __syncthreads();
  float rs2 = rsqrtf((red[0]+red[1]+red[2]+red[3])*(1.f/1024.f) + EPSV);
  float4 gm = ((const float4*)gpre)[tid];
  short4 hs;
  hs.x = f2b(o.x*rs2*gm.x); hs.y = f2b(o.y*rs2*gm.y);
  hs.z = f2b(o.z*rs2*gm.z); hs.w = f2b(o.w*rs2*gm.w);
  *(short4*)(h + (size_t)row*DMODEL + tid*4) = hs;
}

// ---------------- router: top-2 lists with slot packed in bit 16 ----------------
__global__ __launch_bounds__(64) void router_kernel(
    const float* __restrict__ x2, const float* __restrict__ g, const float* __restrict__ Wg,
    float* __restrict__ probs_out, int* __restrict__ tok_list, float* __restrict__ w_list,
    int* __restrict__ counts)
{
  int t = blockIdx.x, lane = threadIdx.x;
  const float4* xr = (const float4*)(x2 + (size_t)t*DMODEL);
  float4 v[4]; float ss = 0.f;
  #pragma unroll
  for (int i=0;i<4;i++){ v[i] = xr[lane + 64*i];
    ss += v[i].x*v[i].x + v[i].y*v[i].y + v[i].z*v[i].z + v[i].w*v[i].w; }
  #pragma unroll
  for (int off=32; off; off>>=1) ss += __shfl_xor(ss, off);
  float rs = rsqrtf(ss*(1.f/1024.f) + EPSV);
  float le[8] = {0,0,0,0,0,0,0,0};
  #pragma unroll
  for (int i=0;i<4;i++){
    int jb = (lane + 64*i)*4;
    float hv[4] = {v[i].x, v[i].y, v[i].z, v[i].w};
    #pragma unroll
    for (int c=0;c<4;c++){
      float hj = hv[c]*rs*g[jb+c];
      const float* wrow = Wg + (size_t)(jb+c)*NE;
      #pragma unroll
      for (int ee=0;ee<8;ee++) le[ee] += hj*wrow[ee];
    }
  }
  #pragma unroll
  for (int ee=0;ee<8;ee++)
    #pragma unroll
    for (int off=32; off; off>>=1) le[ee] += __shfl_xor(le[ee], off);
  float mx = le[0];
  #pragma unroll
  for (int ee=1;ee<8;ee++) mx = fmaxf(mx, le[ee]);
  float p[8], s = 0.f;
  #pragma unroll
  for (int ee=0;ee<8;ee++){ p[ee] = expf(le[ee]-mx); s += p[ee]; }
  float inv = 1.f/s;
  #pragma unroll
  for (int ee=0;ee<8;ee++) p[ee] *= inv;
  if (lane < 8) probs_out[(size_t)t*NE + lane] = p[lane];
  if (lane == 0){
    int i1 = 0;
    #pragma unroll
    for (int ee=1;ee<8;ee++) if (p[ee] > p[i1]) i1 = ee;
    int i2 = (i1==0) ? 1 : 0;
    #pragma unroll
    for (int ee=0;ee<8;ee++) if (ee != i1 && p[ee] > p[i2]) i2 = ee;
    int pos = atomicAdd(&counts[i1], 1);
    tok_list[i1*NTOK+pos] = t;              // slot 0
    w_list[i1*NTOK+pos] = p[i1];
    pos = atomicAdd(&counts[i2], 1);
    tok_list[i2*NTOK+pos] = t | (1<<16);    // slot 1
    w_list[i2*NTOK+pos] = p[i2];
  }
}

__global__ void prefix_kernel(const int* __restrict__ counts, int* __restrict__ bases){
  if (threadIdx.x == 0){
    int a = 0;
    for (int ee=0;ee<8;ee++){ bases[ee] = a; a += counts[ee]; }
  }
}

// ---------------- MoE grouped GEMM1: mid = gelu(h @ We1[e]^T), global_load_lds ----------------
__global__ __launch_bounds__(256) void moe_gemm1_kernel(
    const short* __restrict__ h, const short* __restrict__ we1t,
    const int* __restrict__ tok_list, const int* __restrict__ counts,
    const int* __restrict__ bases, short* __restrict__ mid)
{
  int e = blockIdx.z;
  int cnt = counts[e];
  int m0 = blockIdx.y*128, n0 = blockIdx.x*128;
  if (m0 >= cnt) return;
  int base = bases[e];
  const short* Bt = we1t + (size_t)e*HIDD*DMODEL;
  const int* tl = tok_list + e*NTOK;
  __shared__ short lsA[128*32];
  __shared__ short lsB[128*32];
  int tid = threadIdx.x, wave = tid>>6, lane = tid&63;
  int li = lane&15, g = lane>>4;
  int wm = (wave>>1)*64, wn = (wave&1)*64;
  int srow = wave*32 + (lane>>2), scol = (lane&3)*8;
  const short* gA[2]; const short* gB[2];
  #pragma unroll
  for (int i=0;i<2;i++){
    int rr = min(m0+srow+i*16, cnt-1);
    gA[i] = h + (size_t)(tl[rr] & 0xFFFF)*DMODEL + scol;
    gB[i] = Bt + (size_t)(n0+srow+i*16)*DMODEL + scol;
  }
  f32x4 acc[4][4] = {};
  for (int k0=0; k0<DMODEL; k0+=32){
    #pragma unroll
    for (int i=0;i<2;i++){
      gl_lds16(gA[i]+k0, &lsA[(wave*32+i*16)*32]);
      gl_lds16(gB[i]+k0, &lsB[(wave*32+i*16)*32]);
    }
    __syncthreads();
    bf16x8 af[4], bfr[4];
    #pragma unroll
    for (int m=0;m<4;m++) af[m] = *(bf16x8*)&lsA[(wm+m*16+li)*32 + g*8];
    #pragma unroll
    for (int n=0;n<4;n++) bfr[n] = *(bf16x8*)&lsB[(wn+n*16+li)*32 + g*8];
    #pragma unroll
    for (int m=0;m<4;m++)
      #pragma unroll
      for (int n=0;n<4;n++)
        acc[m][n] = __builtin_amdgcn_mfma_f32_16x16x32_bf16(af[m], bfr[n], acc[m][n], 0,0,0);
    __syncthreads();
  }
  #pragma unroll
  for (int m=0;m<4;m++){
    int lr0 = wm + m*16 + (g<<2);
    #pragma unroll
    for (int n=0;n<4;n++){
      int col = n0 + wn + n*16 + li;
      #pragma unroll
      for (int r=0;r<4;r++){
        int gr = m0 + lr0 + r;
        if (gr < cnt){
          float tval = acc[m][n][r];
          // gelu(t) = t * sigmoid(1.59577*(t + 0.044715 t^3))  (exact tanh identity)
          float u = 1.5957691216057308f*(tval + 0.044715f*tval*tval*tval);
          float ge = tval / (1.f + __expf(-u));
          mid[(size_t)(base+gr)*HIDD + col] = f2b(ge);
        }
      }
    }
  }
}

// ---------------- MoE grouped GEMM2: eo[slot][tok] = w*(mid @ We2[e]^T), global_load_lds ----------------
__global__ __launch_bounds__(256) void moe_gemm2_kernel(
    const short* __restrict__ mid, const short* __restrict__ we2t,
    const int* __restrict__ tok_list, const float* __restrict__ w_list,
    const int* __restrict__ counts, const int* __restrict__ bases,
    float* __restrict__ eo)
{
  int e = blockIdx.z;
  int cnt = counts[e];
  int m0 = blockIdx.y*128, n0 = blockIdx.x*128;
  if (m0 >= cnt) return;
  int base = bases[e];
  const short* A  = mid + (size_t)base*HIDD;
  const short* Bt = we2t + (size_t)e*DMODEL*HIDD;
  const int* tl = tok_list + e*NTOK;
  const float* wl = w_list + e*NTOK;
  __shared__ short lsA[128*32];
  __shared__ short lsB[128*32];
  int tid = threadIdx.x, wave = tid>>6, lane = tid&63;
  int li = lane&15, g = lane>>4;
  int wm = (wave>>1)*64, wn = (wave&1)*64;
  int srow = wave*32 + (lane>>2), scol = (lane&3)*8;
  const short* gA[2]; const short* gB[2];
  #pragma unroll
  for (int i=0;i<2;i++){
    int rr = min(m0+srow+i*16, cnt-1);
    gA[i] = A + (size_t)rr*HIDD + scol;
    gB[i] = Bt + (size_t)(n0+srow+i*16)*HIDD + scol;
  }
  f32x4 acc[4][4] = {};
  for (int k0=0; k0<HIDD; k0+=32){
    #pragma unroll
    for (int i=0;i<2;i++){
      gl_lds16(gA[i]+k0, &lsA[(wave*32+i*16)*32]);
      gl_lds16(gB[i]+k0, &lsB[(wave*32+i*16)*32]);
    }
    __syncthreads();
    bf16x8 af[4], bfr[4];
    #pragma unroll
    for (int m=0;m<4;m++) af[m] = *(bf16x8*)&lsA[(wm+m*16+li)*32 + g*8];
    #pragma unroll
    for (int n=0;n<4;n++) bfr[n] = *(bf16x8*)&lsB[(wn+n*16+li)*32 + g*8];
    #pragma unroll
    for (int m=0;m<4;m++)
      #pragma unroll
      for (int n=0;n<4;n++)
        acc[m][n] = __builtin_amdgcn_mfma_f32_16x16x32_bf16(af[m], bfr[n], acc[m][n], 0,0,0);
    __syncthreads();
  }
  #pragma unroll
  for (int m=0;m<4;m++){
    int lr0 = wm + m*16 + (g<<2);
    #pragma unroll
    for (int n=0;n<4;n++){
      int col = n0 + wn + n*16 + li;
      #pragma unroll
      for (int r=0;r<4;r++){
        int gr = m0 + lr0 + r;
        if (gr < cnt){
          int pv = tl[gr];
          eo[((size_t)(pv>>16)*NTOK + (pv & 0xFFFF))*DMODEL + col] = wl[gr]*acc[m][n][r];
        }
      }
    }
  }
}

// ---------------- out = x2 + rmsnorm(eo0+eo1)*g_post_moe ----------------
__global__ __launch_bounds__(256) void final_kernel(
    const float* __restrict__ x2, const float* __restrict__ eo,
    const float* __restrict__ g, float* __restrict__ out)
{
  int row = blockIdx.x, tid = threadIdx.x;
  float4 m0 = ((const float4*)(eo + (size_t)row*DMODEL))[tid];
  float4 m1 = ((const float4*)(eo + (size_t)(NTOK+row)*DMODEL))[tid];
  float4 mv;
  mv.x = m0.x+m1.x; mv.y = m0.y+m1.y; mv.z = m0.z+m1.z; mv.w = m0.w+m1.w;
  float4 xv = ((const float4*)(x2  + (size_t)row*DMODEL))[tid];
  float ss = mv.x*mv.x + mv.y*mv.y + mv.z*mv.z + mv.w*mv.w;
  #pragma unroll
  for (int off=32; off; off>>=1) ss += __shfl_down(ss, off);
  __shared__ float red[4];
  if ((tid&63)==0) red[tid>>6] = ss;
  __syncthreads();
  float rs = rsqrtf((red[0]+red[1]+red[2]+red[3])*(1.f/1024.f) + EPSV);
  float4 gv = ((const float4*)g)[tid];
  float4 o;
  o.x = xv.x + mv.x*rs*gv.x; o.y = xv.y + mv.y*rs*gv.y;
  o.z = xv.z + mv.z*rs*gv.z; o.w = xv.w + mv.w*rs*gv.w;
  ((float4*)(out + (size_t)row*DMODEL))[tid] = o;
}

extern "C" void kernel_launch(void* const* d_in, const int* in_sizes, int n_in,
                              void* d_out, int out_size, void* d_ws, size_t ws_size,
                              hipStream_t stream) {
  (void)in_sizes; (void)n_in; (void)out_size; (void)ws_size;
  const float* x          = (const float*)d_in[0];
  const float* g_pre_mqa  = (const float*)d_in[1];
  const float* g_post_mqa = (const float*)d_in[2];
  const float* g_pre_moe  = (const float*)d_in[3];
  const float* g_post_moe = (const float*)d_in[4];
  const float* Wq         = (const float*)d_in[5];
  const float* Wk         = (const float*)d_in[6];
  const float* Wv         = (const float*)d_in[7];
  const float* Wo         = (const float*)d_in[8];
  const float* Wg         = (const float*)d_in[9];
  const float* We1        = (const float*)d_in[10];
  const float* We2        = (const float*)d_in[11];

  float* out_x = (float*)d_out;
  float* out_probs = out_x + (size_t)NTOK*DMODEL;

  char* p = (char*)d_ws;
  size_t off = 0;
  auto alloc = [&](size_t bytes)->char*{
    char* r = p + off; off = (off + bytes + 255) & ~(size_t)255; return r; };

  short* we1t = (short*)alloc((size_t)NE*HIDD*DMODEL*2);       // 64M
  short* we2t = (short*)alloc((size_t)NE*DMODEL*HIDD*2);       // 64M
  short* mid  = (short*)alloc((size_t)2*NTOK*HIDD*2);          // 64M

  // region A: xn1 fp16 planes (2x8.4M), later ao fp32 (16.8M)
  char* regA = alloc((size_t)2*NTOK*DMODEL*2);
  _Float16* xn1p1 = (_Float16*)regA;
  _Float16* xn1p2 = (_Float16*)(regA + (size_t)NTOK*DMODEL*2);
  float* ao       = (float*)regA;

  _Float16* wqkvT1 = (_Float16*)alloc((size_t)QKVW*DMODEL*2);
  _Float16* wqkvT2 = (_Float16*)alloc((size_t)QKVW*DMODEL*2);
  _Float16* woT1   = (_Float16*)alloc((size_t)DMODEL*DMODEL*2);
  _Float16* woT2   = (_Float16*)alloc((size_t)DMODEL*DMODEL*2);

  // region B: qkv fp32 (18.9M), later attn fp16 planes (2x8.4M)
  char* regB = alloc((size_t)NTOK*QKVW*4);
  float* qkv = (float*)regB;
  _Float16* attnp1 = (_Float16*)regB;
  _Float16* attnp2 = (_Float16*)(regB + (size_t)NTOK*DMODEL*2);

  // region C: qkvs bf16 planes (3x9.4M=28.3M), later eo fp32 2 slabs (33.6M) + hbuf (8.4M)
  char* regC = alloc((size_t)2*NTOK*DMODEL*4 + (size_t)NTOK*DMODEL*2);
  short* qkvs1 = (short*)regC;
  short* qkvs2 = (short*)(regC + (size_t)NTOK*QKVW*2);
  short* qkvs3 = (short*)(regC + (size_t)2*NTOK*QKVW*2);
  float* eo    = (float*)regC;
  short* hbuf  = (short*)(regC + (size_t)2*NTOK*DMODEL*4);

  short* vt1 = (short*)alloc((size_t)2*HDIM*SEQL*2);
  short* vt2 = (short*)alloc((size_t)2*HDIM*SEQL*2);
  short* vt3 = (short*)alloc((size_t)2*HDIM*SEQL*2);
  float* x2  = (float*)alloc((size_t)NTOK*DMODEL*4);
  int*   tok_l  = (int*)  alloc((size_t)NE*NTOK*4);
  float* w_l    = (float*)alloc((size_t)NE*NTOK*4);
  int*   counts = (int*)  alloc(256);
  int*   bases  = (int*)  alloc(256);

  // ---- weights prep ----
  transpose_conv_kernel<<<dim3(HIDD/32, DMODEL/32, NE), 256, 0, stream>>>(
      We1, we1t, DMODEL, HIDD, (long)DMODEL*HIDD, (long)HIDD*DMODEL);
  transpose_conv_kernel<<<dim3(DMODEL/32, HIDD/32, NE), 256, 0, stream>>>(
      We2, we2t, HIDD, DMODEL, (long)HIDD*DMODEL, (long)DMODEL*HIDD);
  transpose_split2f16_kernel<<<dim3(DMODEL/32, DMODEL/32), 256, 0, stream>>>(
      Wq, wqkvT1, wqkvT2, DMODEL, DMODEL, 0, DMODEL);
  transpose_split2f16_kernel<<<dim3(HDIM/32, DMODEL/32), 256, 0, stream>>>(
      Wk, wqkvT1, wqkvT2, DMODEL, HDIM, DMODEL, DMODEL);
  transpose_split2f16_kernel<<<dim3(HDIM/32, DMODEL/32), 256, 0, stream>>>(
      Wv, wqkvT1, wqkvT2, DMODEL, HDIM, DMODEL+HDIM, DMODEL);
  transpose_split2f16_kernel<<<dim3(DMODEL/32, DMODEL/32), 256, 0, stream>>>(
      Wo, woT1, woT2, DMODEL, DMODEL, 0, DMODEL);

  // ---- pre-router chain: fp16x2 GEMMs + bf16x3 attention ----
  rms_split2_kernel<<<NTOK, 256, 0, stream>>>(x, g_pre_mqa, xn1p1, xn1p2);
  gemm_f16x2_kernel<<<dim3(QKVW/128, NTOK/128), 256, 0, stream>>>(
      xn1p1, xn1p2, wqkvT1, wqkvT2, qkv, DMODEL, QKVW, OUTSCL);
  split3_flat_kernel<<<(NTOK*QKVW/4 + 255)/256, 256, 0, stream>>>(
      qkv, qkvs1, qkvs2, qkvs3, NTOK*QKVW/4);
  vtrans_split3_kernel<<<dim3(SEQL/32, HDIM/32, 2), 256, 0, stream>>>(qkv, vt1, vt2, vt3);
  attn_bf16x3_kernel<<<dim3(SEQL/128, NH, 2), 256, 0, stream>>>(
      qkvs1, qkvs2, qkvs3, vt1, vt2, vt3, attnp1, attnp2);
  gemm_f16x2_kernel<<<dim3(DMODEL/128, NTOK/128), 256, 0, stream>>>(
      attnp1, attnp2, woT1, woT2, ao, DMODEL, DMODEL, OUTSCL);
  attnres_kernel<<<NTOK, 256, 0, stream>>>(x, ao, g_post_mqa, g_pre_moe, x2, hbuf);

  // ---- router + grouped MoE (bf16 MFMA, atomic-free combine) ----
  hipMemsetAsync(counts, 0, 32, stream);
  router_kernel<<<NTOK, 64, 0, stream>>>(x2, g_pre_moe, Wg, out_probs, tok_l, w_l, counts);
  prefix_kernel<<<1, 64, 0, stream>>>(counts, bases);
  moe_gemm1_kernel<<<dim3(HIDD/128, NTOK/128, NE), 256, 0, stream>>>(
      hbuf, we1t, tok_l, counts, bases, mid);
  moe_gemm2_kernel<<<dim3(DMODEL/128, NTOK/128, NE), 256, 0, stream>>>(
      mid, we2t, tok_l, w_l, counts, bases, eo);
  final_kernel<<<NTOK, 256, 0, stream>>>(x2, eo, g_post_moe, out_x);
}

// Round 7
// 805.295 us; speedup vs baseline: 1.9636x; 1.0428x over previous
//
#include <hip/hip_runtime.h>
#include <hip/hip_bf16.h>
#include <math.h>

#define NTOK   4096
#define DMODEL 1024
#define SEQL   2048
#define QKVW   1152     // 1024 q + 64 k + 64 v
#define NH     16
#define HDIM   64
#define NE     8
#define HIDD   4096
#define EPSV   1e-5f
#define KT     32       // attention kv-tile

// fp16 scales: activations *2^8, weights *2^12; folded out via OUTSCL.
#define ASCL   256.f
#define WSCL   4096.f
#define OUTSCL (1.f/1048576.f)          // 2^-20
#define SSCALE (0.125f/65536.f)         // 1/sqrt(64) * 2^-16 (Q,K both *2^8)

typedef __attribute__((ext_vector_type(8))) short bf16x8;
typedef __attribute__((ext_vector_type(8))) _Float16 f16x8;
typedef __attribute__((ext_vector_type(4))) _Float16 f16x4;
typedef __attribute__((ext_vector_type(4))) float f32x4;

#define GLOBAL_AS __attribute__((address_space(1)))
#define LDS_AS    __attribute__((address_space(3)))
__device__ __forceinline__ void gl_lds16(const void* g, void* l){
  __builtin_amdgcn_global_load_lds((const GLOBAL_AS void*)g, (LDS_AS void*)l, 16u, 0, 0u);
}

__device__ __forceinline__ short f2b(float x){
  __hip_bfloat16 h = __float2bfloat16(x);
  return *reinterpret_cast<short*>(&h);
}
__device__ __forceinline__ float b2f(short s){
  __hip_bfloat16 h = *reinterpret_cast<__hip_bfloat16*>(&s);
  return __bfloat162float(h);
}
// 3-piece bf16 split: x ~= a+b+c to ~2^-26 rel (PROVEN rounds 2/4/5/6)
__device__ __forceinline__ void split3(float x, short& a, short& b, short& c){
  a = f2b(x);
  float r1 = x - b2f(a);
  b = f2b(r1);
  float r2 = r1 - b2f(b);
  c = f2b(r2);
}
__device__ __forceinline__ void split2h(float x, _Float16& a, _Float16& b){
  a = (_Float16)x;
  b = (_Float16)(x - (float)a);
}

// ---------------- transpose fp32 [R][C] -> bf16 [C][R] (expert weights) ----------------
__global__ __launch_bounds__(256) void transpose_conv_kernel(
    const float* __restrict__ in, short* __restrict__ out,
    int R, int C, long inb, long outb)
{
  __shared__ float tile[32][33];
  in  += (size_t)blockIdx.z * inb;
  out += (size_t)blockIdx.z * outb;
  int c0 = blockIdx.x*32, r0 = blockIdx.y*32;
  int tx = threadIdx.x & 31, ty = threadIdx.x >> 5;
  #pragma unroll
  for (int i=0;i<4;i++)
    tile[ty+i*8][tx] = in[(size_t)(r0+ty+i*8)*C + c0+tx];
  __syncthreads();
  #pragma unroll
  for (int i=0;i<4;i++)
    out[(size_t)(c0+ty+i*8)*R + r0+tx] = f2b(tile[tx][ty+i*8]);
}

// ---------------- transpose fp32 [R][C] -> 2 fp16 planes [C+rowOff][outLD=R], *2^12 ----------------
__global__ __launch_bounds__(256) void transpose_split2f16_kernel(
    const float* __restrict__ in, _Float16* __restrict__ o1, _Float16* __restrict__ o2,
    int R, int C, int rowOff, int outLD)
{
  __shared__ float tile[32][33];
  int c0 = blockIdx.x*32, r0 = blockIdx.y*32;
  int tx = threadIdx.x & 31, ty = threadIdx.x >> 5;
  #pragma unroll
  for (int i=0;i<4;i++)
    tile[ty+i*8][tx] = in[(size_t)(r0+ty+i*8)*C + c0+tx];
  __syncthreads();
  #pragma unroll
  for (int i=0;i<4;i++){
    float v = tile[tx][ty+i*8] * WSCL;
    _Float16 a,b; split2h(v,a,b);
    size_t idx = (size_t)(c0+ty+i*8+rowOff)*outLD + r0+tx;
    o1[idx]=a; o2[idx]=b;
  }
}

// ---------------- rmsnorm(x)*g*2^8 -> 2 fp16 planes ----------------
__global__ __launch_bounds__(256) void rms_split2_kernel(
    const float* __restrict__ x, const float* __restrict__ g,
    _Float16* __restrict__ o1, _Float16* __restrict__ o2)
{
  int row = blockIdx.x, tid = threadIdx.x;
  const float4* xr = (const float4*)(x + (size_t)row*DMODEL);
  float4 v = xr[tid];
  float ss = v.x*v.x + v.y*v.y + v.z*v.z + v.w*v.w;
  #pragma unroll
  for (int off=32; off; off>>=1) ss += __shfl_down(ss, off);
  __shared__ float red[4];
  if ((tid&63)==0) red[tid>>6] = ss;
  __syncthreads();
  float rs = rsqrtf((red[0]+red[1]+red[2]+red[3])*(1.f/1024.f) + EPSV) * ASCL;
  float4 gv = ((const float4*)g)[tid];
  float o[4] = {v.x*rs*gv.x, v.y*rs*gv.y, v.z*rs*gv.z, v.w*rs*gv.w};
  f16x4 s1,s2;
  #pragma unroll
  for (int c=0;c<4;c++){ _Float16 a,b; split2h(o[c],a,b); s1[c]=a; s2[c]=b; }
  size_t base = (size_t)row*DMODEL + tid*4;
  *(f16x4*)(o1+base) = s1; *(f16x4*)(o2+base) = s2;
}

// ---------------- flat fp32 *2^8 -> 2 fp16 planes (Q/K for attention) ----------------
__global__ void split2_flat_kernel(const float* __restrict__ in,
    _Float16* __restrict__ o1, _Float16* __restrict__ o2, int n4)
{
  int i = blockIdx.x*256 + threadIdx.x;
  if (i >= n4) return;
  float4 v = ((const float4*)in)[i];
  float w[4] = {v.x*ASCL, v.y*ASCL, v.z*ASCL, v.w*ASCL};
  f16x4 s1,s2;
  #pragma unroll
  for (int c=0;c<4;c++){ _Float16 a,b; split2h(w[c],a,b); s1[c]=a; s2[c]=b; }
  ((f16x4*)o1)[i]=s1; ((f16x4*)o2)[i]=s2;
}

// ---------------- V^T build: qkv fp32 [4096][1152] -> vt bf16 planes [2][64][2048] ----------------
__global__ __launch_bounds__(256) void vtrans_split3_kernel(
    const float* __restrict__ qkv,
    short* __restrict__ o1, short* __restrict__ o2, short* __restrict__ o3)
{
  __shared__ float tile[32][33];
  int s0 = blockIdx.x*32, d0 = blockIdx.y*32, b = blockIdx.z;
  int tx = threadIdx.x & 31, ty = threadIdx.x >> 5;
  #pragma unroll
  for (int i=0;i<4;i++)
    tile[ty+i*8][tx] = qkv[(size_t)(b*SEQL + s0+ty+i*8)*QKVW + DMODEL+HDIM + d0+tx];
  __syncthreads();
  #pragma unroll
  for (int i=0;i<4;i++){
    float v = tile[tx][ty+i*8];   // [s=tx][d=ty+i*8]
    short a,bs,c; split3(v,a,bs,c);
    size_t idx = (size_t)(b*HDIM + d0+ty+i*8)*SEQL + s0+tx;
    o1[idx]=a; o2[idx]=bs; o3[idx]=c;
  }
}

// ---------------- fp32-accurate GEMM via 3-pass fp16x2 MFMA + global_load_lds (PROVEN r6) ----------------
__global__ __launch_bounds__(256) void gemm_f16x2_kernel(
    const _Float16* __restrict__ a1, const _Float16* __restrict__ a2,
    const _Float16* __restrict__ b1, const _Float16* __restrict__ b2,
    float* __restrict__ C, int K, int ldc, float outscale)
{
  __shared__ _Float16 lsA[2][128*32];
  __shared__ _Float16 lsB[2][128*32];
  int m0 = blockIdx.y*128, n0 = blockIdx.x*128;
  int tid = threadIdx.x, wave = tid>>6, lane = tid&63;
  int g = lane>>4, li = lane&15;
  int wm = (wave>>1)*64, wn = (wave&1)*64;
  const _Float16* Ap[2] = {a1,a2};
  const _Float16* Bp[2] = {b1,b2};
  int srow = wave*32 + (lane>>2), scol = (lane&3)*8;
  const _Float16* gA[2][2]; const _Float16* gB[2][2];
  #pragma unroll
  for (int p=0;p<2;p++)
    #pragma unroll
    for (int i=0;i<2;i++){
      gA[p][i] = Ap[p] + (size_t)(m0+srow+i*16)*K + scol;
      gB[p][i] = Bp[p] + (size_t)(n0+srow+i*16)*K + scol;
    }
  f32x4 acc[4][4] = {};
  for (int k0=0; k0<K; k0+=32){
    #pragma unroll
    for (int p=0;p<2;p++)
      #pragma unroll
      for (int i=0;i<2;i++){
        gl_lds16(gA[p][i]+k0, &lsA[p][(wave*32+i*16)*32]);
        gl_lds16(gB[p][i]+k0, &lsB[p][(wave*32+i*16)*32]);
      }
    __syncthreads();
    #pragma unroll
    for (int i=0;i<2;i++){
      f16x8 af[4];
      #pragma unroll
      for (int m=0;m<4;m++) af[m] = *(f16x8*)&lsA[i][(wm+m*16+li)*32 + g*8];
      #pragma unroll
      for (int j=0;j<2-i;j++){
        #pragma unroll
        for (int n=0;n<4;n++){
          f16x8 bfr = *(f16x8*)&lsB[j][(wn+n*16+li)*32 + g*8];
          #pragma unroll
          for (int m=0;m<4;m++)
            acc[m][n] = __builtin_amdgcn_mfma_f32_16x16x32_f16(af[m], bfr, acc[m][n], 0,0,0);
        }
      }
    }
    __syncthreads();
  }
  #pragma unroll
  for (int m=0;m<4;m++){
    int lr0 = wm + m*16 + g*4;
    #pragma unroll
    for (int n=0;n<4;n++){
      int col = n0 + wn + n*16 + li;
      #pragma unroll
      for (int r=0;r<4;r++)
        C[(size_t)(m0+lr0+r)*ldc + col] = acc[m][n][r]*outscale;
    }
  }
}

// ---------------- flash attention: fp16x2 QK^T (3-pass) + bf16x3 PV (6-pass, PROVEN) ----------------
// QB=128: grid (16 qtiles, 16 heads, 2 batch), 256 thr (4 waves x 32 q-rows).
// Q in regs (fp16 planes); K 2 fp16 planes in LDS; V 3 bf16 planes in LDS.
// Safe-by-construction: QK^T A and B both use the same lane->k slot rule
// (permutation cancels); PV unchanged from round 6.
__global__ __launch_bounds__(256) void attn_mix_kernel(
    const _Float16* __restrict__ q1, const _Float16* __restrict__ q2,
    const short* __restrict__ v1, const short* __restrict__ v2, const short* __restrict__ v3,
    _Float16* __restrict__ o1, _Float16* __restrict__ o2)
{
  __shared__ _Float16 Ks[32*136];  // [kv][plane*64+d], 2 fp16 planes
  __shared__ short Vs[64*104];     // [d][plane*32+kv], 3 bf16 planes
  int qt = blockIdx.x, h = blockIdx.y, b = blockIdx.z;
  int tid = threadIdx.x, wave = tid>>6, lane = tid&63;
  int g = lane>>4, li = lane&15;
  size_t qbase = (size_t)b*SEQL + qt*128;
  const _Float16* qsrc[2] = {q1,q2};
  const short* vsrc[3] = {v1,v2,v3};
  // Q B-fragments hoisted to registers: [nf][plane][kk]
  f16x8 qf[2][2][2];
  #pragma unroll
  for (int nf=0;nf<2;nf++){
    size_t qrow = qbase + wave*32 + nf*16 + li;
    #pragma unroll
    for (int j=0;j<2;j++)
      #pragma unroll
      for (int kk=0;kk<2;kk++)
        qf[nf][j][kk] = *(const f16x8*)(qsrc[j] + qrow*QKVW + h*HDIM + kk*32 + g*8);
  }
  float m_run[2] = {-1e30f,-1e30f}, l_run[2] = {0.f,0.f};
  f32x4 acc_o[4][2] = {};
  int src1 = (((2*g)&3)<<4) + li;
  int src2 = (((2*g+1)&3)<<4) + li;
  bool hi_half = (g>=2);

  for (int kvt=0; kvt<SEQL/KT; kvt++){
    __syncthreads();
    // K: 32 rows * 16 chunks (2 fp16 planes x 8 chunks of 8)
    #pragma unroll
    for (int i=0;i<2;i++){
      int c = tid + 256*i;
      int row = c>>4, sub = c&15;
      int p = sub>>3, d = (sub&7)*8;
      *(f16x8*)&Ks[row*136 + p*64 + d] =
        *(const f16x8*)(qsrc[p] + ((size_t)b*SEQL + kvt*KT + row)*QKVW + DMODEL + d);
    }
    // V^T: 64 rows * 12 chunks (3 bf16 planes x 4 chunks of 8)
    #pragma unroll
    for (int i=0;i<3;i++){
      int c = tid + 256*i;
      int row = c/12, sub = c - row*12;
      int p = sub>>2, s8 = (sub&3)*8;
      *(bf16x8*)&Vs[row*104 + p*32 + s8] =
        *(const bf16x8*)(vsrc[p] + ((size_t)b*HDIM + row)*SEQL + kvt*KT + s8);
    }
    __syncthreads();
    // S^T = K . Q^T  (rows kv, cols q), fp16x2 3-pass
    f32x4 s_acc[2][2] = {};
    #pragma unroll
    for (int i=0;i<2;i++){
      #pragma unroll
      for (int kk=0;kk<2;kk++){
        f16x8 af[2];
        #pragma unroll
        for (int mf=0;mf<2;mf++)
          af[mf] = *(f16x8*)&Ks[(mf*16+li)*136 + i*64 + kk*32 + g*8];
        #pragma unroll
        for (int j=0;j<2-i;j++){
          #pragma unroll
          for (int nf=0;nf<2;nf++){
            #pragma unroll
            for (int mf=0;mf<2;mf++)
              s_acc[mf][nf] = __builtin_amdgcn_mfma_f32_16x16x32_f16(af[mf], qf[nf][j][kk], s_acc[mf][nf], 0,0,0);
          }
        }
      }
    }
    // online softmax with defer-max (T13, THR=8); S carries 2^16 -> SSCALE
    float p[2][2][4];
    #pragma unroll
    for (int nf=0;nf<2;nf++){
      float mx = -1e30f;
      #pragma unroll
      for (int mf=0;mf<2;mf++)
        #pragma unroll
        for (int r=0;r<4;r++) mx = fmaxf(mx, s_acc[mf][nf][r]);
      mx = fmaxf(mx, __shfl_xor(mx,16));
      mx = fmaxf(mx, __shfl_xor(mx,32));
      mx *= SSCALE;
      if (!__all(mx <= m_run[nf] + 8.f)){
        float mn = fmaxf(m_run[nf], mx);
        float al = __expf(m_run[nf] - mn);
        m_run[nf] = mn;
        l_run[nf] *= al;
        #pragma unroll
        for (int mfd=0; mfd<4; mfd++){
          acc_o[mfd][nf][0]*=al; acc_o[mfd][nf][1]*=al;
          acc_o[mfd][nf][2]*=al; acc_o[mfd][nf][3]*=al;
        }
      }
      float rsum = 0.f;
      #pragma unroll
      for (int mf=0;mf<2;mf++)
        #pragma unroll
        for (int r=0;r<4;r++){
          float pv = __expf(s_acc[mf][nf][r]*SSCALE - m_run[nf]);
          p[mf][nf][r] = pv; rsum += pv;
        }
      rsum += __shfl_xor(rsum,16);
      rsum += __shfl_xor(rsum,32);
      l_run[nf] += rsum;
    }
    // gather this lane's B-frag kv-slice (kv = 8g..8g+7), split3 (bf16, PROVEN)
    bf16x8 fp_frag[2][3];
    #pragma unroll
    for (int nf=0;nf<2;nf++){
      float p8[8];
      #pragma unroll
      for (int jj=0;jj<4;jj++){
        float v0 = __shfl(p[0][nf][jj], src1);
        float vv1 = __shfl(p[1][nf][jj], src1);
        p8[jj] = hi_half ? vv1 : v0;
        float w0 = __shfl(p[0][nf][jj], src2);
        float w1 = __shfl(p[1][nf][jj], src2);
        p8[4+jj] = hi_half ? w1 : w0;
      }
      #pragma unroll
      for (int jj=0;jj<8;jj++){
        short xa,xb,xc; split3(p8[jj], xa,xb,xc);
        fp_frag[nf][0][jj]=xa; fp_frag[nf][1][jj]=xb; fp_frag[nf][2][jj]=xc;
      }
    }
    // O^T += V^T . P   (rows d, cols q), bf16x3 6-pass
    #pragma unroll
    for (int vj=0;vj<3;vj++){
      bf16x8 av[4];
      #pragma unroll
      for (int mfd=0;mfd<4;mfd++)
        av[mfd] = *(bf16x8*)&Vs[(mfd*16+li)*104 + vj*32 + g*8];
      #pragma unroll
      for (int pi=0; pi<3-vj; pi++)
        #pragma unroll
        for (int mfd=0;mfd<4;mfd++)
          #pragma unroll
          for (int nf=0;nf<2;nf++)
            acc_o[mfd][nf] = __builtin_amdgcn_mfma_f32_16x16x32_bf16(av[mfd], fp_frag[nf][pi], acc_o[mfd][nf], 0,0,0);
    }
  }
  // epilogue: attn*2^8, split2 -> fp16 planes (feeds fp16 Wo GEMM)
  #pragma unroll
  for (int nf=0;nf<2;nf++){
    float inv = ASCL/l_run[nf];
    size_t q = qbase + wave*32 + nf*16 + li;
    #pragma unroll
    for (int mfd=0;mfd<4;mfd++){
      int d0 = mfd*16 + g*4;
      f16x4 sa,sb;
      #pragma unroll
      for (int r=0;r<4;r++){
        _Float16 xa,xb; split2h(acc_o[mfd][nf][r]*inv, xa,xb);
        sa[r]=xa; sb[r]=xb;
      }
      size_t base = q*DMODEL + h*HDIM + d0;
      *(f16x4*)(o1+base)=sa; *(f16x4*)(o2+base)=sb;
    }
  }
}

// ---------------- x2 = x + rmsnorm(ao)*g_post ; h = bf16(rmsnorm(x2)*g_pre) ----------------
__global__ __launch_bounds__(256) void attnres_kernel(
    const float* __restrict__ x, const float* __restrict__ ao,
    const float* __restrict__ gpost, const float* __restrict__ gpre,
    float* __restrict__ x2, short* __restrict__ h)
{
  int row = blockIdx.x, tid = threadIdx.x;
  float4 a  = ((const float4*)(ao + (size_t)row*DMODEL))[tid];
  float4 xv = ((const float4*)(x  + (size_t)row*DMODEL))[tid];
  float ss = a.x*a.x + a.y*a.y + a.z*a.z + a.w*a.w;
  #pragma unroll
  for (int off=32; off; off>>=1) ss += __shfl_down(ss, off);
  __shared__ float red[4];
  if ((tid&63)==0) red[tid>>6] = ss;
  __syncthreads();
  float rs1 = rsqrtf((red[0]+red[1]+red[2]+red[3])*(1.f/1024.f) + EPSV);
  float4 gp = ((const float4*)gpost)[tid];
  float4 o;
  o.x = xv.x + a.x*rs1*gp.x; o.y = xv.y + a.y*rs1*gp.y;
  o.z = xv.z + a.z*rs1*gp.z; o.w = xv.w + a.w*rs1*gp.w;
  ((float4*)(x2 + (size_t)row*DMODEL))[tid] = o;
  float s2 = o.x*o.x + o.y*o.y + o.z*o.z + o.w*o.w;
  __syncthreads();
  #pragma unroll
  for (int off=32; off; off>>=1) s2 += __shfl_down(s2, off);
  if ((tid&63)==0) red[tid>>6] = s2;
  __syncthreads();
  float rs2 = rsqrtf((red[0]+red[1]+red[2]+red[3])*(1.f/1024.f) + EPSV);
  float4 gm = ((const float4*)gpre)[tid];
  short4 hs;
  hs.x = f2b(o.x*rs2*gm.x); hs.y = f2b(o.y*rs2*gm.y);
  hs.z = f2b(o.z*rs2*gm.z); hs.w = f2b(o.w*rs2*gm.w);
  *(short4*)(h + (size_t)row*DMODEL + tid*4) = hs;
}

// ---------------- router: top-2 lists with slot packed in bit 16 ----------------
__global__ __launch_bounds__(64) void router_kernel(
    const float* __restrict__ x2, const float* __restrict__ g, const float* __restrict__ Wg,
    float* __restrict__ probs_out, int* __restrict__ tok_list, float* __restrict__ w_list,
    int* __restrict__ counts)
{
  int t = blockIdx.x, lane = threadIdx.x;
  const float4* xr = (const float4*)(x2 + (size_t)t*DMODEL);
  float4 v[4]; float ss = 0.f;
  #pragma unroll
  for (int i=0;i<4;i++){ v[i] = xr[lane + 64*i];
    ss += v[i].x*v[i].x + v[i].y*v[i].y + v[i].z*v[i].z + v[i].w*v[i].w; }
  #pragma unroll
  for (int off=32; off; off>>=1) ss += __shfl_xor(ss, off);
  float rs = rsqrtf(ss*(1.f/1024.f) + EPSV);
  float le[8] = {0,0,0,0,0,0,0,0};
  #pragma unroll
  for (int i=0;i<4;i++){
    int jb = (lane + 64*i)*4;
    float hv[4] = {v[i].x, v[i].y, v[i].z, v[i].w};
    #pragma unroll
    for (int c=0;c<4;c++){
      float hj = hv[c]*rs*g[jb+c];
      const float* wrow = Wg + (size_t)(jb+c)*NE;
      #pragma unroll
      for (int ee=0;ee<8;ee++) le[ee] += hj*wrow[ee];
    }
  }
  #pragma unroll
  for (int ee=0;ee<8;ee++)
    #pragma unroll
    for (int off=32; off; off>>=1) le[ee] += __shfl_xor(le[ee], off);
  float mx = le[0];
  #pragma unroll
  for (int ee=1;ee<8;ee++) mx = fmaxf(mx, le[ee]);
  float p[8], s = 0.f;
  #pragma unroll
  for (int ee=0;ee<8;ee++){ p[ee] = expf(le[ee]-mx); s += p[ee]; }
  float inv = 1.f/s;
  #pragma unroll
  for (int ee=0;ee<8;ee++) p[ee] *= inv;
  if (lane < 8) probs_out[(size_t)t*NE + lane] = p[lane];
  if (lane == 0){
    int i1 = 0;
    #pragma unroll
    for (int ee=1;ee<8;ee++) if (p[ee] > p[i1]) i1 = ee;
    int i2 = (i1==0) ? 1 : 0;
    #pragma unroll
    for (int ee=0;ee<8;ee++) if (ee != i1 && p[ee] > p[i2]) i2 = ee;
    int pos = atomicAdd(&counts[i1], 1);
    tok_list[i1*NTOK+pos] = t;              // slot 0
    w_list[i1*NTOK+pos] = p[i1];
    pos = atomicAdd(&counts[i2], 1);
    tok_list[i2*NTOK+pos] = t | (1<<16);    // slot 1
    w_list[i2*NTOK+pos] = p[i2];
  }
}

__global__ void prefix_kernel(const int* __restrict__ counts, int* __restrict__ bases){
  if (threadIdx.x == 0){
    int a = 0;
    for (int ee=0;ee<8;ee++){ bases[ee] = a; a += counts[ee]; }
  }
}

// ---------------- MoE grouped GEMM1: mid = gelu(h @ We1[e]^T), global_load_lds ----------------
__global__ __launch_bounds__(256) void moe_gemm1_kernel(
    const short* __restrict__ h, const short* __restrict__ we1t,
    const int* __restrict__ tok_list, const int* __restrict__ counts,
    const int* __restrict__ bases, short* __restrict__ mid)
{
  int e = blockIdx.z;
  int cnt = counts[e];
  int m0 = blockIdx.y*128, n0 = blockIdx.x*128;
  if (m0 >= cnt) return;
  int base = bases[e];
  const short* Bt = we1t + (size_t)e*HIDD*DMODEL;
  const int* tl = tok_list + e*NTOK;
  __shared__ short lsA[128*32];
  __shared__ short lsB[128*32];
  int tid = threadIdx.x, wave = tid>>6, lane = tid&63;
  int li = lane&15, g = lane>>4;
  int wm = (wave>>1)*64, wn = (wave&1)*64;
  int srow = wave*32 + (lane>>2), scol = (lane&3)*8;
  const short* gA[2]; const short* gB[2];
  #pragma unroll
  for (int i=0;i<2;i++){
    int rr = min(m0+srow+i*16, cnt-1);
    gA[i] = h + (size_t)(tl[rr] & 0xFFFF)*DMODEL + scol;
    gB[i] = Bt + (size_t)(n0+srow+i*16)*DMODEL + scol;
  }
  f32x4 acc[4][4] = {};
  for (int k0=0; k0<DMODEL; k0+=32){
    #pragma unroll
    for (int i=0;i<2;i++){
      gl_lds16(gA[i]+k0, &lsA[(wave*32+i*16)*32]);
      gl_lds16(gB[i]+k0, &lsB[(wave*32+i*16)*32]);
    }
    __syncthreads();
    bf16x8 af[4], bfr[4];
    #pragma unroll
    for (int m=0;m<4;m++) af[m] = *(bf16x8*)&lsA[(wm+m*16+li)*32 + g*8];
    #pragma unroll
    for (int n=0;n<4;n++) bfr[n] = *(bf16x8*)&lsB[(wn+n*16+li)*32 + g*8];
    #pragma unroll
    for (int m=0;m<4;m++)
      #pragma unroll
      for (int n=0;n<4;n++)
        acc[m][n] = __builtin_amdgcn_mfma_f32_16x16x32_bf16(af[m], bfr[n], acc[m][n], 0,0,0);
    __syncthreads();
  }
  #pragma unroll
  for (int m=0;m<4;m++){
    int lr0 = wm + m*16 + (g<<2);
    #pragma unroll
    for (int n=0;n<4;n++){
      int col = n0 + wn + n*16 + li;
      #pragma unroll
      for (int r=0;r<4;r++){
        int gr = m0 + lr0 + r;
        if (gr < cnt){
          float tval = acc[m][n][r];
          float u = 1.5957691216057308f*(tval + 0.044715f*tval*tval*tval);
          float ge = tval / (1.f + __expf(-u));
          mid[(size_t)(base+gr)*HIDD + col] = f2b(ge);
        }
      }
    }
  }
}

// ---------------- MoE grouped GEMM2: eo[slot][tok] = w*(mid @ We2[e]^T), global_load_lds ----------------
__global__ __launch_bounds__(256) void moe_gemm2_kernel(
    const short* __restrict__ mid, const short* __restrict__ we2t,
    const int* __restrict__ tok_list, const float* __restrict__ w_list,
    const int* __restrict__ counts, const int* __restrict__ bases,
    float* __restrict__ eo)
{
  int e = blockIdx.z;
  int cnt = counts[e];
  int m0 = blockIdx.y*128, n0 = blockIdx.x*128;
  if (m0 >= cnt) return;
  int base = bases[e];
  const short* A  = mid + (size_t)base*HIDD;
  const short* Bt = we2t + (size_t)e*DMODEL*HIDD;
  const int* tl = tok_list + e*NTOK;
  const float* wl = w_list + e*NTOK;
  __shared__ short lsA[128*32];
  __shared__ short lsB[128*32];
  int tid = threadIdx.x, wave = tid>>6, lane = tid&63;
  int li = lane&15, g = lane>>4;
  int wm = (wave>>1)*64, wn = (wave&1)*64;
  int srow = wave*32 + (lane>>2), scol = (lane&3)*8;
  const short* gA[2]; const short* gB[2];
  #pragma unroll
  for (int i=0;i<2;i++){
    int rr = min(m0+srow+i*16, cnt-1);
    gA[i] = A + (size_t)rr*HIDD + scol;
    gB[i] = Bt + (size_t)(n0+srow+i*16)*HIDD + scol;
  }
  f32x4 acc[4][4] = {};
  for (int k0=0; k0<HIDD; k0+=32){
    #pragma unroll
    for (int i=0;i<2;i++){
      gl_lds16(gA[i]+k0, &lsA[(wave*32+i*16)*32]);
      gl_lds16(gB[i]+k0, &lsB[(wave*32+i*16)*32]);
    }
    __syncthreads();
    bf16x8 af[4], bfr[4];
    #pragma unroll
    for (int m=0;m<4;m++) af[m] = *(bf16x8*)&lsA[(wm+m*16+li)*32 + g*8];
    #pragma unroll
    for (int n=0;n<4;n++) bfr[n] = *(bf16x8*)&lsB[(wn+n*16+li)*32 + g*8];
    #pragma unroll
    for (int m=0;m<4;m++)
      #pragma unroll
      for (int n=0;n<4;n++)
        acc[m][n] = __builtin_amdgcn_mfma_f32_16x16x32_bf16(af[m], bfr[n], acc[m][n], 0,0,0);
    __syncthreads();
  }
  #pragma unroll
  for (int m=0;m<4;m++){
    int lr0 = wm + m*16 + (g<<2);
    #pragma unroll
    for (int n=0;n<4;n++){
      int col = n0 + wn + n*16 + li;
      #pragma unroll
      for (int r=0;r<4;r++){
        int gr = m0 + lr0 + r;
        if (gr < cnt){
          int pv = tl[gr];
          eo[((size_t)(pv>>16)*NTOK + (pv & 0xFFFF))*DMODEL + col] = wl[gr]*acc[m][n][r];
        }
      }
    }
  }
}

// ---------------- out = x2 + rmsnorm(eo0+eo1)*g_post_moe ----------------
__global__ __launch_bounds__(256) void final_kernel(
    const float* __restrict__ x2, const float* __restrict__ eo,
    const float* __restrict__ g, float* __restrict__ out)
{
  int row = blockIdx.x, tid = threadIdx.x;
  float4 m0 = ((const float4*)(eo + (size_t)row*DMODEL))[tid];
  float4 m1 = ((const float4*)(eo + (size_t)(NTOK+row)*DMODEL))[tid];
  float4 mv;
  mv.x = m0.x+m1.x; mv.y = m0.y+m1.y; mv.z = m0.z+m1.z; mv.w = m0.w+m1.w;
  float4 xv = ((const float4*)(x2  + (size_t)row*DMODEL))[tid];
  float ss = mv.x*mv.x + mv.y*mv.y + mv.z*mv.z + mv.w*mv.w;
  #pragma unroll
  for (int off=32; off; off>>=1) ss += __shfl_down(ss, off);
  __shared__ float red[4];
  if ((tid&63)==0) red[tid>>6] = ss;
  __syncthreads();
  float rs = rsqrtf((red[0]+red[1]+red[2]+red[3])*(1.f/1024.f) + EPSV);
  float4 gv = ((const float4*)g)[tid];
  float4 o;
  o.x = xv.x + mv.x*rs*gv.x; o.y = xv.y + mv.y*rs*gv.y;
  o.z = xv.z + mv.z*rs*gv.z; o.w = xv.w + mv.w*rs*gv.w;
  ((float4*)(out + (size_t)row*DMODEL))[tid] = o;
}

extern "C" void kernel_launch(void* const* d_in, const int* in_sizes, int n_in,
                              void* d_out, int out_size, void* d_ws, size_t ws_size,
                              hipStream_t stream) {
  (void)in_sizes; (void)n_in; (void)out_size; (void)ws_size;
  const float* x          = (const float*)d_in[0];
  const float* g_pre_mqa  = (const float*)d_in[1];
  const float* g_post_mqa = (const float*)d_in[2];
  const float* g_pre_moe  = (const float*)d_in[3];
  const float* g_post_moe = (const float*)d_in[4];
  const float* Wq         = (const float*)d_in[5];
  const float* Wk         = (const float*)d_in[6];
  const float* Wv         = (const float*)d_in[7];
  const float* Wo         = (const float*)d_in[8];
  const float* Wg         = (const float*)d_in[9];
  const float* We1        = (const float*)d_in[10];
  const float* We2        = (const float*)d_in[11];

  float* out_x = (float*)d_out;
  float* out_probs = out_x + (size_t)NTOK*DMODEL;

  char* p = (char*)d_ws;
  size_t off = 0;
  auto alloc = [&](size_t bytes)->char*{
    char* r = p + off; off = (off + bytes + 255) & ~(size_t)255; return r; };

  short* we1t = (short*)alloc((size_t)NE*HIDD*DMODEL*2);       // 64M
  short* we2t = (short*)alloc((size_t)NE*DMODEL*HIDD*2);       // 64M
  short* mid  = (short*)alloc((size_t)2*NTOK*HIDD*2);          // 64M

  // region A: xn1 fp16 planes (2x8.4M), later ao fp32 (16.8M)
  char* regA = alloc((size_t)2*NTOK*DMODEL*2);
  _Float16* xn1p1 = (_Float16*)regA;
  _Float16* xn1p2 = (_Float16*)(regA + (size_t)NTOK*DMODEL*2);
  float* ao       = (float*)regA;

  _Float16* wqkvT1 = (_Float16*)alloc((size_t)QKVW*DMODEL*2);
  _Float16* wqkvT2 = (_Float16*)alloc((size_t)QKVW*DMODEL*2);
  _Float16* woT1   = (_Float16*)alloc((size_t)DMODEL*DMODEL*2);
  _Float16* woT2   = (_Float16*)alloc((size_t)DMODEL*DMODEL*2);

  // region B: qkv fp32 (18.9M), later attn fp16 planes (2x8.4M)
  char* regB = alloc((size_t)NTOK*QKVW*4);
  float* qkv = (float*)regB;
  _Float16* attnp1 = (_Float16*)regB;
  _Float16* attnp2 = (_Float16*)(regB + (size_t)NTOK*DMODEL*2);

  // region C: qkvf fp16 planes (2x9.4M=18.9M), later eo fp32 2 slabs (33.6M) + hbuf (8.4M)
  char* regC = alloc((size_t)2*NTOK*DMODEL*4 + (size_t)NTOK*DMODEL*2);
  _Float16* qkvf1 = (_Float16*)regC;
  _Float16* qkvf2 = (_Float16*)(regC + (size_t)NTOK*QKVW*2);
  float* eo    = (float*)regC;
  short* hbuf  = (short*)(regC + (size_t)2*NTOK*DMODEL*4);

  short* vt1 = (short*)alloc((size_t)2*HDIM*SEQL*2);
  short* vt2 = (short*)alloc((size_t)2*HDIM*SEQL*2);
  short* vt3 = (short*)alloc((size_t)2*HDIM*SEQL*2);
  float* x2  = (float*)alloc((size_t)NTOK*DMODEL*4);
  int*   tok_l  = (int*)  alloc((size_t)NE*NTOK*4);
  float* w_l    = (float*)alloc((size_t)NE*NTOK*4);
  int*   counts = (int*)  alloc(256);
  int*   bases  = (int*)  alloc(256);

  // ---- weights prep ----
  transpose_conv_kernel<<<dim3(HIDD/32, DMODEL/32, NE), 256, 0, stream>>>(
      We1, we1t, DMODEL, HIDD, (long)DMODEL*HIDD, (long)HIDD*DMODEL);
  transpose_conv_kernel<<<dim3(DMODEL/32, HIDD/32, NE), 256, 0, stream>>>(
      We2, we2t, HIDD, DMODEL, (long)HIDD*DMODEL, (long)DMODEL*HIDD);
  transpose_split2f16_kernel<<<dim3(DMODEL/32, DMODEL/32), 256, 0, stream>>>(
      Wq, wqkvT1, wqkvT2, DMODEL, DMODEL, 0, DMODEL);
  transpose_split2f16_kernel<<<dim3(HDIM/32, DMODEL/32), 256, 0, stream>>>(
      Wk, wqkvT1, wqkvT2, DMODEL, HDIM, DMODEL, DMODEL);
  transpose_split2f16_kernel<<<dim3(HDIM/32, DMODEL/32), 256, 0, stream>>>(
      Wv, wqkvT1, wqkvT2, DMODEL, HDIM, DMODEL+HDIM, DMODEL);
  transpose_split2f16_kernel<<<dim3(DMODEL/32, DMODEL/32), 256, 0, stream>>>(
      Wo, woT1, woT2, DMODEL, DMODEL, 0, DMODEL);

  // ---- pre-router chain: fp16x2 GEMMs + mixed fp16-QK/bf16-PV attention ----
  rms_split2_kernel<<<NTOK, 256, 0, stream>>>(x, g_pre_mqa, xn1p1, xn1p2);
  gemm_f16x2_kernel<<<dim3(QKVW/128, NTOK/128), 256, 0, stream>>>(
      xn1p1, xn1p2, wqkvT1, wqkvT2, qkv, DMODEL, QKVW, OUTSCL);
  split2_flat_kernel<<<(NTOK*QKVW/4 + 255)/256, 256, 0, stream>>>(
      qkv, qkvf1, qkvf2, NTOK*QKVW/4);
  vtrans_split3_kernel<<<dim3(SEQL/32, HDIM/32, 2), 256, 0, stream>>>(qkv, vt1, vt2, vt3);
  attn_mix_kernel<<<dim3(SEQL/128, NH, 2), 256, 0, stream>>>(
      qkvf1, qkvf2, vt1, vt2, vt3, attnp1, attnp2);
  gemm_f16x2_kernel<<<dim3(DMODEL/128, NTOK/128), 256, 0, stream>>>(
      attnp1, attnp2, woT1, woT2, ao, DMODEL, DMODEL, OUTSCL);
  attnres_kernel<<<NTOK, 256, 0, stream>>>(x, ao, g_post_mqa, g_pre_moe, x2, hbuf);

  // ---- router + grouped MoE (bf16 MFMA, atomic-free combine) ----
  hipMemsetAsync(counts, 0, 32, stream);
  router_kernel<<<NTOK, 64, 0, stream>>>(x2, g_pre_moe, Wg, out_probs, tok_l, w_l, counts);
  prefix_kernel<<<1, 64, 0, stream>>>(counts, bases);
  moe_gemm1_kernel<<<dim3(HIDD/128, NTOK/128, NE), 256, 0, stream>>>(
      hbuf, we1t, tok_l, counts, bases, mid);
  moe_gemm2_kernel<<<dim3(DMODEL/128, NTOK/128, NE), 256, 0, stream>>>(
      mid, we2t, tok_l, w_l, counts, bases, eo);
  final_kernel<<<NTOK, 256, 0, stream>>>(x2, eo, g_post_moe, out_x);
}

// Round 8
// 771.943 us; speedup vs baseline: 2.0485x; 1.0432x over previous
//
#include <hip/hip_runtime.h>
#include <hip/hip_bf16.h>
#include <math.h>

#define NTOK   4096
#define DMODEL 1024
#define SEQL   2048
#define QKVW   1152     // 1024 q + 64 k + 64 v
#define NH     16
#define HDIM   64
#define NE     8
#define HIDD   4096
#define EPSV   1e-5f
#define KT     32       // attention kv-tile

// fp16 scales: activations *2^8, weights *2^12; folded out via OUTSCL.
// P scaled 2^15 via PBIAS; defer-max THR=0.5 keeps p_bar <= 2^15*e^0.5 = 54k < 65504.
#define ASCL   256.f
#define WSCL   4096.f
#define OUTSCL (1.f/1048576.f)          // 2^-20
#define SSCALE (0.125f/65536.f)         // 1/sqrt(64) * 2^-16 (Q,K both *2^8)
#define PBIAS  10.397207708399179f      // 15*ln2 -> P scaled 2^15
#define DTHR   0.5f                     // defer-max threshold (fp16-P overflow-safe)

typedef __attribute__((ext_vector_type(8))) short bf16x8;
typedef __attribute__((ext_vector_type(8))) _Float16 f16x8;
typedef __attribute__((ext_vector_type(4))) _Float16 f16x4;
typedef __attribute__((ext_vector_type(4))) float f32x4;

#define GLOBAL_AS __attribute__((address_space(1)))
#define LDS_AS    __attribute__((address_space(3)))
__device__ __forceinline__ void gl_lds16(const void* g, void* l){
  __builtin_amdgcn_global_load_lds((const GLOBAL_AS void*)g, (LDS_AS void*)l, 16u, 0, 0u);
}

__device__ __forceinline__ short f2b(float x){
  __hip_bfloat16 h = __float2bfloat16(x);
  return *reinterpret_cast<short*>(&h);
}
__device__ __forceinline__ void split2h(float x, _Float16& a, _Float16& b){
  a = (_Float16)x;
  b = (_Float16)(x - (float)a);
}

// ---------------- transpose fp32 [R][C] -> bf16 [C][R] (expert weights) ----------------
// vectorized: short4 stores (8B/lane) instead of per-element 2B stores.
__global__ __launch_bounds__(256) void transpose_conv_kernel(
    const float* __restrict__ in, short* __restrict__ out,
    int R, int C, long inb, long outb)
{
  __shared__ float tile[32][33];
  in  += (size_t)blockIdx.z * inb;
  out += (size_t)blockIdx.z * outb;
  int c0 = blockIdx.x*32, r0 = blockIdx.y*32;
  int tx = threadIdx.x & 31, ty = threadIdx.x >> 5;
  #pragma unroll
  for (int i=0;i<4;i++)
    tile[ty+i*8][tx] = in[(size_t)(r0+ty+i*8)*C + c0+tx];   // tile[r][c]
  __syncthreads();
  int cl = threadIdx.x >> 3, quad = threadIdx.x & 7;
  short4 s;
  s.x = f2b(tile[quad*4+0][cl]);
  s.y = f2b(tile[quad*4+1][cl]);
  s.z = f2b(tile[quad*4+2][cl]);
  s.w = f2b(tile[quad*4+3][cl]);
  *(short4*)&out[(size_t)(c0+cl)*R + r0 + quad*4] = s;
}

// ---------------- transpose fp32 [R][C] -> 2 fp16 planes [C+rowOff][outLD=R], *2^12 ----------------
__global__ __launch_bounds__(256) void transpose_split2f16_kernel(
    const float* __restrict__ in, _Float16* __restrict__ o1, _Float16* __restrict__ o2,
    int R, int C, int rowOff, int outLD)
{
  __shared__ float tile[32][33];
  int c0 = blockIdx.x*32, r0 = blockIdx.y*32;
  int tx = threadIdx.x & 31, ty = threadIdx.x >> 5;
  #pragma unroll
  for (int i=0;i<4;i++)
    tile[ty+i*8][tx] = in[(size_t)(r0+ty+i*8)*C + c0+tx];
  __syncthreads();
  #pragma unroll
  for (int i=0;i<4;i++){
    float v = tile[tx][ty+i*8] * WSCL;
    _Float16 va,vb; split2h(v,va,vb);
    size_t idx = (size_t)(c0+ty+i*8+rowOff)*outLD + r0+tx;
    o1[idx]=va; o2[idx]=vb;
  }
}

// ---------------- rmsnorm(x)*g*2^8 -> 2 fp16 planes ----------------
__global__ __launch_bounds__(256) void rms_split2_kernel(
    const float* __restrict__ x, const float* __restrict__ g,
    _Float16* __restrict__ o1, _Float16* __restrict__ o2)
{
  int row = blockIdx.x, tid = threadIdx.x;
  const float4* xr = (const float4*)(x + (size_t)row*DMODEL);
  float4 v = xr[tid];
  float ss = v.x*v.x + v.y*v.y + v.z*v.z + v.w*v.w;
  #pragma unroll
  for (int off=32; off; off>>=1) ss += __shfl_down(ss, off);
  __shared__ float red[4];
  if ((tid&63)==0) red[tid>>6] = ss;
  __syncthreads();
  float rs = rsqrtf((red[0]+red[1]+red[2]+red[3])*(1.f/1024.f) + EPSV) * ASCL;
  float4 gv = ((const float4*)g)[tid];
  float o[4] = {v.x*rs*gv.x, v.y*rs*gv.y, v.z*rs*gv.z, v.w*rs*gv.w};
  f16x4 s1,s2;
  #pragma unroll
  for (int c=0;c<4;c++){ _Float16 a,b; split2h(o[c],a,b); s1[c]=a; s2[c]=b; }
  size_t base = (size_t)row*DMODEL + tid*4;
  *(f16x4*)(o1+base) = s1; *(f16x4*)(o2+base) = s2;
}

// ---------------- flat fp32 *2^8 -> 2 fp16 planes (Q/K for attention) ----------------
__global__ void split2_flat_kernel(const float* __restrict__ in,
    _Float16* __restrict__ o1, _Float16* __restrict__ o2, int n4)
{
  int i = blockIdx.x*256 + threadIdx.x;
  if (i >= n4) return;
  float4 v = ((const float4*)in)[i];
  float w[4] = {v.x*ASCL, v.y*ASCL, v.z*ASCL, v.w*ASCL};
  f16x4 s1,s2;
  #pragma unroll
  for (int c=0;c<4;c++){ _Float16 a,b; split2h(w[c],a,b); s1[c]=a; s2[c]=b; }
  ((f16x4*)o1)[i]=s1; ((f16x4*)o2)[i]=s2;
}

// ---------------- V^T build: qkv fp32 -> vt fp16 planes [2][64][2048], *2^8 ----------------
// NOTE round-3 postmortem: the split outputs MUST NOT shadow the batch index.
__global__ __launch_bounds__(256) void vtrans_split2_kernel(
    const float* __restrict__ qkv,
    _Float16* __restrict__ o1, _Float16* __restrict__ o2)
{
  __shared__ float tile[32][33];
  int s0 = blockIdx.x*32, d0 = blockIdx.y*32, bb = blockIdx.z;
  int tx = threadIdx.x & 31, ty = threadIdx.x >> 5;
  #pragma unroll
  for (int i=0;i<4;i++)
    tile[ty+i*8][tx] = qkv[(size_t)(bb*SEQL + s0+ty+i*8)*QKVW + DMODEL+HDIM + d0+tx];
  __syncthreads();
  #pragma unroll
  for (int i=0;i<4;i++){
    float v = tile[tx][ty+i*8] * ASCL;   // [s=tx][d=ty+i*8]
    _Float16 va,vb; split2h(v,va,vb);
    size_t idx = (size_t)(bb*HDIM + d0+ty+i*8)*SEQL + s0+tx;
    o1[idx]=va; o2[idx]=vb;
  }
}

// ---------------- fp32-accurate GEMM via 3-pass fp16x2 MFMA + global_load_lds (PROVEN r6/r7) ----------------
__global__ __launch_bounds__(256) void gemm_f16x2_kernel(
    const _Float16* __restrict__ a1, const _Float16* __restrict__ a2,
    const _Float16* __restrict__ b1, const _Float16* __restrict__ b2,
    float* __restrict__ C, int K, int ldc, float outscale)
{
  __shared__ _Float16 lsA[2][128*32];
  __shared__ _Float16 lsB[2][128*32];
  int m0 = blockIdx.y*128, n0 = blockIdx.x*128;
  int tid = threadIdx.x, wave = tid>>6, lane = tid&63;
  int g = lane>>4, li = lane&15;
  int wm = (wave>>1)*64, wn = (wave&1)*64;
  const _Float16* Ap[2] = {a1,a2};
  const _Float16* Bp[2] = {b1,b2};
  int srow = wave*32 + (lane>>2), scol = (lane&3)*8;
  const _Float16* gA[2][2]; const _Float16* gB[2][2];
  #pragma unroll
  for (int p=0;p<2;p++)
    #pragma unroll
    for (int i=0;i<2;i++){
      gA[p][i] = Ap[p] + (size_t)(m0+srow+i*16)*K + scol;
      gB[p][i] = Bp[p] + (size_t)(n0+srow+i*16)*K + scol;
    }
  f32x4 acc[4][4] = {};
  for (int k0=0; k0<K; k0+=32){
    #pragma unroll
    for (int p=0;p<2;p++)
      #pragma unroll
      for (int i=0;i<2;i++){
        gl_lds16(gA[p][i]+k0, &lsA[p][(wave*32+i*16)*32]);
        gl_lds16(gB[p][i]+k0, &lsB[p][(wave*32+i*16)*32]);
      }
    __syncthreads();
    #pragma unroll
    for (int i=0;i<2;i++){
      f16x8 af[4];
      #pragma unroll
      for (int m=0;m<4;m++) af[m] = *(f16x8*)&lsA[i][(wm+m*16+li)*32 + g*8];
      #pragma unroll
      for (int j=0;j<2-i;j++){
        #pragma unroll
        for (int n=0;n<4;n++){
          f16x8 bfr = *(f16x8*)&lsB[j][(wn+n*16+li)*32 + g*8];
          #pragma unroll
          for (int m=0;m<4;m++)
            acc[m][n] = __builtin_amdgcn_mfma_f32_16x16x32_f16(af[m], bfr, acc[m][n], 0,0,0);
        }
      }
    }
    __syncthreads();
  }
  #pragma unroll
  for (int m=0;m<4;m++){
    int lr0 = wm + m*16 + g*4;
    #pragma unroll
    for (int n=0;n<4;n++){
      int col = n0 + wn + n*16 + li;
      #pragma unroll
      for (int r=0;r<4;r++)
        C[(size_t)(m0+lr0+r)*ldc + col] = acc[m][n][r]*outscale;
    }
  }
}

// ---------------- flash attention: fp16x2 QK^T + fp16x2 PV (both 3-pass), swapped QK^T ----------------
// QB=128: grid (16 qtiles, 16 heads, 2 batch), 256 thr (4 waves x 32 q-rows).
// Q in regs; K 2 fp16 planes LDS; V 2 fp16 planes (*2^8) LDS; P scaled 2^15 (PBIAS);
// defer-max THR=0.5 (fp16-P overflow bound). Epilogue 1/l_run -> attn*2^8.
__global__ __launch_bounds__(256) void attn_f16_kernel(
    const _Float16* __restrict__ q1, const _Float16* __restrict__ q2,
    const _Float16* __restrict__ v1, const _Float16* __restrict__ v2,
    _Float16* __restrict__ o1, _Float16* __restrict__ o2)
{
  __shared__ _Float16 Ks[32*136];  // [kv][plane*64+d]
  __shared__ _Float16 Vs[64*72];   // [d][plane*32+kv]
  int qt = blockIdx.x, h = blockIdx.y, b = blockIdx.z;
  int tid = threadIdx.x, wave = tid>>6, lane = tid&63;
  int g = lane>>4, li = lane&15;
  size_t qbase = (size_t)b*SEQL + qt*128;
  const _Float16* qsrc[2] = {q1,q2};
  const _Float16* vsrc[2] = {v1,v2};
  // Q B-fragments hoisted to registers: [nf][plane][kk]
  f16x8 qf[2][2][2];
  #pragma unroll
  for (int nf=0;nf<2;nf++){
    size_t qrow = qbase + wave*32 + nf*16 + li;
    #pragma unroll
    for (int j=0;j<2;j++)
      #pragma unroll
      for (int kk=0;kk<2;kk++)
        qf[nf][j][kk] = *(const f16x8*)(qsrc[j] + qrow*QKVW + h*HDIM + kk*32 + g*8);
  }
  float m_run[2] = {-1e30f,-1e30f}, l_run[2] = {0.f,0.f};
  f32x4 acc_o[4][2] = {};
  int src1 = (((2*g)&3)<<4) + li;
  int src2 = (((2*g+1)&3)<<4) + li;
  bool hi_half = (g>=2);

  for (int kvt=0; kvt<SEQL/KT; kvt++){
    __syncthreads();
    #pragma unroll
    for (int i=0;i<2;i++){
      int c = tid + 256*i;
      { // K: 32 rows * 16 chunks
        int row = c>>4, sub = c&15;
        int pl = sub>>3, d = (sub&7)*8;
        *(f16x8*)&Ks[row*136 + pl*64 + d] =
          *(const f16x8*)(qsrc[pl] + ((size_t)b*SEQL + kvt*KT + row)*QKVW + DMODEL + d);
      }
      { // V^T: 64 rows * 8 chunks
        int row = c>>3, sub = c&7;
        int pl = sub>>2, s8 = (sub&3)*8;
        *(f16x8*)&Vs[row*72 + pl*32 + s8] =
          *(const f16x8*)(vsrc[pl] + ((size_t)b*HDIM + row)*SEQL + kvt*KT + s8);
      }
    }
    __syncthreads();
    // S^T = K . Q^T  (rows kv, cols q), fp16x2 3-pass
    f32x4 s_acc[2][2] = {};
    #pragma unroll
    for (int i=0;i<2;i++){
      #pragma unroll
      for (int kk=0;kk<2;kk++){
        f16x8 af[2];
        #pragma unroll
        for (int mf=0;mf<2;mf++)
          af[mf] = *(f16x8*)&Ks[(mf*16+li)*136 + i*64 + kk*32 + g*8];
        #pragma unroll
        for (int j=0;j<2-i;j++){
          #pragma unroll
          for (int nf=0;nf<2;nf++){
            #pragma unroll
            for (int mf=0;mf<2;mf++)
              s_acc[mf][nf] = __builtin_amdgcn_mfma_f32_16x16x32_f16(af[mf], qf[nf][j][kk], s_acc[mf][nf], 0,0,0);
          }
        }
      }
    }
    // online softmax; P_bar = 2^15 * exp(s - m_run); defer-max THR=0.5
    float p[2][2][4];
    #pragma unroll
    for (int nf=0;nf<2;nf++){
      float mx = -1e30f;
      #pragma unroll
      for (int mf=0;mf<2;mf++)
        #pragma unroll
        for (int r=0;r<4;r++) mx = fmaxf(mx, s_acc[mf][nf][r]);
      mx = fmaxf(mx, __shfl_xor(mx,16));
      mx = fmaxf(mx, __shfl_xor(mx,32));
      mx *= SSCALE;
      if (!__all(mx <= m_run[nf] + DTHR)){
        float mn = fmaxf(m_run[nf], mx);
        float al = __expf(m_run[nf] - mn);
        m_run[nf] = mn;
        l_run[nf] *= al;
        #pragma unroll
        for (int mfd=0; mfd<4; mfd++){
          acc_o[mfd][nf][0]*=al; acc_o[mfd][nf][1]*=al;
          acc_o[mfd][nf][2]*=al; acc_o[mfd][nf][3]*=al;
        }
      }
      float rsum = 0.f;
      #pragma unroll
      for (int mf=0;mf<2;mf++)
        #pragma unroll
        for (int r=0;r<4;r++){
          float pv = __expf(s_acc[mf][nf][r]*SSCALE - m_run[nf] + PBIAS);
          p[mf][nf][r] = pv; rsum += pv;
        }
      rsum += __shfl_xor(rsum,16);
      rsum += __shfl_xor(rsum,32);
      l_run[nf] += rsum;
    }
    // gather this lane's B-frag kv-slice (kv = 8g..8g+7), split2 -> fp16 planes
    f16x8 fp_frag[2][2];
    #pragma unroll
    for (int nf=0;nf<2;nf++){
      float p8[8];
      #pragma unroll
      for (int jj=0;jj<4;jj++){
        float v0 = __shfl(p[0][nf][jj], src1);
        float vv1 = __shfl(p[1][nf][jj], src1);
        p8[jj] = hi_half ? vv1 : v0;
        float w0 = __shfl(p[0][nf][jj], src2);
        float w1 = __shfl(p[1][nf][jj], src2);
        p8[4+jj] = hi_half ? w1 : w0;
      }
      #pragma unroll
      for (int jj=0;jj<8;jj++){
        _Float16 xa,xb; split2h(p8[jj], xa,xb);
        fp_frag[nf][0][jj]=xa; fp_frag[nf][1][jj]=xb;
      }
    }
    // O^T += V^T . P   (rows d, cols q), fp16x2 3-pass
    #pragma unroll
    for (int vj=0;vj<2;vj++){
      f16x8 av[4];
      #pragma unroll
      for (int mfd=0;mfd<4;mfd++)
        av[mfd] = *(f16x8*)&Vs[(mfd*16+li)*72 + vj*32 + g*8];
      #pragma unroll
      for (int pi=0; pi<2-vj; pi++)
        #pragma unroll
        for (int mfd=0;mfd<4;mfd++)
          #pragma unroll
          for (int nf=0;nf<2;nf++)
            acc_o[mfd][nf] = __builtin_amdgcn_mfma_f32_16x16x32_f16(av[mfd], fp_frag[nf][pi], acc_o[mfd][nf], 0,0,0);
    }
  }
  // epilogue: acc_o/l_run = attn*2^8 (V carried 2^8; 2^15 P-scale cancels); split2 write
  #pragma unroll
  for (int nf=0;nf<2;nf++){
    float inv = 1.f/l_run[nf];
    size_t q = qbase + wave*32 + nf*16 + li;
    #pragma unroll
    for (int mfd=0;mfd<4;mfd++){
      int d0 = mfd*16 + g*4;
      f16x4 sa,sb;
      #pragma unroll
      for (int r=0;r<4;r++){
        _Float16 xa,xb; split2h(acc_o[mfd][nf][r]*inv, xa,xb);
        sa[r]=xa; sb[r]=xb;
      }
      size_t base = q*DMODEL + h*HDIM + d0;
      *(f16x4*)(o1+base)=sa; *(f16x4*)(o2+base)=sb;
    }
  }
}

// ---------------- x2 = x + rmsnorm(ao)*g_post ; h = bf16(rmsnorm(x2)*g_pre) ----------------
__global__ __launch_bounds__(256) void attnres_kernel(
    const float* __restrict__ x, const float* __restrict__ ao,
    const float* __restrict__ gpost, const float* __restrict__ gpre,
    float* __restrict__ x2, short* __restrict__ h)
{
  int row = blockIdx.x, tid = threadIdx.x;
  float4 a  = ((const float4*)(ao + (size_t)row*DMODEL))[tid];
  float4 xv = ((const float4*)(x  + (size_t)row*DMODEL))[tid];
  float ss = a.x*a.x + a.y*a.y + a.z*a.z + a.w*a.w;
  #pragma unroll
  for (int off=32; off; off>>=1) ss += __shfl_down(ss, off);
  __shared__ float red[4];
  if ((tid&63)==0) red[tid>>6] = ss;
  __syncthreads();
  float rs1 = rsqrtf((red[0]+red[1]+red[2]+red[3])*(1.f/1024.f) + EPSV);
  float4 gp = ((const float4*)gpost)[tid];
  float4 o;
  o.x = xv.x + a.x*rs1*gp.x; o.y = xv.y + a.y*rs1*gp.y;
  o.z = xv.z + a.z*rs1*gp.z; o.w = xv.w + a.w*rs1*gp.w;
  ((float4*)(x2 + (size_t)row*DMODEL))[tid] = o;
  float s2 = o.x*o.x + o.y*o.y + o.z*o.z + o.w*o.w;
  __syncthreads();
  #pragma unroll
  for (int off=32; off; off>>=1) s2 += __shfl_down(s2, off);
  if ((tid&63)==0) red[tid>>6] = s2;
  __syncthreads();
  float rs2 = rsqrtf((red[0]+red[1]+red[2]+red[3])*(1.f/1024.f) + EPSV);
  float4 gm = ((const float4*)gpre)[tid];
  short4 hs;
  hs.x = f2b(o.x*rs2*gm.x); hs.y = f2b(o.y*rs2*gm.y);
  hs.z = f2b(o.z*rs2*gm.z); hs.w = f2b(o.w*rs2*gm.w);
  *(short4*)(h + (size_t)row*DMODEL + tid*4) = hs;
}

// ---------------- router: top-2 lists with slot packed in bit 16 ----------------
__global__ __launch_bounds__(64) void router_kernel(
    const float* __restrict__ x2, const float* __restrict__ g, const float* __restrict__ Wg,
    float* __restrict__ probs_out, int* __restrict__ tok_list, float* __restrict__ w_list,
    int* __restrict__ counts)
{
  int t = blockIdx.x, lane = threadIdx.x;
  const float4* xr = (const float4*)(x2 + (size_t)t*DMODEL);
  float4 v[4]; float ss = 0.f;
  #pragma unroll
  for (int i=0;i<4;i++){ v[i] = xr[lane + 64*i];
    ss += v[i].x*v[i].x + v[i].y*v[i].y + v[i].z*v[i].z + v[i].w*v[i].w; }
  #pragma unroll
  for (int off=32; off; off>>=1) ss += __shfl_xor(ss, off);
  float rs = rsqrtf(ss*(1.f/1024.f) + EPSV);
  float le[8] = {0,0,0,0,0,0,0,0};
  #pragma unroll
  for (int i=0;i<4;i++){
    int jb = (lane + 64*i)*4;
    float hv[4] = {v[i].x, v[i].y, v[i].z, v[i].w};
    #pragma unroll
    for (int c=0;c<4;c++){
      float hj = hv[c]*rs*g[jb+c];
      const float* wrow = Wg + (size_t)(jb+c)*NE;
      #pragma unroll
      for (int ee=0;ee<8;ee++) le[ee] += hj*wrow[ee];
    }
  }
  #pragma unroll
  for (int ee=0;ee<8;ee++)
    #pragma unroll
    for (int off=32; off; off>>=1) le[ee] += __shfl_xor(le[ee], off);
  float mx = le[0];
  #pragma unroll
  for (int ee=1;ee<8;ee++) mx = fmaxf(mx, le[ee]);
  float p[8], s = 0.f;
  #pragma unroll
  for (int ee=0;ee<8;ee++){ p[ee] = expf(le[ee]-mx); s += p[ee]; }
  float inv = 1.f/s;
  #pragma unroll
  for (int ee=0;ee<8;ee++) p[ee] *= inv;
  if (lane < 8) probs_out[(size_t)t*NE + lane] = p[lane];
  if (lane == 0){
    int i1 = 0;
    #pragma unroll
    for (int ee=1;ee<8;ee++) if (p[ee] > p[i1]) i1 = ee;
    int i2 = (i1==0) ? 1 : 0;
    #pragma unroll
    for (int ee=0;ee<8;ee++) if (ee != i1 && p[ee] > p[i2]) i2 = ee;
    int pos = atomicAdd(&counts[i1], 1);
    tok_list[i1*NTOK+pos] = t;              // slot 0
    w_list[i1*NTOK+pos] = p[i1];
    pos = atomicAdd(&counts[i2], 1);
    tok_list[i2*NTOK+pos] = t | (1<<16);    // slot 1
    w_list[i2*NTOK+pos] = p[i2];
  }
}

__global__ void prefix_kernel(const int* __restrict__ counts, int* __restrict__ bases){
  if (threadIdx.x == 0){
    int a = 0;
    for (int ee=0;ee<8;ee++){ bases[ee] = a; a += counts[ee]; }
  }
}

// ---------------- MoE grouped GEMM1: mid = gelu(h @ We1[e]^T), global_load_lds ----------------
__global__ __launch_bounds__(256) void moe_gemm1_kernel(
    const short* __restrict__ h, const short* __restrict__ we1t,
    const int* __restrict__ tok_list, const int* __restrict__ counts,
    const int* __restrict__ bases, short* __restrict__ mid)
{
  int e = blockIdx.z;
  int cnt = counts[e];
  int m0 = blockIdx.y*128, n0 = blockIdx.x*128;
  if (m0 >= cnt) return;
  int base = bases[e];
  const short* Bt = we1t + (size_t)e*HIDD*DMODEL;
  const int* tl = tok_list + e*NTOK;
  __shared__ short lsA[128*32];
  __shared__ short lsB[128*32];
  int tid = threadIdx.x, wave = tid>>6, lane = tid&63;
  int li = lane&15, g = lane>>4;
  int wm = (wave>>1)*64, wn = (wave&1)*64;
  int srow = wave*32 + (lane>>2), scol = (lane&3)*8;
  const short* gA[2]; const short* gB[2];
  #pragma unroll
  for (int i=0;i<2;i++){
    int rr = min(m0+srow+i*16, cnt-1);
    gA[i] = h + (size_t)(tl[rr] & 0xFFFF)*DMODEL + scol;
    gB[i] = Bt + (size_t)(n0+srow+i*16)*DMODEL + scol;
  }
  f32x4 acc[4][4] = {};
  for (int k0=0; k0<DMODEL; k0+=32){
    #pragma unroll
    for (int i=0;i<2;i++){
      gl_lds16(gA[i]+k0, &lsA[(wave*32+i*16)*32]);
      gl_lds16(gB[i]+k0, &lsB[(wave*32+i*16)*32]);
    }
    __syncthreads();
    bf16x8 af[4], bfr[4];
    #pragma unroll
    for (int m=0;m<4;m++) af[m] = *(bf16x8*)&lsA[(wm+m*16+li)*32 + g*8];
    #pragma unroll
    for (int n=0;n<4;n++) bfr[n] = *(bf16x8*)&lsB[(wn+n*16+li)*32 + g*8];
    #pragma unroll
    for (int m=0;m<4;m++)
      #pragma unroll
      for (int n=0;n<4;n++)
        acc[m][n] = __builtin_amdgcn_mfma_f32_16x16x32_bf16(af[m], bfr[n], acc[m][n], 0,0,0);
    __syncthreads();
  }
  #pragma unroll
  for (int m=0;m<4;m++){
    int lr0 = wm + m*16 + (g<<2);
    #pragma unroll
    for (int n=0;n<4;n++){
      int col = n0 + wn + n*16 + li;
      #pragma unroll
      for (int r=0;r<4;r++){
        int gr = m0 + lr0 + r;
        if (gr < cnt){
          float tval = acc[m][n][r];
          float u = 1.5957691216057308f*(tval + 0.044715f*tval*tval*tval);
          float ge = tval / (1.f + __expf(-u));
          mid[(size_t)(base+gr)*HIDD + col] = f2b(ge);
        }
      }
    }
  }
}

// ---------------- MoE grouped GEMM2: eo[slot][tok] = w*(mid @ We2[e]^T), global_load_lds ----------------
__global__ __launch_bounds__(256) void moe_gemm2_kernel(
    const short* __restrict__ mid, const short* __restrict__ we2t,
    const int* __restrict__ tok_list, const float* __restrict__ w_list,
    const int* __restrict__ counts, const int* __restrict__ bases,
    float* __restrict__ eo)
{
  int e = blockIdx.z;
  int cnt = counts[e];
  int m0 = blockIdx.y*128, n0 = blockIdx.x*128;
  if (m0 >= cnt) return;
  int base = bases[e];
  const short* A  = mid + (size_t)base*HIDD;
  const short* Bt = we2t + (size_t)e*DMODEL*HIDD;
  const int* tl = tok_list + e*NTOK;
  const float* wl = w_list + e*NTOK;
  __shared__ short lsA[128*32];
  __shared__ short lsB[128*32];
  int tid = threadIdx.x, wave = tid>>6, lane = tid&63;
  int li = lane&15, g = lane>>4;
  int wm = (wave>>1)*64, wn = (wave&1)*64;
  int srow = wave*32 + (lane>>2), scol = (lane&3)*8;
  const short* gA[2]; const short* gB[2];
  #pragma unroll
  for (int i=0;i<2;i++){
    int rr = min(m0+srow+i*16, cnt-1);
    gA[i] = A + (size_t)rr*HIDD + scol;
    gB[i] = Bt + (size_t)(n0+srow+i*16)*HIDD + scol;
  }
  f32x4 acc[4][4] = {};
  for (int k0=0; k0<HIDD; k0+=32){
    #pragma unroll
    for (int i=0;i<2;i++){
      gl_lds16(gA[i]+k0, &lsA[(wave*32+i*16)*32]);
      gl_lds16(gB[i]+k0, &lsB[(wave*32+i*16)*32]);
    }
    __syncthreads();
    bf16x8 af[4], bfr[4];
    #pragma unroll
    for (int m=0;m<4;m++) af[m] = *(bf16x8*)&lsA[(wm+m*16+li)*32 + g*8];
    #pragma unroll
    for (int n=0;n<4;n++) bfr[n] = *(bf16x8*)&lsB[(wn+n*16+li)*32 + g*8];
    #pragma unroll
    for (int m=0;m<4;m++)
      #pragma unroll
      for (int n=0;n<4;n++)
        acc[m][n] = __builtin_amdgcn_mfma_f32_16x16x32_bf16(af[m], bfr[n], acc[m][n], 0,0,0);
    __syncthreads();
  }
  #pragma unroll
  for (int m=0;m<4;m++){
    int lr0 = wm + m*16 + (g<<2);
    #pragma unroll
    for (int n=0;n<4;n++){
      int col = n0 + wn + n*16 + li;
      #pragma unroll
      for (int r=0;r<4;r++){
        int gr = m0 + lr0 + r;
        if (gr < cnt){
          int pv = tl[gr];
          eo[((size_t)(pv>>16)*NTOK + (pv & 0xFFFF))*DMODEL + col] = wl[gr]*acc[m][n][r];
        }
      }
    }
  }
}

// ---------------- out = x2 + rmsnorm(eo0+eo1)*g_post_moe ----------------
__global__ __launch_bounds__(256) void final_kernel(
    const float* __restrict__ x2, const float* __restrict__ eo,
    const float* __restrict__ g, float* __restrict__ out)
{
  int row = blockIdx.x, tid = threadIdx.x;
  float4 m0 = ((const float4*)(eo + (size_t)row*DMODEL))[tid];
  float4 m1 = ((const float4*)(eo + (size_t)(NTOK+row)*DMODEL))[tid];
  float4 mv;
  mv.x = m0.x+m1.x; mv.y = m0.y+m1.y; mv.z = m0.z+m1.z; mv.w = m0.w+m1.w;
  float4 xv = ((const float4*)(x2  + (size_t)row*DMODEL))[tid];
  float ss = mv.x*mv.x + mv.y*mv.y + mv.z*mv.z + mv.w*mv.w;
  #pragma unroll
  for (int off=32; off; off>>=1) ss += __shfl_down(ss, off);
  __shared__ float red[4];
  if ((tid&63)==0) red[tid>>6] = ss;
  __syncthreads();
  float rs = rsqrtf((red[0]+red[1]+red[2]+red[3])*(1.f/1024.f) + EPSV);
  float4 gv = ((const float4*)g)[tid];
  float4 o;
  o.x = xv.x + mv.x*rs*gv.x; o.y = xv.y + mv.y*rs*gv.y;
  o.z = xv.z + mv.z*rs*gv.z; o.w = xv.w + mv.w*rs*gv.w;
  ((float4*)(out + (size_t)row*DMODEL))[tid] = o;
}

extern "C" void kernel_launch(void* const* d_in, const int* in_sizes, int n_in,
                              void* d_out, int out_size, void* d_ws, size_t ws_size,
                              hipStream_t stream) {
  (void)in_sizes; (void)n_in; (void)out_size; (void)ws_size;
  const float* x          = (const float*)d_in[0];
  const float* g_pre_mqa  = (const float*)d_in[1];
  const float* g_post_mqa = (const float*)d_in[2];
  const float* g_pre_moe  = (const float*)d_in[3];
  const float* g_post_moe = (const float*)d_in[4];
  const float* Wq         = (const float*)d_in[5];
  const float* Wk         = (const float*)d_in[6];
  const float* Wv         = (const float*)d_in[7];
  const float* Wo         = (const float*)d_in[8];
  const float* Wg         = (const float*)d_in[9];
  const float* We1        = (const float*)d_in[10];
  const float* We2        = (const float*)d_in[11];

  float* out_x = (float*)d_out;
  float* out_probs = out_x + (size_t)NTOK*DMODEL;

  char* p = (char*)d_ws;
  size_t off = 0;
  auto alloc = [&](size_t bytes)->char*{
    char* r = p + off; off = (off + bytes + 255) & ~(size_t)255; return r; };

  short* we1t = (short*)alloc((size_t)NE*HIDD*DMODEL*2);       // 64M
  short* we2t = (short*)alloc((size_t)NE*DMODEL*HIDD*2);       // 64M
  short* mid  = (short*)alloc((size_t)2*NTOK*HIDD*2);          // 64M

  // region A: xn1 fp16 planes (2x8.4M), later ao fp32 (16.8M)
  char* regA = alloc((size_t)2*NTOK*DMODEL*2);
  _Float16* xn1p1 = (_Float16*)regA;
  _Float16* xn1p2 = (_Float16*)(regA + (size_t)NTOK*DMODEL*2);
  float* ao       = (float*)regA;

  _Float16* wqkvT1 = (_Float16*)alloc((size_t)QKVW*DMODEL*2);
  _Float16* wqkvT2 = (_Float16*)alloc((size_t)QKVW*DMODEL*2);
  _Float16* woT1   = (_Float16*)alloc((size_t)DMODEL*DMODEL*2);
  _Float16* woT2   = (_Float16*)alloc((size_t)DMODEL*DMODEL*2);

  // region B: qkv fp32 (18.9M), later attn fp16 planes (2x8.4M)
  char* regB = alloc((size_t)NTOK*QKVW*4);
  float* qkv = (float*)regB;
  _Float16* attnp1 = (_Float16*)regB;
  _Float16* attnp2 = (_Float16*)(regB + (size_t)NTOK*DMODEL*2);

  // region C: qkvf fp16 planes (2x9.4M=18.9M), later eo fp32 2 slabs (33.6M) + hbuf (8.4M)
  char* regC = alloc((size_t)2*NTOK*DMODEL*4 + (size_t)NTOK*DMODEL*2);
  _Float16* qkvf1 = (_Float16*)regC;
  _Float16* qkvf2 = (_Float16*)(regC + (size_t)NTOK*QKVW*2);
  float* eo    = (float*)regC;
  short* hbuf  = (short*)(regC + (size_t)2*NTOK*DMODEL*4);

  _Float16* vt1 = (_Float16*)alloc((size_t)2*HDIM*SEQL*2);
  _Float16* vt2 = (_Float16*)alloc((size_t)2*HDIM*SEQL*2);
  float* x2  = (float*)alloc((size_t)NTOK*DMODEL*4);
  int*   tok_l  = (int*)  alloc((size_t)NE*NTOK*4);
  float* w_l    = (float*)alloc((size_t)NE*NTOK*4);
  int*   counts = (int*)  alloc(256);
  int*   bases  = (int*)  alloc(256);

  // ---- weights prep ----
  transpose_conv_kernel<<<dim3(HIDD/32, DMODEL/32, NE), 256, 0, stream>>>(
      We1, we1t, DMODEL, HIDD, (long)DMODEL*HIDD, (long)HIDD*DMODEL);
  transpose_conv_kernel<<<dim3(DMODEL/32, HIDD/32, NE), 256, 0, stream>>>(
      We2, we2t, HIDD, DMODEL, (long)HIDD*DMODEL, (long)DMODEL*HIDD);
  transpose_split2f16_kernel<<<dim3(DMODEL/32, DMODEL/32), 256, 0, stream>>>(
      Wq, wqkvT1, wqkvT2, DMODEL, DMODEL, 0, DMODEL);
  transpose_split2f16_kernel<<<dim3(HDIM/32, DMODEL/32), 256, 0, stream>>>(
      Wk, wqkvT1, wqkvT2, DMODEL, HDIM, DMODEL, DMODEL);
  transpose_split2f16_kernel<<<dim3(HDIM/32, DMODEL/32), 256, 0, stream>>>(
      Wv, wqkvT1, wqkvT2, DMODEL, HDIM, DMODEL+HDIM, DMODEL);
  transpose_split2f16_kernel<<<dim3(DMODEL/32, DMODEL/32), 256, 0, stream>>>(
      Wo, woT1, woT2, DMODEL, DMODEL, 0, DMODEL);

  // ---- pre-router chain: fp16x2 GEMMs + fp16 attention ----
  rms_split2_kernel<<<NTOK, 256, 0, stream>>>(x, g_pre_mqa, xn1p1, xn1p2);
  gemm_f16x2_kernel<<<dim3(QKVW/128, NTOK/128), 256, 0, stream>>>(
      xn1p1, xn1p2, wqkvT1, wqkvT2, qkv, DMODEL, QKVW, OUTSCL);
  split2_flat_kernel<<<(NTOK*QKVW/4 + 255)/256, 256, 0, stream>>>(
      qkv, qkvf1, qkvf2, NTOK*QKVW/4);
  vtrans_split2_kernel<<<dim3(SEQL/32, HDIM/32, 2), 256, 0, stream>>>(qkv, vt1, vt2);
  attn_f16_kernel<<<dim3(SEQL/128, NH, 2), 256, 0, stream>>>(
      qkvf1, qkvf2, vt1, vt2, attnp1, attnp2);
  gemm_f16x2_kernel<<<dim3(DMODEL/128, NTOK/128), 256, 0, stream>>>(
      attnp1, attnp2, woT1, woT2, ao, DMODEL, DMODEL, OUTSCL);
  attnres_kernel<<<NTOK, 256, 0, stream>>>(x, ao, g_post_mqa, g_pre_moe, x2, hbuf);

  // ---- router + grouped MoE (bf16 MFMA, atomic-free combine) ----
  hipMemsetAsync(counts, 0, 32, stream);
  router_kernel<<<NTOK, 64, 0, stream>>>(x2, g_pre_moe, Wg, out_probs, tok_l, w_l, counts);
  prefix_kernel<<<1, 64, 0, stream>>>(counts, bases);
  moe_gemm1_kernel<<<dim3(HIDD/128, NTOK/128, NE), 256, 0, stream>>>(
      hbuf, we1t, tok_l, counts, bases, mid);
  moe_gemm2_kernel<<<dim3(DMODEL/128, NTOK/128, NE), 256, 0, stream>>>(
      mid, we2t, tok_l, w_l, counts, bases, eo);
  final_kernel<<<NTOK, 256, 0, stream>>>(x2, eo, g_post_moe, out_x);
}

// Round 9
// 745.524 us; speedup vs baseline: 2.1210x; 1.0354x over previous
//
#include <hip/hip_runtime.h>
#include <hip/hip_bf16.h>
#include <math.h>

#define NTOK   4096
#define DMODEL 1024
#define SEQL   2048
#define QKVW   1152     // 1024 q + 64 k + 64 v
#define NH     16
#define HDIM   64
#define NE     8
#define HIDD   4096
#define EPSV   1e-5f
#define KT     32       // attention kv-tile

// fp16 scales: activations *2^8, weights *2^12; folded out via OUTSCL.
// P scaled 2^15 via PBIAS; defer-max THR=0.5 keeps p_bar <= 2^15*e^0.5 = 54k < 65504.
#define ASCL   256.f
#define WSCL   4096.f
#define OUTSCL (1.f/1048576.f)          // 2^-20
#define SSCALE (0.125f/65536.f)         // 1/sqrt(64) * 2^-16 (Q,K both *2^8)
#define PBIAS  10.397207708399179f      // 15*ln2 -> P scaled 2^15
#define DTHR   0.5f                     // defer-max threshold (fp16-P overflow-safe)

typedef __attribute__((ext_vector_type(8))) short bf16x8;
typedef __attribute__((ext_vector_type(8))) _Float16 f16x8;
typedef __attribute__((ext_vector_type(4))) _Float16 f16x4;
typedef __attribute__((ext_vector_type(4))) float f32x4;

#define GLOBAL_AS __attribute__((address_space(1)))
#define LDS_AS    __attribute__((address_space(3)))
__device__ __forceinline__ void gl_lds16(const void* g, void* l){
  __builtin_amdgcn_global_load_lds((const GLOBAL_AS void*)g, (LDS_AS void*)l, 16u, 0, 0u);
}

__device__ __forceinline__ short f2b(float x){
  __hip_bfloat16 h = __float2bfloat16(x);
  return *reinterpret_cast<short*>(&h);
}
__device__ __forceinline__ void split2h(float x, _Float16& a, _Float16& b){
  a = (_Float16)x;
  b = (_Float16)(x - (float)a);
}

// ---------------- transpose fp32 [R][C] -> bf16 [C][R] (expert weights), short4 stores ----------------
__global__ __launch_bounds__(256) void transpose_conv_kernel(
    const float* __restrict__ in, short* __restrict__ out,
    int R, int C, long inb, long outb)
{
  __shared__ float tile[32][33];
  in  += (size_t)blockIdx.z * inb;
  out += (size_t)blockIdx.z * outb;
  int c0 = blockIdx.x*32, r0 = blockIdx.y*32;
  int tx = threadIdx.x & 31, ty = threadIdx.x >> 5;
  #pragma unroll
  for (int i=0;i<4;i++)
    tile[ty+i*8][tx] = in[(size_t)(r0+ty+i*8)*C + c0+tx];   // tile[r][c]
  __syncthreads();
  int cl = threadIdx.x >> 3, quad = threadIdx.x & 7;
  short4 s;
  s.x = f2b(tile[quad*4+0][cl]);
  s.y = f2b(tile[quad*4+1][cl]);
  s.z = f2b(tile[quad*4+2][cl]);
  s.w = f2b(tile[quad*4+3][cl]);
  *(short4*)&out[(size_t)(c0+cl)*R + r0 + quad*4] = s;
}

// ---------------- transpose fp32 [R][C] -> 2 fp16 planes [C+rowOff][outLD=R], *2^12 ----------------
__global__ __launch_bounds__(256) void transpose_split2f16_kernel(
    const float* __restrict__ in, _Float16* __restrict__ o1, _Float16* __restrict__ o2,
    int R, int C, int rowOff, int outLD)
{
  __shared__ float tile[32][33];
  int c0 = blockIdx.x*32, r0 = blockIdx.y*32;
  int tx = threadIdx.x & 31, ty = threadIdx.x >> 5;
  #pragma unroll
  for (int i=0;i<4;i++)
    tile[ty+i*8][tx] = in[(size_t)(r0+ty+i*8)*C + c0+tx];
  __syncthreads();
  #pragma unroll
  for (int i=0;i<4;i++){
    float v = tile[tx][ty+i*8] * WSCL;
    _Float16 va,vb; split2h(v,va,vb);
    size_t idx = (size_t)(c0+ty+i*8+rowOff)*outLD + r0+tx;
    o1[idx]=va; o2[idx]=vb;
  }
}

// ---------------- rmsnorm(x)*g*2^8 -> 2 fp16 planes ----------------
__global__ __launch_bounds__(256) void rms_split2_kernel(
    const float* __restrict__ x, const float* __restrict__ g,
    _Float16* __restrict__ o1, _Float16* __restrict__ o2)
{
  int row = blockIdx.x, tid = threadIdx.x;
  const float4* xr = (const float4*)(x + (size_t)row*DMODEL);
  float4 v = xr[tid];
  float ss = v.x*v.x + v.y*v.y + v.z*v.z + v.w*v.w;
  #pragma unroll
  for (int off=32; off; off>>=1) ss += __shfl_down(ss, off);
  __shared__ float red[4];
  if ((tid&63)==0) red[tid>>6] = ss;
  __syncthreads();
  float rs = rsqrtf((red[0]+red[1]+red[2]+red[3])*(1.f/1024.f) + EPSV) * ASCL;
  float4 gv = ((const float4*)g)[tid];
  float o[4] = {v.x*rs*gv.x, v.y*rs*gv.y, v.z*rs*gv.z, v.w*rs*gv.w};
  f16x4 s1,s2;
  #pragma unroll
  for (int c=0;c<4;c++){ _Float16 a,b; split2h(o[c],a,b); s1[c]=a; s2[c]=b; }
  size_t base = (size_t)row*DMODEL + tid*4;
  *(f16x4*)(o1+base) = s1; *(f16x4*)(o2+base) = s2;
}

// ---------------- V^T build from qkv fp16 planes -> vt fp16 planes [2][64][2048] ----------------
// planes already carry *2^8; no rescale. (r3 postmortem: never shadow the batch index.)
__global__ __launch_bounds__(256) void vtrans_split2_kernel(
    const _Float16* __restrict__ p1, const _Float16* __restrict__ p2,
    _Float16* __restrict__ o1, _Float16* __restrict__ o2)
{
  __shared__ float tile[32][33];
  int s0 = blockIdx.x*32, d0 = blockIdx.y*32, bb = blockIdx.z;
  int tx = threadIdx.x & 31, ty = threadIdx.x >> 5;
  #pragma unroll
  for (int i=0;i<4;i++){
    size_t idx = (size_t)(bb*SEQL + s0+ty+i*8)*QKVW + DMODEL+HDIM + d0+tx;
    tile[ty+i*8][tx] = (float)p1[idx] + (float)p2[idx];
  }
  __syncthreads();
  #pragma unroll
  for (int i=0;i<4;i++){
    float v = tile[tx][ty+i*8];          // [s=tx][d=ty+i*8], already *2^8
    _Float16 va,vb; split2h(v,va,vb);
    size_t idx = (size_t)(bb*HDIM + d0+ty+i*8)*SEQL + s0+tx;
    o1[idx]=va; o2[idx]=vb;
  }
}

// ---------------- fp32-accurate GEMM via 3-pass fp16x2 MFMA + global_load_lds (PROVEN r6/r7) ----------------
__global__ __launch_bounds__(256) void gemm_f16x2_kernel(
    const _Float16* __restrict__ a1, const _Float16* __restrict__ a2,
    const _Float16* __restrict__ b1, const _Float16* __restrict__ b2,
    float* __restrict__ C, int K, int ldc, float outscale)
{
  __shared__ _Float16 lsA[2][128*32];
  __shared__ _Float16 lsB[2][128*32];
  int m0 = blockIdx.y*128, n0 = blockIdx.x*128;
  int tid = threadIdx.x, wave = tid>>6, lane = tid&63;
  int g = lane>>4, li = lane&15;
  int wm = (wave>>1)*64, wn = (wave&1)*64;
  const _Float16* Ap[2] = {a1,a2};
  const _Float16* Bp[2] = {b1,b2};
  int srow = wave*32 + (lane>>2), scol = (lane&3)*8;
  const _Float16* gA[2][2]; const _Float16* gB[2][2];
  #pragma unroll
  for (int p=0;p<2;p++)
    #pragma unroll
    for (int i=0;i<2;i++){
      gA[p][i] = Ap[p] + (size_t)(m0+srow+i*16)*K + scol;
      gB[p][i] = Bp[p] + (size_t)(n0+srow+i*16)*K + scol;
    }
  f32x4 acc[4][4] = {};
  for (int k0=0; k0<K; k0+=32){
    #pragma unroll
    for (int p=0;p<2;p++)
      #pragma unroll
      for (int i=0;i<2;i++){
        gl_lds16(gA[p][i]+k0, &lsA[p][(wave*32+i*16)*32]);
        gl_lds16(gB[p][i]+k0, &lsB[p][(wave*32+i*16)*32]);
      }
    __syncthreads();
    #pragma unroll
    for (int i=0;i<2;i++){
      f16x8 af[4];
      #pragma unroll
      for (int m=0;m<4;m++) af[m] = *(f16x8*)&lsA[i][(wm+m*16+li)*32 + g*8];
      #pragma unroll
      for (int j=0;j<2-i;j++){
        #pragma unroll
        for (int n=0;n<4;n++){
          f16x8 bfr = *(f16x8*)&lsB[j][(wn+n*16+li)*32 + g*8];
          #pragma unroll
          for (int m=0;m<4;m++)
            acc[m][n] = __builtin_amdgcn_mfma_f32_16x16x32_f16(af[m], bfr, acc[m][n], 0,0,0);
        }
      }
    }
    __syncthreads();
  }
  #pragma unroll
  for (int m=0;m<4;m++){
    int lr0 = wm + m*16 + g*4;
    #pragma unroll
    for (int n=0;n<4;n++){
      int col = n0 + wn + n*16 + li;
      #pragma unroll
      for (int r=0;r<4;r++)
        C[(size_t)(m0+lr0+r)*ldc + col] = acc[m][n][r]*outscale;
    }
  }
}

// ---------------- same GEMM, split-epilogue: writes 2 fp16 planes (for QKV) ----------------
__global__ __launch_bounds__(256) void gemm_f16x2s_kernel(
    const _Float16* __restrict__ a1, const _Float16* __restrict__ a2,
    const _Float16* __restrict__ b1, const _Float16* __restrict__ b2,
    _Float16* __restrict__ o1, _Float16* __restrict__ o2, int K, int ldc, float outscale)
{
  __shared__ _Float16 lsA[2][128*32];
  __shared__ _Float16 lsB[2][128*32];
  int m0 = blockIdx.y*128, n0 = blockIdx.x*128;
  int tid = threadIdx.x, wave = tid>>6, lane = tid&63;
  int g = lane>>4, li = lane&15;
  int wm = (wave>>1)*64, wn = (wave&1)*64;
  const _Float16* Ap[2] = {a1,a2};
  const _Float16* Bp[2] = {b1,b2};
  int srow = wave*32 + (lane>>2), scol = (lane&3)*8;
  const _Float16* gA[2][2]; const _Float16* gB[2][2];
  #pragma unroll
  for (int p=0;p<2;p++)
    #pragma unroll
    for (int i=0;i<2;i++){
      gA[p][i] = Ap[p] + (size_t)(m0+srow+i*16)*K + scol;
      gB[p][i] = Bp[p] + (size_t)(n0+srow+i*16)*K + scol;
    }
  f32x4 acc[4][4] = {};
  for (int k0=0; k0<K; k0+=32){
    #pragma unroll
    for (int p=0;p<2;p++)
      #pragma unroll
      for (int i=0;i<2;i++){
        gl_lds16(gA[p][i]+k0, &lsA[p][(wave*32+i*16)*32]);
        gl_lds16(gB[p][i]+k0, &lsB[p][(wave*32+i*16)*32]);
      }
    __syncthreads();
    #pragma unroll
    for (int i=0;i<2;i++){
      f16x8 af[4];
      #pragma unroll
      for (int m=0;m<4;m++) af[m] = *(f16x8*)&lsA[i][(wm+m*16+li)*32 + g*8];
      #pragma unroll
      for (int j=0;j<2-i;j++){
        #pragma unroll
        for (int n=0;n<4;n++){
          f16x8 bfr = *(f16x8*)&lsB[j][(wn+n*16+li)*32 + g*8];
          #pragma unroll
          for (int m=0;m<4;m++)
            acc[m][n] = __builtin_amdgcn_mfma_f32_16x16x32_f16(af[m], bfr, acc[m][n], 0,0,0);
        }
      }
    }
    __syncthreads();
  }
  #pragma unroll
  for (int m=0;m<4;m++){
    int lr0 = wm + m*16 + g*4;
    #pragma unroll
    for (int n=0;n<4;n++){
      int col = n0 + wn + n*16 + li;
      #pragma unroll
      for (int r=0;r<4;r++){
        float val = acc[m][n][r]*outscale;
        _Float16 xa,xb; split2h(val,xa,xb);
        size_t idx = (size_t)(m0+lr0+r)*ldc + col;
        o1[idx]=xa; o2[idx]=xb;
      }
    }
  }
}

// ---------------- flash attention: fp16x2 QK^T + fp16x2 PV, T14 async-stage, setprio ----------------
// QB=128: grid (16 qtiles, 16 heads, 2 batch), 256 thr (4 waves x 32 q-rows).
__global__ __launch_bounds__(256) void attn_f16_kernel(
    const _Float16* __restrict__ q1, const _Float16* __restrict__ q2,
    const _Float16* __restrict__ v1, const _Float16* __restrict__ v2,
    _Float16* __restrict__ o1, _Float16* __restrict__ o2)
{
  __shared__ _Float16 Ks[32*136];  // [kv][plane*64+d]
  __shared__ _Float16 Vs[64*72];   // [d][plane*32+kv]
  int qt = blockIdx.x, h = blockIdx.y, b = blockIdx.z;
  int tid = threadIdx.x, wave = tid>>6, lane = tid&63;
  int g = lane>>4, li = lane&15;
  size_t qbase = (size_t)b*SEQL + qt*128;
  const _Float16* qsrc[2] = {q1,q2};
  const _Float16* vsrc[2] = {v1,v2};
  // Q B-fragments hoisted to registers: [nf][plane][kk]
  f16x8 qf[2][2][2];
  #pragma unroll
  for (int nf=0;nf<2;nf++){
    size_t qrow = qbase + wave*32 + nf*16 + li;
    #pragma unroll
    for (int j=0;j<2;j++)
      #pragma unroll
      for (int kk=0;kk<2;kk++)
        qf[nf][j][kk] = *(const f16x8*)(qsrc[j] + qrow*QKVW + h*HDIM + kk*32 + g*8);
  }
  // T14 staging coords (per-lane): 2 K-chunks + 2 V-chunks of 8 f16
  const _Float16* kga[2]; int klds[2];
  const _Float16* vga[2]; int vlds[2];
  #pragma unroll
  for (int i=0;i<2;i++){
    int c = tid + 256*i;
    { int row=c>>4, sub=c&15, pl=sub>>3, d=(sub&7)*8;
      kga[i] = qsrc[pl] + ((size_t)b*SEQL + row)*QKVW + DMODEL + d;
      klds[i] = row*136 + pl*64 + d; }
    { int row=c>>3, sub=c&7, pl=sub>>2, s8=(sub&3)*8;
      vga[i] = vsrc[pl] + ((size_t)b*HDIM + row)*SEQL + s8;
      vlds[i] = row*72 + pl*32 + s8; }
  }
  f16x8 kreg[2], vreg[2];
  #pragma unroll
  for (int i=0;i<2;i++){ kreg[i]=*(const f16x8*)kga[i]; vreg[i]=*(const f16x8*)vga[i]; }

  float m_run[2] = {-1e30f,-1e30f}, l_run[2] = {0.f,0.f};
  f32x4 acc_o[4][2] = {};
  int src1 = (((2*g)&3)<<4) + li;
  int src2 = (((2*g+1)&3)<<4) + li;
  bool hi_half = (g>=2);

  for (int kvt=0; kvt<SEQL/KT; kvt++){
    // write staged tile to LDS
    #pragma unroll
    for (int i=0;i<2;i++){
      *(f16x8*)&Ks[klds[i]] = kreg[i];
      *(f16x8*)&Vs[vlds[i]] = vreg[i];
    }
    __syncthreads();
    // T14: issue next tile's global loads; they retire under the compute below
    if (kvt+1 < SEQL/KT){
      #pragma unroll
      for (int i=0;i<2;i++){
        kreg[i] = *(const f16x8*)(kga[i] + (size_t)(kvt+1)*KT*QKVW);
        vreg[i] = *(const f16x8*)(vga[i] + (size_t)(kvt+1)*KT);
      }
    }
    // S^T = K . Q^T  (rows kv, cols q), fp16x2 3-pass
    f32x4 s_acc[2][2] = {};
    __builtin_amdgcn_s_setprio(1);
    #pragma unroll
    for (int i=0;i<2;i++){
      #pragma unroll
      for (int kk=0;kk<2;kk++){
        f16x8 af[2];
        #pragma unroll
        for (int mf=0;mf<2;mf++)
          af[mf] = *(f16x8*)&Ks[(mf*16+li)*136 + i*64 + kk*32 + g*8];
        #pragma unroll
        for (int j=0;j<2-i;j++){
          #pragma unroll
          for (int nf=0;nf<2;nf++){
            #pragma unroll
            for (int mf=0;mf<2;mf++)
              s_acc[mf][nf] = __builtin_amdgcn_mfma_f32_16x16x32_f16(af[mf], qf[nf][j][kk], s_acc[mf][nf], 0,0,0);
          }
        }
      }
    }
    __builtin_amdgcn_s_setprio(0);
    // online softmax; P_bar = 2^15 * exp(s - m_run); defer-max THR=0.5
    float p[2][2][4];
    #pragma unroll
    for (int nf=0;nf<2;nf++){
      float mx = -1e30f;
      #pragma unroll
      for (int mf=0;mf<2;mf++)
        #pragma unroll
        for (int r=0;r<4;r++) mx = fmaxf(mx, s_acc[mf][nf][r]);
      mx = fmaxf(mx, __shfl_xor(mx,16));
      mx = fmaxf(mx, __shfl_xor(mx,32));
      mx *= SSCALE;
      if (!__all(mx <= m_run[nf] + DTHR)){
        float mn = fmaxf(m_run[nf], mx);
        float al = __expf(m_run[nf] - mn);
        m_run[nf] = mn;
        l_run[nf] *= al;
        #pragma unroll
        for (int mfd=0; mfd<4; mfd++){
          acc_o[mfd][nf][0]*=al; acc_o[mfd][nf][1]*=al;
          acc_o[mfd][nf][2]*=al; acc_o[mfd][nf][3]*=al;
        }
      }
      float rsum = 0.f;
      #pragma unroll
      for (int mf=0;mf<2;mf++)
        #pragma unroll
        for (int r=0;r<4;r++){
          float pv = __expf(s_acc[mf][nf][r]*SSCALE - m_run[nf] + PBIAS);
          p[mf][nf][r] = pv; rsum += pv;
        }
      rsum += __shfl_xor(rsum,16);
      rsum += __shfl_xor(rsum,32);
      l_run[nf] += rsum;
    }
    // gather this lane's B-frag kv-slice (kv = 8g..8g+7), split2 -> fp16 planes
    f16x8 fp_frag[2][2];
    #pragma unroll
    for (int nf=0;nf<2;nf++){
      float p8[8];
      #pragma unroll
      for (int jj=0;jj<4;jj++){
        float v0 = __shfl(p[0][nf][jj], src1);
        float vv1 = __shfl(p[1][nf][jj], src1);
        p8[jj] = hi_half ? vv1 : v0;
        float w0 = __shfl(p[0][nf][jj], src2);
        float w1 = __shfl(p[1][nf][jj], src2);
        p8[4+jj] = hi_half ? w1 : w0;
      }
      #pragma unroll
      for (int jj=0;jj<8;jj++){
        _Float16 xa,xb; split2h(p8[jj], xa,xb);
        fp_frag[nf][0][jj]=xa; fp_frag[nf][1][jj]=xb;
      }
    }
    // O^T += V^T . P   (rows d, cols q), fp16x2 3-pass
    __builtin_amdgcn_s_setprio(1);
    #pragma unroll
    for (int vj=0;vj<2;vj++){
      f16x8 av[4];
      #pragma unroll
      for (int mfd=0;mfd<4;mfd++)
        av[mfd] = *(f16x8*)&Vs[(mfd*16+li)*72 + vj*32 + g*8];
      #pragma unroll
      for (int pi=0; pi<2-vj; pi++)
        #pragma unroll
        for (int mfd=0;mfd<4;mfd++)
          #pragma unroll
          for (int nf=0;nf<2;nf++)
            acc_o[mfd][nf] = __builtin_amdgcn_mfma_f32_16x16x32_f16(av[mfd], fp_frag[nf][pi], acc_o[mfd][nf], 0,0,0);
    }
    __builtin_amdgcn_s_setprio(0);
    __syncthreads();
  }
  // epilogue: acc_o/l_run = attn*2^8 (V carried 2^8; 2^15 P-scale cancels); split2 write
  #pragma unroll
  for (int nf=0;nf<2;nf++){
    float inv = 1.f/l_run[nf];
    size_t q = qbase + wave*32 + nf*16 + li;
    #pragma unroll
    for (int mfd=0;mfd<4;mfd++){
      int d0 = mfd*16 + g*4;
      f16x4 sa,sb;
      #pragma unroll
      for (int r=0;r<4;r++){
        _Float16 xa,xb; split2h(acc_o[mfd][nf][r]*inv, xa,xb);
        sa[r]=xa; sb[r]=xb;
      }
      size_t base = q*DMODEL + h*HDIM + d0;
      *(f16x4*)(o1+base)=sa; *(f16x4*)(o2+base)=sb;
    }
  }
}

// ---------------- x2 = x + rmsnorm(ao)*g_post ; h = bf16(rmsnorm(x2)*g_pre) ----------------
__global__ __launch_bounds__(256) void attnres_kernel(
    const float* __restrict__ x, const float* __restrict__ ao,
    const float* __restrict__ gpost, const float* __restrict__ gpre,
    float* __restrict__ x2, short* __restrict__ h)
{
  int row = blockIdx.x, tid = threadIdx.x;
  float4 a  = ((const float4*)(ao + (size_t)row*DMODEL))[tid];
  float4 xv = ((const float4*)(x  + (size_t)row*DMODEL))[tid];
  float ss = a.x*a.x + a.y*a.y + a.z*a.z + a.w*a.w;
  #pragma unroll
  for (int off=32; off; off>>=1) ss += __shfl_down(ss, off);
  __shared__ float red[4];
  if ((tid&63)==0) red[tid>>6] = ss;
  __syncthreads();
  float rs1 = rsqrtf((red[0]+red[1]+red[2]+red[3])*(1.f/1024.f) + EPSV);
  float4 gp = ((const float4*)gpost)[tid];
  float4 o;
  o.x = xv.x + a.x*rs1*gp.x; o.y = xv.y + a.y*rs1*gp.y;
  o.z = xv.z + a.z*rs1*gp.z; o.w = xv.w + a.w*rs1*gp.w;
  ((float4*)(x2 + (size_t)row*DMODEL))[tid] = o;
  float s2 = o.x*o.x + o.y*o.y + o.z*o.z + o.w*o.w;
  __syncthreads();
  #pragma unroll
  for (int off=32; off; off>>=1) s2 += __shfl_down(s2, off);
  if ((tid&63)==0) red[tid>>6] = s2;
  __syncthreads();
  float rs2 = rsqrtf((red[0]+red[1]+red[2]+red[3])*(1.f/1024.f) + EPSV);
  float4 gm = ((const float4*)gpre)[tid];
  short4 hs;
  hs.x = f2b(o.x*rs2*gm.x); hs.y = f2b(o.y*rs2*gm.y);
  hs.z = f2b(o.z*rs2*gm.z); hs.w = f2b(o.w*rs2*gm.w);
  *(short4*)(h + (size_t)row*DMODEL + tid*4) = hs;
}

// ---------------- router: top-2 lists with slot packed in bit 16 ----------------
__global__ __launch_bounds__(64) void router_kernel(
    const float* __restrict__ x2, const float* __restrict__ g, const float* __restrict__ Wg,
    float* __restrict__ probs_out, int* __restrict__ tok_list, float* __restrict__ w_list,
    int* __restrict__ counts)
{
  int t = blockIdx.x, lane = threadIdx.x;
  const float4* xr = (const float4*)(x2 + (size_t)t*DMODEL);
  float4 v[4]; float ss = 0.f;
  #pragma unroll
  for (int i=0;i<4;i++){ v[i] = xr[lane + 64*i];
    ss += v[i].x*v[i].x + v[i].y*v[i].y + v[i].z*v[i].z + v[i].w*v[i].w; }
  #pragma unroll
  for (int off=32; off; off>>=1) ss += __shfl_xor(ss, off);
  float rs = rsqrtf(ss*(1.f/1024.f) + EPSV);
  float le[8] = {0,0,0,0,0,0,0,0};
  #pragma unroll
  for (int i=0;i<4;i++){
    int jb = (lane + 64*i)*4;
    float hv[4] = {v[i].x, v[i].y, v[i].z, v[i].w};
    #pragma unroll
    for (int c=0;c<4;c++){
      float hj = hv[c]*rs*g[jb+c];
      const float* wrow = Wg + (size_t)(jb+c)*NE;
      #pragma unroll
      for (int ee=0;ee<8;ee++) le[ee] += hj*wrow[ee];
    }
  }
  #pragma unroll
  for (int ee=0;ee<8;ee++)
    #pragma unroll
    for (int off=32; off; off>>=1) le[ee] += __shfl_xor(le[ee], off);
  float mx = le[0];
  #pragma unroll
  for (int ee=1;ee<8;ee++) mx = fmaxf(mx, le[ee]);
  float p[8], s = 0.f;
  #pragma unroll
  for (int ee=0;ee<8;ee++){ p[ee] = expf(le[ee]-mx); s += p[ee]; }
  float inv = 1.f/s;
  #pragma unroll
  for (int ee=0;ee<8;ee++) p[ee] *= inv;
  if (lane < 8) probs_out[(size_t)t*NE + lane] = p[lane];
  if (lane == 0){
    int i1 = 0;
    #pragma unroll
    for (int ee=1;ee<8;ee++) if (p[ee] > p[i1]) i1 = ee;
    int i2 = (i1==0) ? 1 : 0;
    #pragma unroll
    for (int ee=0;ee<8;ee++) if (ee != i1 && p[ee] > p[i2]) i2 = ee;
    int pos = atomicAdd(&counts[i1], 1);
    tok_list[i1*NTOK+pos] = t;              // slot 0
    w_list[i1*NTOK+pos] = p[i1];
    pos = atomicAdd(&counts[i2], 1);
    tok_list[i2*NTOK+pos] = t | (1<<16);    // slot 1
    w_list[i2*NTOK+pos] = p[i2];
  }
}

__global__ void prefix_kernel(const int* __restrict__ counts, int* __restrict__ bases){
  if (threadIdx.x == 0){
    int a = 0;
    for (int ee=0;ee<8;ee++){ bases[ee] = a; a += counts[ee]; }
  }
}

// ---------------- MoE grouped GEMM1: mid = gelu(h @ We1[e]^T), global_load_lds ----------------
__global__ __launch_bounds__(256) void moe_gemm1_kernel(
    const short* __restrict__ h, const short* __restrict__ we1t,
    const int* __restrict__ tok_list, const int* __restrict__ counts,
    const int* __restrict__ bases, short* __restrict__ mid)
{
  int e = blockIdx.z;
  int cnt = counts[e];
  int m0 = blockIdx.y*128, n0 = blockIdx.x*128;
  if (m0 >= cnt) return;
  int base = bases[e];
  const short* Bt = we1t + (size_t)e*HIDD*DMODEL;
  const int* tl = tok_list + e*NTOK;
  __shared__ short lsA[128*32];
  __shared__ short lsB[128*32];
  int tid = threadIdx.x, wave = tid>>6, lane = tid&63;
  int li = lane&15, g = lane>>4;
  int wm = (wave>>1)*64, wn = (wave&1)*64;
  int srow = wave*32 + (lane>>2), scol = (lane&3)*8;
  const short* gA[2]; const short* gB[2];
  #pragma unroll
  for (int i=0;i<2;i++){
    int rr = min(m0+srow+i*16, cnt-1);
    gA[i] = h + (size_t)(tl[rr] & 0xFFFF)*DMODEL + scol;
    gB[i] = Bt + (size_t)(n0+srow+i*16)*DMODEL + scol;
  }
  f32x4 acc[4][4] = {};
  for (int k0=0; k0<DMODEL; k0+=32){
    #pragma unroll
    for (int i=0;i<2;i++){
      gl_lds16(gA[i]+k0, &lsA[(wave*32+i*16)*32]);
      gl_lds16(gB[i]+k0, &lsB[(wave*32+i*16)*32]);
    }
    __syncthreads();
    bf16x8 af[4], bfr[4];
    #pragma unroll
    for (int m=0;m<4;m++) af[m] = *(bf16x8*)&lsA[(wm+m*16+li)*32 + g*8];
    #pragma unroll
    for (int n=0;n<4;n++) bfr[n] = *(bf16x8*)&lsB[(wn+n*16+li)*32 + g*8];
    #pragma unroll
    for (int m=0;m<4;m++)
      #pragma unroll
      for (int n=0;n<4;n++)
        acc[m][n] = __builtin_amdgcn_mfma_f32_16x16x32_bf16(af[m], bfr[n], acc[m][n], 0,0,0);
    __syncthreads();
  }
  #pragma unroll
  for (int m=0;m<4;m++){
    int lr0 = wm + m*16 + (g<<2);
    #pragma unroll
    for (int n=0;n<4;n++){
      int col = n0 + wn + n*16 + li;
      #pragma unroll
      for (int r=0;r<4;r++){
        int gr = m0 + lr0 + r;
        if (gr < cnt){
          float tval = acc[m][n][r];
          float u = 1.5957691216057308f*(tval + 0.044715f*tval*tval*tval);
          float ge = tval / (1.f + __expf(-u));
          mid[(size_t)(base+gr)*HIDD + col] = f2b(ge);
        }
      }
    }
  }
}

// ---------------- MoE grouped GEMM2: eo[slot][tok] = w*(mid @ We2[e]^T), global_load_lds ----------------
__global__ __launch_bounds__(256) void moe_gemm2_kernel(
    const short* __restrict__ mid, const short* __restrict__ we2t,
    const int* __restrict__ tok_list, const float* __restrict__ w_list,
    const int* __restrict__ counts, const int* __restrict__ bases,
    float* __restrict__ eo)
{
  int e = blockIdx.z;
  int cnt = counts[e];
  int m0 = blockIdx.y*128, n0 = blockIdx.x*128;
  if (m0 >= cnt) return;
  int base = bases[e];
  const short* A  = mid + (size_t)base*HIDD;
  const short* Bt = we2t + (size_t)e*DMODEL*HIDD;
  const int* tl = tok_list + e*NTOK;
  const float* wl = w_list + e*NTOK;
  __shared__ short lsA[128*32];
  __shared__ short lsB[128*32];
  int tid = threadIdx.x, wave = tid>>6, lane = tid&63;
  int li = lane&15, g = lane>>4;
  int wm = (wave>>1)*64, wn = (wave&1)*64;
  int srow = wave*32 + (lane>>2), scol = (lane&3)*8;
  const short* gA[2]; const short* gB[2];
  #pragma unroll
  for (int i=0;i<2;i++){
    int rr = min(m0+srow+i*16, cnt-1);
    gA[i] = A + (size_t)rr*HIDD + scol;
    gB[i] = Bt + (size_t)(n0+srow+i*16)*HIDD + scol;
  }
  f32x4 acc[4][4] = {};
  for (int k0=0; k0<HIDD; k0+=32){
    #pragma unroll
    for (int i=0;i<2;i++){
      gl_lds16(gA[i]+k0, &lsA[(wave*32+i*16)*32]);
      gl_lds16(gB[i]+k0, &lsB[(wave*32+i*16)*32]);
    }
    __syncthreads();
    bf16x8 af[4], bfr[4];
    #pragma unroll
    for (int m=0;m<4;m++) af[m] = *(bf16x8*)&lsA[(wm+m*16+li)*32 + g*8];
    #pragma unroll
    for (int n=0;n<4;n++) bfr[n] = *(bf16x8*)&lsB[(wn+n*16+li)*32 + g*8];
    #pragma unroll
    for (int m=0;m<4;m++)
      #pragma unroll
      for (int n=0;n<4;n++)
        acc[m][n] = __builtin_amdgcn_mfma_f32_16x16x32_bf16(af[m], bfr[n], acc[m][n], 0,0,0);
    __syncthreads();
  }
  #pragma unroll
  for (int m=0;m<4;m++){
    int lr0 = wm + m*16 + (g<<2);
    #pragma unroll
    for (int n=0;n<4;n++){
      int col = n0 + wn + n*16 + li;
      #pragma unroll
      for (int r=0;r<4;r++){
        int gr = m0 + lr0 + r;
        if (gr < cnt){
          int pv = tl[gr];
          eo[((size_t)(pv>>16)*NTOK + (pv & 0xFFFF))*DMODEL + col] = wl[gr]*acc[m][n][r];
        }
      }
    }
  }
}

// ---------------- out = x2 + rmsnorm(eo0+eo1)*g_post_moe ----------------
__global__ __launch_bounds__(256) void final_kernel(
    const float* __restrict__ x2, const float* __restrict__ eo,
    const float* __restrict__ g, float* __restrict__ out)
{
  int row = blockIdx.x, tid = threadIdx.x;
  float4 m0 = ((const float4*)(eo + (size_t)row*DMODEL))[tid];
  float4 m1 = ((const float4*)(eo + (size_t)(NTOK+row)*DMODEL))[tid];
  float4 mv;
  mv.x = m0.x+m1.x; mv.y = m0.y+m1.y; mv.z = m0.z+m1.z; mv.w = m0.w+m1.w;
  float4 xv = ((const float4*)(x2  + (size_t)row*DMODEL))[tid];
  float ss = mv.x*mv.x + mv.y*mv.y + mv.z*mv.z + mv.w*mv.w;
  #pragma unroll
  for (int off=32; off; off>>=1) ss += __shfl_down(ss, off);
  __shared__ float red[4];
  if ((tid&63)==0) red[tid>>6] = ss;
  __syncthreads();
  float rs = rsqrtf((red[0]+red[1]+red[2]+red[3])*(1.f/1024.f) + EPSV);
  float4 gv = ((const float4*)g)[tid];
  float4 o;
  o.x = xv.x + mv.x*rs*gv.x; o.y = xv.y + mv.y*rs*gv.y;
  o.z = xv.z + mv.z*rs*gv.z; o.w = xv.w + mv.w*rs*gv.w;
  ((float4*)(out + (size_t)row*DMODEL))[tid] = o;
}

extern "C" void kernel_launch(void* const* d_in, const int* in_sizes, int n_in,
                              void* d_out, int out_size, void* d_ws, size_t ws_size,
                              hipStream_t stream) {
  (void)in_sizes; (void)n_in; (void)out_size; (void)ws_size;
  const float* x          = (const float*)d_in[0];
  const float* g_pre_mqa  = (const float*)d_in[1];
  const float* g_post_mqa = (const float*)d_in[2];
  const float* g_pre_moe  = (const float*)d_in[3];
  const float* g_post_moe = (const float*)d_in[4];
  const float* Wq         = (const float*)d_in[5];
  const float* Wk         = (const float*)d_in[6];
  const float* Wv         = (const float*)d_in[7];
  const float* Wo         = (const float*)d_in[8];
  const float* Wg         = (const float*)d_in[9];
  const float* We1        = (const float*)d_in[10];
  const float* We2        = (const float*)d_in[11];

  float* out_x = (float*)d_out;
  float* out_probs = out_x + (size_t)NTOK*DMODEL;

  char* p = (char*)d_ws;
  size_t off = 0;
  auto alloc = [&](size_t bytes)->char*{
    char* r = p + off; off = (off + bytes + 255) & ~(size_t)255; return r; };

  short* we1t = (short*)alloc((size_t)NE*HIDD*DMODEL*2);       // 64M
  short* we2t = (short*)alloc((size_t)NE*DMODEL*HIDD*2);       // 64M
  short* mid  = (short*)alloc((size_t)2*NTOK*HIDD*2);          // 64M

  // region A: xn1 fp16 planes (2x8.4M), later ao fp32 (16.8M)
  char* regA = alloc((size_t)2*NTOK*DMODEL*2);
  _Float16* xn1p1 = (_Float16*)regA;
  _Float16* xn1p2 = (_Float16*)(regA + (size_t)NTOK*DMODEL*2);
  float* ao       = (float*)regA;

  _Float16* wqkvT1 = (_Float16*)alloc((size_t)QKVW*DMODEL*2);
  _Float16* wqkvT2 = (_Float16*)alloc((size_t)QKVW*DMODEL*2);
  _Float16* woT1   = (_Float16*)alloc((size_t)DMODEL*DMODEL*2);
  _Float16* woT2   = (_Float16*)alloc((size_t)DMODEL*DMODEL*2);

  // region B: attn fp16 planes (2x8.4M)
  char* regB = alloc((size_t)2*NTOK*DMODEL*2);
  _Float16* attnp1 = (_Float16*)regB;
  _Float16* attnp2 = (_Float16*)(regB + (size_t)NTOK*DMODEL*2);

  // region C: qkvf fp16 planes (2x9.4M=18.9M), later eo fp32 2 slabs (33.6M) + hbuf (8.4M)
  char* regC = alloc((size_t)2*NTOK*DMODEL*4 + (size_t)NTOK*DMODEL*2);
  _Float16* qkvf1 = (_Float16*)regC;
  _Float16* qkvf2 = (_Float16*)(regC + (size_t)NTOK*QKVW*2);
  float* eo    = (float*)regC;
  short* hbuf  = (short*)(regC + (size_t)2*NTOK*DMODEL*4);

  _Float16* vt1 = (_Float16*)alloc((size_t)2*HDIM*SEQL*2);
  _Float16* vt2 = (_Float16*)alloc((size_t)2*HDIM*SEQL*2);
  float* x2  = (float*)alloc((size_t)NTOK*DMODEL*4);
  int*   tok_l  = (int*)  alloc((size_t)NE*NTOK*4);
  float* w_l    = (float*)alloc((size_t)NE*NTOK*4);
  int*   counts = (int*)  alloc(256);
  int*   bases  = (int*)  alloc(256);

  // ---- weights prep ----
  transpose_conv_kernel<<<dim3(HIDD/32, DMODEL/32, NE), 256, 0, stream>>>(
      We1, we1t, DMODEL, HIDD, (long)DMODEL*HIDD, (long)HIDD*DMODEL);
  transpose_conv_kernel<<<dim3(DMODEL/32, HIDD/32, NE), 256, 0, stream>>>(
      We2, we2t, HIDD, DMODEL, (long)HIDD*DMODEL, (long)DMODEL*HIDD);
  transpose_split2f16_kernel<<<dim3(DMODEL/32, DMODEL/32), 256, 0, stream>>>(
      Wq, wqkvT1, wqkvT2, DMODEL, DMODEL, 0, DMODEL);
  transpose_split2f16_kernel<<<dim3(HDIM/32, DMODEL/32), 256, 0, stream>>>(
      Wk, wqkvT1, wqkvT2, DMODEL, HDIM, DMODEL, DMODEL);
  transpose_split2f16_kernel<<<dim3(HDIM/32, DMODEL/32), 256, 0, stream>>>(
      Wv, wqkvT1, wqkvT2, DMODEL, HDIM, DMODEL+HDIM, DMODEL);
  transpose_split2f16_kernel<<<dim3(DMODEL/32, DMODEL/32), 256, 0, stream>>>(
      Wo, woT1, woT2, DMODEL, DMODEL, 0, DMODEL);

  // ---- pre-router chain: fp16x2 GEMMs (QKV writes split planes directly) + fp16 attention ----
  rms_split2_kernel<<<NTOK, 256, 0, stream>>>(x, g_pre_mqa, xn1p1, xn1p2);
  gemm_f16x2s_kernel<<<dim3(QKVW/128, NTOK/128), 256, 0, stream>>>(
      xn1p1, xn1p2, wqkvT1, wqkvT2, qkvf1, qkvf2, DMODEL, QKVW, OUTSCL*ASCL);
  vtrans_split2_kernel<<<dim3(SEQL/32, HDIM/32, 2), 256, 0, stream>>>(qkvf1, qkvf2, vt1, vt2);
  attn_f16_kernel<<<dim3(SEQL/128, NH, 2), 256, 0, stream>>>(
      qkvf1, qkvf2, vt1, vt2, attnp1, attnp2);
  gemm_f16x2_kernel<<<dim3(DMODEL/128, NTOK/128), 256, 0, stream>>>(
      attnp1, attnp2, woT1, woT2, ao, DMODEL, DMODEL, OUTSCL);
  attnres_kernel<<<NTOK, 256, 0, stream>>>(x, ao, g_post_mqa, g_pre_moe, x2, hbuf);

  // ---- router + grouped MoE (bf16 MFMA, atomic-free combine) ----
  hipMemsetAsync(counts, 0, 32, stream);
  router_kernel<<<NTOK, 64, 0, stream>>>(x2, g_pre_moe, Wg, out_probs, tok_l, w_l, counts);
  prefix_kernel<<<1, 64, 0, stream>>>(counts, bases);
  moe_gemm1_kernel<<<dim3(HIDD/128, NTOK/128, NE), 256, 0, stream>>>(
      hbuf, we1t, tok_l, counts, bases, mid);
  moe_gemm2_kernel<<<dim3(DMODEL/128, NTOK/128, NE), 256, 0, stream>>>(
      mid, we2t, tok_l, w_l, counts, bases, eo);
  final_kernel<<<NTOK, 256, 0, stream>>>(x2, eo, g_post_moe, out_x);
}